// Round 1
// baseline (1195.649 us; speedup 1.0000x reference)
//
#include <hip/hip_runtime.h>
#include <hip/hip_bf16.h>

#define N_USERS_C 100000
#define N_ITEMS_C 20000
#define N_NODES_C 120000
#define E_TOT_C   400000
#define D_IN_C    192
#define HID_C     256
#define NEG_C     0.2f
#define CLAMP_C   1000.0f
#define KPAD_C    1152   // 1148 padded to multiple of 32

typedef __attribute__((ext_vector_type(8))) short bfrag;
typedef __attribute__((ext_vector_type(4))) float ffrag;

__device__ __forceinline__ float bf2f(unsigned short u){
  return __uint_as_float(((unsigned)u) << 16);
}
__device__ __forceinline__ float ldf(const void* p, long i, int isf32){
  return isf32 ? ((const float*)p)[i] : bf2f(((const unsigned short*)p)[i]);
}
__device__ __forceinline__ float sane(float v){
  return (v > -1e30f && v < 1e30f) ? v : 0.f;
}

// ---------- dtype discriminator (inputs) ----------
__global__ __launch_bounds__(256) void detect_dtype(const unsigned short* __restrict__ ue,
                                                    int* __restrict__ flag){
  __shared__ int cnt[256];
  int tid = threadIdx.x; int c = 0;
  for (int i = tid; i < 8192; i += 256){
    unsigned e = (ue[i] >> 7) & 0xFFu;
    if (e >= 129u) c++;
  }
  cnt[tid] = c; __syncthreads();
  if (tid == 0){
    int s = 0;
    for (int i = 0; i < 256; i++) s += cnt[i];
    *flag = (s > 100) ? 1 : 0;
  }
}

// ---------- convert small weight tensors into a bf16 arena ----------
#define NCONV 18
struct ConvArgs { const void* src[NCONV]; int n[NCONV]; int off[NCONV]; };

// grid = NCONV * 8 blocks; block handles tensor (b>>3), slice (b&7).
__global__ __launch_bounds__(256) void conv_small(ConvArgs a, __hip_bfloat16* __restrict__ arena,
                                                  const int* __restrict__ flag){
  int t = blockIdx.x >> 3, sub = blockIdx.x & 7;
  int f32 = *flag;
  const void* s = a.src[t];
  int n = a.n[t], off = a.off[t];
  for (int i = sub * 256 + threadIdx.x; i < n; i += 2048)
    arena[off + i] = __float2bfloat16(ldf(s, i, f32));
}

// Bt (272 x K): rows 0..255 = W^T; 256..256+H-1 = fold(Ws,a_s); next H = fold(Wd,a_d); rest 0.
__global__ void prep_bt(const __hip_bfloat16* __restrict__ Ws,
                        const __hip_bfloat16* __restrict__ Wd,
                        const __hip_bfloat16* __restrict__ as_,
                        const __hip_bfloat16* __restrict__ ad_,
                        __hip_bfloat16* __restrict__ Bt, int K, int H, int C){
  int idx = blockIdx.x * 256 + threadIdx.x;
  if (idx >= 272 * K) return;
  int col = idx / K, k = idx - col * K;
  float v;
  if (col < 256) {
    v = __bfloat162float(Ws[k * 256 + col]);
  } else if (col < 256 + H) {
    int h = col - 256; float s = 0.f;
    for (int c = 0; c < C; c++)
      s += __bfloat162float(Ws[k * 256 + h * C + c]) * __bfloat162float(as_[h * C + c]);
    v = s;
  } else if (col < 256 + 2 * H) {
    int h = col - 256 - H; float s = 0.f;
    for (int c = 0; c < C; c++)
      s += __bfloat162float(Wd[k * 256 + h * C + c]) * __bfloat162float(ad_[h * C + c]);
    v = s;
  } else v = 0.f;
  Bt[(long)col * K + k] = __float2bfloat16(v);
}

// x: (120000 x 192) bf16. Users: emb | zeros. Movies: item_emb cols 0..63.
__global__ void assemble_x(const void* __restrict__ ue, const void* __restrict__ ie,
                           __hip_bfloat16* __restrict__ x, const int* __restrict__ flag){
  long idx = (long)blockIdx.x * 256 + threadIdx.x;
  if (idx >= (long)N_NODES_C * D_IN_C) return;
  int f32 = *flag;
  int n = (int)(idx / D_IN_C); int c = (int)(idx - (long)n * D_IN_C);
  if (n < N_USERS_C) {
    x[idx] = __float2bfloat16((c < 64) ? ldf(ue, (long)n * 64 + c, f32) : 0.f);
  } else if (c < 64) {
    x[idx] = __float2bfloat16(ldf(ie, (long)(n - N_USERS_C) * 64 + c, f32));
  }
}

// ---------- movie feature path: MFMA instead of scalar MLP ----------
// mov_x (20000 x 1148) -> bf16 padded (20000 x 1152)
__global__ void conv_movx(const void* __restrict__ mv, __hip_bfloat16* __restrict__ out,
                          const int* __restrict__ flag){
  long idx = (long)blockIdx.x * 256 + threadIdx.x;
  if (idx >= (long)N_ITEMS_C * KPAD_C) return;
  int f32 = *flag;
  int m = (int)(idx / KPAD_C); int c = (int)(idx - (long)m * KPAD_C);
  float v = (c < 1148) ? ldf(mv, (long)m * 1148 + c, f32) : 0.f;
  out[idx] = __float2bfloat16(v);
}

// W1t (128 x 1152): row n<64 -> gW1 col n (k<20); row n>=64 -> tW1 col n-64 (20<=k<1148).
__global__ void prep_w1t(const __hip_bfloat16* __restrict__ gW1,
                         const __hip_bfloat16* __restrict__ tW1,
                         __hip_bfloat16* __restrict__ W1t){
  int idx = blockIdx.x * 256 + threadIdx.x;
  if (idx >= 128 * KPAD_C) return;
  int n = idx / KPAD_C, k = idx - n * KPAD_C;
  __hip_bfloat16 v = __float2bfloat16(0.f);
  if (n < 64) { if (k < 20) v = gW1[k * 64 + n]; }
  else       { if (k >= 20 && k < 1148) v = tW1[(k - 20) * 64 + (n - 64)]; }
  W1t[idx] = v;
}

// W2t (128 x 128) blockdiag of gW2 / tW2.
__global__ void prep_w2t(const __hip_bfloat16* __restrict__ gW2,
                         const __hip_bfloat16* __restrict__ tW2,
                         __hip_bfloat16* __restrict__ W2t){
  int idx = blockIdx.x * 256 + threadIdx.x;
  if (idx >= 128 * 128) return;
  int n = idx >> 7, k = idx & 127;
  __hip_bfloat16 v = __float2bfloat16(0.f);
  if (n < 64) { if (k < 64)  v = gW2[k * 64 + n]; }
  else        { if (k >= 64) v = tW2[(k - 64) * 64 + (n - 64)]; }
  W2t[idx] = v;
}

__global__ void prep_movie_bias(const __hip_bfloat16* __restrict__ gb1,
                                const __hip_bfloat16* __restrict__ tb1,
                                const __hip_bfloat16* __restrict__ gb2,
                                const __hip_bfloat16* __restrict__ tb2,
                                __hip_bfloat16* __restrict__ b1c,
                                __hip_bfloat16* __restrict__ b2c){
  int i = threadIdx.x;
  if (i < 64)       b1c[i] = gb1[i];
  else if (i < 128) b1c[i] = tb1[i - 64];
  else if (i < 192) b2c[i - 128] = gb2[i - 128];
  else              b2c[i - 128] = tb2[i - 192];
}

// MFMA GEMM, N=128 (8 n-tiles), M rows with guard, optional relu, bias add.
__global__ __launch_bounds__(256) void movie_gemm(
    const __hip_bfloat16* __restrict__ A, int lda, int M,
    const __hip_bfloat16* __restrict__ Bt, int K,
    const __hip_bfloat16* __restrict__ bias, int do_relu,
    __hip_bfloat16* __restrict__ out, int ldo, int ocol){
  int wave = threadIdx.x >> 6;
  int lane = threadIdx.x & 63;
  int l15 = lane & 15;
  int quad = lane >> 4;
  int rowbase = blockIdx.x * 64 + wave * 16;
  int ar = rowbase + l15; if (ar >= M) ar = M - 1;
  ffrag acc[8];
#pragma unroll
  for (int i = 0; i < 8; i++) acc[i] = (ffrag){0.f, 0.f, 0.f, 0.f};
  const short* As = (const short*)A;
  const short* Bs = (const short*)Bt;
  long arow = (long)ar * lda;
  for (int k0 = 0; k0 < K; k0 += 32) {
    int koff = k0 + quad * 8;
    bfrag af = *(const bfrag*)(As + arow + koff);
#pragma unroll
    for (int nt = 0; nt < 8; nt++) {
      bfrag bf = *(const bfrag*)(Bs + (long)(nt * 16 + l15) * K + koff);
      acc[nt] = __builtin_amdgcn_mfma_f32_16x16x32_bf16(af, bf, acc[nt], 0, 0, 0);
    }
  }
#pragma unroll
  for (int reg = 0; reg < 4; reg++) {
    int grow = rowbase + quad * 4 + reg;
    if (grow >= M) continue;
#pragma unroll
    for (int nt = 0; nt < 8; nt++) {
      float v = acc[nt][reg] + __bfloat162float(bias[nt * 16 + l15]);
      if (do_relu) v = fmaxf(v, 0.f);
      out[(long)grow * ldo + ocol + nt * 16 + l15] = __float2bfloat16(v);
    }
  }
}

// MFMA GEMM: A (M x K bf16) @ Bt^T -> Hout (M x 256 bf16) + als/ald (f32, M x natt).
__global__ __launch_bounds__(256) void gemm_fused(
    const __hip_bfloat16* __restrict__ A, const __hip_bfloat16* __restrict__ Bt,
    __hip_bfloat16* __restrict__ Hout, float* __restrict__ als, float* __restrict__ ald,
    int K, int natt){
  int wave = threadIdx.x >> 6;
  int lane = threadIdx.x & 63;
  int l15 = lane & 15;
  int quad = lane >> 4;
  int rowbase = blockIdx.x * 64 + wave * 16;
  ffrag acc[17];
#pragma unroll
  for (int i = 0; i < 17; i++) acc[i] = (ffrag){0.f, 0.f, 0.f, 0.f};
  const short* As = (const short*)A;
  const short* Bs = (const short*)Bt;
  long arow = (long)(rowbase + l15) * K;
  for (int k0 = 0; k0 < K; k0 += 32) {
    int koff = k0 + quad * 8;
    bfrag af = *(const bfrag*)(As + arow + koff);
#pragma unroll
    for (int nt = 0; nt < 17; nt++) {
      bfrag bf = *(const bfrag*)(Bs + (long)(nt * 16 + l15) * K + koff);
      acc[nt] = __builtin_amdgcn_mfma_f32_16x16x32_bf16(af, bf, acc[nt], 0, 0, 0);
    }
  }
  int col = l15;
#pragma unroll
  for (int reg = 0; reg < 4; reg++) {
    int grow = rowbase + quad * 4 + reg;
    long obase = (long)grow * 256;
#pragma unroll
    for (int nt = 0; nt < 16; nt++)
      Hout[obase + nt * 16 + col] = __float2bfloat16(acc[nt][reg]);
    float v = acc[16][reg];
    if (col < natt) als[grow * natt + col] = v;
    else if (col < 2 * natt) ald[grow * natt + (col - natt)] = v;
  }
}

// ---------- CSR build (in-edges per dst) ----------
__global__ void zero_deg(int* __restrict__ deg){
  int i = blockIdx.x * 256 + threadIdx.x;
  if (i < N_NODES_C) deg[i] = 0;
}

__global__ void deg_count(const int* __restrict__ ei, int* __restrict__ deg){
  int e = blockIdx.x * 256 + threadIdx.x;
  if (e >= E_TOT_C) return;
  int dst = ei[E_TOT_C + e];
  if (dst >= 0 && dst < N_NODES_C) atomicAdd(&deg[dst], 1);
}

__global__ __launch_bounds__(256) void scan_deg(const int* __restrict__ deg,
                                                int* __restrict__ ptrn){
  __shared__ int part[256];
  const int CH = 469;
  int tid = threadIdx.x;
  int base = tid * CH;
  int s = 0;
  for (int i = 0; i < CH; i++) { int idx = base + i; if (idx < N_NODES_C) s += deg[idx]; }
  part[tid] = s; __syncthreads();
  if (tid == 0) {
    int run = 0;
    for (int i = 0; i < 256; i++) { int t = part[i]; part[i] = run; run += t; }
    ptrn[N_NODES_C] = run;
  }
  __syncthreads();
  int run = part[tid];
  for (int i = 0; i < CH; i++) {
    int idx = base + i;
    if (idx < N_NODES_C) { ptrn[idx] = run; run += deg[idx]; }
  }
}

__global__ void scatter_edges(const int* __restrict__ ei, const int* __restrict__ ptrn,
                              int* __restrict__ cursor, int* __restrict__ elist_src){
  int e = blockIdx.x * 256 + threadIdx.x;
  if (e >= E_TOT_C) return;
  int dst = ei[E_TOT_C + e];
  if (dst < 0 || dst >= N_NODES_C) return;
  int pos = atomicAdd(&cursor[dst], 1);
  elist_src[ptrn[dst] + pos] = ei[e];
}

// ---------- layer 1: per-node softmax aggregation (8 heads) + bias + elu ----------
__global__ __launch_bounds__(256) void aggregate1(
    const int* __restrict__ ptrn, const int* __restrict__ elist_src,
    const float* __restrict__ als, const float* __restrict__ ald,
    const __hip_bfloat16* __restrict__ hs, const __hip_bfloat16* __restrict__ bias,
    __hip_bfloat16* __restrict__ h1){
  int node = blockIdx.x * 4 + (threadIdx.x >> 6);
  if (node >= N_NODES_C) return;
  int lane = threadIdx.x & 63;
  int c0 = lane * 4;
  int h = lane >> 3;
  int beg = ptrn[node], end = ptrn[node + 1];
  float aldv = sane(ald[node * 8 + h]);
  float mx = -1e30f;
  for (int i = beg; i < end; i++) {
    int src = elist_src[i]; src = src < 0 ? 0 : (src >= N_NODES_C ? N_NODES_C - 1 : src);
    float ev = sane(als[src * 8 + h]) + aldv;
    ev = ev > 0.f ? ev : NEG_C * ev;
    mx = fmaxf(mx, ev);
  }
  float wsum = 0.f, a0 = 0.f, a1 = 0.f, a2 = 0.f, a3 = 0.f;
  for (int i = beg; i < end; i++) {
    int src = elist_src[i]; src = src < 0 ? 0 : (src >= N_NODES_C ? N_NODES_C - 1 : src);
    float ev = sane(als[src * 8 + h]) + aldv;
    ev = ev > 0.f ? ev : NEG_C * ev;
    float w = __expf(ev - mx);
    wsum += w;
    ushort4 hv = *(const ushort4*)((const unsigned short*)hs + (long)src * 256 + c0);
    a0 += w * bf2f(hv.x); a1 += w * bf2f(hv.y);
    a2 += w * bf2f(hv.z); a3 += w * bf2f(hv.w);
  }
  float inv = 1.f / (wsum + 1e-16f);
  float v0 = a0 * inv + __bfloat162float(bias[c0 + 0]);
  float v1 = a1 * inv + __bfloat162float(bias[c0 + 1]);
  float v2 = a2 * inv + __bfloat162float(bias[c0 + 2]);
  float v3 = a3 * inv + __bfloat162float(bias[c0 + 3]);
  v0 = v0 > 0.f ? v0 : (__expf(v0) - 1.f);
  v1 = v1 > 0.f ? v1 : (__expf(v1) - 1.f);
  v2 = v2 > 0.f ? v2 : (__expf(v2) - 1.f);
  v3 = v3 > 0.f ? v3 : (__expf(v3) - 1.f);
  v0 = fminf(fmaxf(v0, -CLAMP_C), CLAMP_C);
  v1 = fminf(fmaxf(v1, -CLAMP_C), CLAMP_C);
  v2 = fminf(fmaxf(v2, -CLAMP_C), CLAMP_C);
  v3 = fminf(fmaxf(v3, -CLAMP_C), CLAMP_C);
  long ob = (long)node * 256 + c0;
  h1[ob + 0] = __float2bfloat16(v0); h1[ob + 1] = __float2bfloat16(v1);
  h1[ob + 2] = __float2bfloat16(v2); h1[ob + 3] = __float2bfloat16(v3);
}

// ---------- layer 2: 1 head, no activation. OUTPUT IS FLOAT32. ----------
__global__ __launch_bounds__(256) void aggregate2(
    const int* __restrict__ ptrn, const int* __restrict__ elist_src,
    const float* __restrict__ als, const float* __restrict__ ald,
    const __hip_bfloat16* __restrict__ hs, const __hip_bfloat16* __restrict__ bias,
    float* __restrict__ out){
  int node = blockIdx.x * 4 + (threadIdx.x >> 6);
  if (node >= N_NODES_C) return;
  int lane = threadIdx.x & 63;
  int c0 = lane * 4;
  int beg = ptrn[node], end = ptrn[node + 1];
  float aldv = sane(ald[node]);
  float mx = -1e30f;
  for (int i = beg; i < end; i++) {
    int src = elist_src[i]; src = src < 0 ? 0 : (src >= N_NODES_C ? N_NODES_C - 1 : src);
    float ev = sane(als[src]) + aldv;
    ev = ev > 0.f ? ev : NEG_C * ev;
    mx = fmaxf(mx, ev);
  }
  float wsum = 0.f, a0 = 0.f, a1 = 0.f, a2 = 0.f, a3 = 0.f;
  for (int i = beg; i < end; i++) {
    int src = elist_src[i]; src = src < 0 ? 0 : (src >= N_NODES_C ? N_NODES_C - 1 : src);
    float ev = sane(als[src]) + aldv;
    ev = ev > 0.f ? ev : NEG_C * ev;
    float w = __expf(ev - mx);
    wsum += w;
    ushort4 hv = *(const ushort4*)((const unsigned short*)hs + (long)src * 256 + c0);
    a0 += w * bf2f(hv.x); a1 += w * bf2f(hv.y);
    a2 += w * bf2f(hv.z); a3 += w * bf2f(hv.w);
  }
  float inv = 1.f / (wsum + 1e-16f);
  float4 v;
  v.x = a0 * inv + __bfloat162float(bias[c0 + 0]);
  v.y = a1 * inv + __bfloat162float(bias[c0 + 1]);
  v.z = a2 * inv + __bfloat162float(bias[c0 + 2]);
  v.w = a3 * inv + __bfloat162float(bias[c0 + 3]);
  v.x = fminf(fmaxf(v.x, -CLAMP_C), CLAMP_C);
  v.y = fminf(fmaxf(v.y, -CLAMP_C), CLAMP_C);
  v.z = fminf(fmaxf(v.z, -CLAMP_C), CLAMP_C);
  v.w = fminf(fmaxf(v.w, -CLAMP_C), CLAMP_C);
  *(float4*)(out + (long)node * 256 + c0) = v;
}

__global__ void write_tail(float* __restrict__ out, int out_size){
  if (threadIdx.x == 0 && blockIdx.x == 0) {
    out[out_size - 3] = 0.f;
    out[out_size - 2] = (float)N_USERS_C;
    out[out_size - 1] = (float)N_NODES_C;
  }
}

extern "C" void kernel_launch(void* const* d_in, const int* in_sizes, int n_in,
                              void* d_out, int out_size, void* d_ws, size_t ws_size,
                              hipStream_t stream) {
  const void* mov_x    = d_in[2];
  const int*  ei       = (const int*)d_in[3];
  const void* user_emb = d_in[4];
  const void* item_emb = d_in[5];

  char* ws = (char*)d_ws;
  size_t off = 0;
  auto alloc = [&](size_t bytes) -> void* {
    void* p = ws + off; off += (bytes + 255) / 256 * 256; return p;
  };
  int* flag   = (int*)alloc(4);
  __hip_bfloat16* arena = (__hip_bfloat16*)alloc(312832 * 2);
  __hip_bfloat16* Bt1 = (__hip_bfloat16*)alloc(272 * 192 * 2);
  __hip_bfloat16* Bt2 = (__hip_bfloat16*)alloc(272 * 256 * 2);
  __hip_bfloat16* W1t = (__hip_bfloat16*)alloc(128 * KPAD_C * 2);
  __hip_bfloat16* W2t = (__hip_bfloat16*)alloc(128 * 128 * 2);
  __hip_bfloat16* b1c = (__hip_bfloat16*)alloc(128 * 2);
  __hip_bfloat16* b2c = (__hip_bfloat16*)alloc(128 * 2);
  int* ptrn   = (int*)alloc((N_NODES_C + 1) * 4);
  int* deg    = (int*)alloc(N_NODES_C * 4);
  int* elist  = (int*)alloc(E_TOT_C * 4);
  float* als  = (float*)alloc((size_t)N_NODES_C * 8 * 4);
  float* ald  = (float*)alloc((size_t)N_NODES_C * 8 * 4);
  __hip_bfloat16* x  = (__hip_bfloat16*)alloc((size_t)N_NODES_C * D_IN_C * 2); // 46.08 MB
  __hip_bfloat16* hs = (__hip_bfloat16*)alloc((size_t)N_NODES_C * HID_C * 2);  // 61.44 MB
  // d_out (f32, 122.88 MB) hosts two dead-before-aggregate2 temporaries:
  //   h1 (bf16 61.44 MB) at byte 0; mov_bf (bf16 46.08 MB) at byte 61,440,000.
  __hip_bfloat16* h1     = (__hip_bfloat16*)d_out;
  __hip_bfloat16* mov_bf = (__hip_bfloat16*)((char*)d_out + 61440000);
  __hip_bfloat16* hid    = hs;  // movie hidden (20000x128) parks in hs

  const int oWs1=0, oWd1=49152, oas1=98304, oad1=98560, ob1=98816,
            oWs2=99072, oWd2=164608, oas2=230144, oad2=230400, ob2=230656,
            ogW1=230912, ogb1=232192, ogW2=232256, ogb2=236352,
            otW1=236416, otb1=308608, otW2=308672, otb2=312768;

  detect_dtype<<<1, 256, 0, stream>>>((const unsigned short*)user_emb, flag);

  ConvArgs ca;
  const int srcidx[NCONV] = {14,15,16,17,18,19,20,21,22,23,6,7,8,9,10,11,12,13};
  const int offs[NCONV]   = {oWs1,oWd1,oas1,oad1,ob1,oWs2,oWd2,oas2,oad2,ob2,
                             ogW1,ogb1,ogW2,ogb2,otW1,otb1,otW2,otb2};
  const int ns[NCONV]     = {49152,49152,256,256,256,65536,65536,256,256,256,
                             1280,64,4096,64,72192,64,4096,64};
  for (int i = 0; i < NCONV; i++) { ca.src[i] = d_in[srcidx[i]]; ca.n[i] = ns[i]; ca.off[i] = offs[i]; }
  conv_small<<<NCONV * 8, 256, 0, stream>>>(ca, arena, flag);

  // movie feature path (MFMA)
  conv_movx<<<(int)(((long)N_ITEMS_C * KPAD_C + 255) / 256), 256, 0, stream>>>(
      mov_x, mov_bf, flag);
  prep_w1t<<<(128 * KPAD_C + 255) / 256, 256, 0, stream>>>(arena + ogW1, arena + otW1, W1t);
  prep_w2t<<<(128 * 128 + 255) / 256, 256, 0, stream>>>(arena + ogW2, arena + otW2, W2t);
  prep_movie_bias<<<1, 256, 0, stream>>>(arena + ogb1, arena + otb1,
                                         arena + ogb2, arena + otb2, b1c, b2c);
  assemble_x<<<(int)(((long)N_NODES_C * D_IN_C + 255) / 256), 256, 0, stream>>>(
      user_emb, item_emb, x, flag);
  movie_gemm<<<(N_ITEMS_C + 63) / 64, 256, 0, stream>>>(
      mov_bf, KPAD_C, N_ITEMS_C, W1t, KPAD_C, b1c, 1, hid, 128, 0);
  movie_gemm<<<(N_ITEMS_C + 63) / 64, 256, 0, stream>>>(
      hid, 128, N_ITEMS_C, W2t, 128, b2c, 0,
      x + (long)N_USERS_C * D_IN_C, D_IN_C, 64);

  prep_bt<<<(272 * 192 + 255) / 256, 256, 0, stream>>>(
      arena + oWs1, arena + oWd1, arena + oas1, arena + oad1, Bt1, 192, 8, 32);
  prep_bt<<<(272 * 256 + 255) / 256, 256, 0, stream>>>(
      arena + oWs2, arena + oWd2, arena + oas2, arena + oad2, Bt2, 256, 1, 256);

  // CSR of in-edges
  zero_deg<<<(N_NODES_C + 255) / 256, 256, 0, stream>>>(deg);
  deg_count<<<(E_TOT_C + 255) / 256, 256, 0, stream>>>(ei, deg);
  scan_deg<<<1, 256, 0, stream>>>(deg, ptrn);
  zero_deg<<<(N_NODES_C + 255) / 256, 256, 0, stream>>>(deg);
  scatter_edges<<<(E_TOT_C + 255) / 256, 256, 0, stream>>>(ei, ptrn, deg, elist);

  // layer 1
  gemm_fused<<<N_NODES_C / 64, 256, 0, stream>>>(x, Bt1, hs, als, ald, 192, 8);
  aggregate1<<<N_NODES_C / 4, 256, 0, stream>>>(ptrn, elist, als, ald, hs, arena + ob1, h1);

  // layer 2
  gemm_fused<<<N_NODES_C / 64, 256, 0, stream>>>(h1, Bt2, hs, als, ald, 256, 1);
  aggregate2<<<N_NODES_C / 4, 256, 0, stream>>>(ptrn, elist, als, ald, hs, arena + ob2,
                                                (float*)d_out);
  write_tail<<<1, 64, 0, stream>>>((float*)d_out, out_size);
}

// Round 2
// 936.223 us; speedup vs baseline: 1.2771x; 1.2771x over previous
//
#include <hip/hip_runtime.h>
#include <hip/hip_bf16.h>

#define N_USERS_C 100000
#define N_ITEMS_C 20000
#define N_NODES_C 120000
#define E_TOT_C   400000
#define D_IN_C    192
#define HID_C     256
#define NEG_C     0.2f
#define CLAMP_C   1000.0f
#define KPAD_C    1152   // 1148 padded to multiple of 32
#define NB_SCAN   ((N_NODES_C + 255) / 256)   // 469 scan blocks

typedef __attribute__((ext_vector_type(8))) short bfrag;
typedef __attribute__((ext_vector_type(4))) float ffrag;

__device__ __forceinline__ float bf2f(unsigned short u){
  return __uint_as_float(((unsigned)u) << 16);
}
__device__ __forceinline__ float ldf(const void* p, long i, int isf32){
  return isf32 ? ((const float*)p)[i] : bf2f(((const unsigned short*)p)[i]);
}
__device__ __forceinline__ float sane(float v){
  return (v > -1e30f && v < 1e30f) ? v : 0.f;
}

// ---------- dtype discriminator (inputs) ----------
__global__ __launch_bounds__(256) void detect_dtype(const unsigned short* __restrict__ ue,
                                                    int* __restrict__ flag){
  __shared__ int cnt[256];
  int tid = threadIdx.x; int c = 0;
  for (int i = tid; i < 8192; i += 256){
    unsigned e = (ue[i] >> 7) & 0xFFu;
    if (e >= 129u) c++;
  }
  cnt[tid] = c; __syncthreads();
  if (tid == 0){
    int s = 0;
    for (int i = 0; i < 256; i++) s += cnt[i];
    *flag = (s > 100) ? 1 : 0;
  }
}

// ---------- convert small weight tensors into a bf16 arena ----------
#define NCONV 18
struct ConvArgs { const void* src[NCONV]; int n[NCONV]; int off[NCONV]; };

// grid = NCONV * 8 blocks; block handles tensor (b>>3), slice (b&7).
__global__ __launch_bounds__(256) void conv_small(ConvArgs a, __hip_bfloat16* __restrict__ arena,
                                                  const int* __restrict__ flag){
  int t = blockIdx.x >> 3, sub = blockIdx.x & 7;
  int f32 = *flag;
  const void* s = a.src[t];
  int n = a.n[t], off = a.off[t];
  for (int i = sub * 256 + threadIdx.x; i < n; i += 2048)
    arena[off + i] = __float2bfloat16(ldf(s, i, f32));
}

// Bt (272 x K): rows 0..255 = W^T; 256..256+H-1 = fold(Ws,a_s); next H = fold(Wd,a_d); rest 0.
__global__ void prep_bt(const __hip_bfloat16* __restrict__ Ws,
                        const __hip_bfloat16* __restrict__ Wd,
                        const __hip_bfloat16* __restrict__ as_,
                        const __hip_bfloat16* __restrict__ ad_,
                        __hip_bfloat16* __restrict__ Bt, int K, int H, int C){
  int idx = blockIdx.x * 256 + threadIdx.x;
  if (idx >= 272 * K) return;
  int col = idx / K, k = idx - col * K;
  float v;
  if (col < 256) {
    v = __bfloat162float(Ws[k * 256 + col]);
  } else if (col < 256 + H) {
    int h = col - 256; float s = 0.f;
    for (int c = 0; c < C; c++)
      s += __bfloat162float(Ws[k * 256 + h * C + c]) * __bfloat162float(as_[h * C + c]);
    v = s;
  } else if (col < 256 + 2 * H) {
    int h = col - 256 - H; float s = 0.f;
    for (int c = 0; c < C; c++)
      s += __bfloat162float(Wd[k * 256 + h * C + c]) * __bfloat162float(ad_[h * C + c]);
    v = s;
  } else v = 0.f;
  Bt[(long)col * K + k] = __float2bfloat16(v);
}

// x: (120000 x 192) bf16. Users: emb | zeros. Movies: item_emb cols 0..63.
__global__ void assemble_x(const void* __restrict__ ue, const void* __restrict__ ie,
                           __hip_bfloat16* __restrict__ x, const int* __restrict__ flag){
  long idx = (long)blockIdx.x * 256 + threadIdx.x;
  if (idx >= (long)N_NODES_C * D_IN_C) return;
  int f32 = *flag;
  int n = (int)(idx / D_IN_C); int c = (int)(idx - (long)n * D_IN_C);
  if (n < N_USERS_C) {
    x[idx] = __float2bfloat16((c < 64) ? ldf(ue, (long)n * 64 + c, f32) : 0.f);
  } else if (c < 64) {
    x[idx] = __float2bfloat16(ldf(ie, (long)(n - N_USERS_C) * 64 + c, f32));
  }
}

// ---------- movie feature path: MFMA instead of scalar MLP ----------
// mov_x (20000 x 1148) -> bf16 padded (20000 x 1152)
__global__ void conv_movx(const void* __restrict__ mv, __hip_bfloat16* __restrict__ out,
                          const int* __restrict__ flag){
  long idx = (long)blockIdx.x * 256 + threadIdx.x;
  if (idx >= (long)N_ITEMS_C * KPAD_C) return;
  int f32 = *flag;
  int m = (int)(idx / KPAD_C); int c = (int)(idx - (long)m * KPAD_C);
  float v = (c < 1148) ? ldf(mv, (long)m * 1148 + c, f32) : 0.f;
  out[idx] = __float2bfloat16(v);
}

// W1t (128 x 1152): row n<64 -> gW1 col n (k<20); row n>=64 -> tW1 col n-64 (20<=k<1148).
__global__ void prep_w1t(const __hip_bfloat16* __restrict__ gW1,
                         const __hip_bfloat16* __restrict__ tW1,
                         __hip_bfloat16* __restrict__ W1t){
  int idx = blockIdx.x * 256 + threadIdx.x;
  if (idx >= 128 * KPAD_C) return;
  int n = idx / KPAD_C, k = idx - n * KPAD_C;
  __hip_bfloat16 v = __float2bfloat16(0.f);
  if (n < 64) { if (k < 20) v = gW1[k * 64 + n]; }
  else       { if (k >= 20 && k < 1148) v = tW1[(k - 20) * 64 + (n - 64)]; }
  W1t[idx] = v;
}

// W2t (128 x 128) blockdiag of gW2 / tW2.
__global__ void prep_w2t(const __hip_bfloat16* __restrict__ gW2,
                         const __hip_bfloat16* __restrict__ tW2,
                         __hip_bfloat16* __restrict__ W2t){
  int idx = blockIdx.x * 256 + threadIdx.x;
  if (idx >= 128 * 128) return;
  int n = idx >> 7, k = idx & 127;
  __hip_bfloat16 v = __float2bfloat16(0.f);
  if (n < 64) { if (k < 64)  v = gW2[k * 64 + n]; }
  else        { if (k >= 64) v = tW2[(k - 64) * 64 + (n - 64)]; }
  W2t[idx] = v;
}

__global__ void prep_movie_bias(const __hip_bfloat16* __restrict__ gb1,
                                const __hip_bfloat16* __restrict__ tb1,
                                const __hip_bfloat16* __restrict__ gb2,
                                const __hip_bfloat16* __restrict__ tb2,
                                __hip_bfloat16* __restrict__ b1c,
                                __hip_bfloat16* __restrict__ b2c){
  int i = threadIdx.x;
  if (i < 64)       b1c[i] = gb1[i];
  else if (i < 128) b1c[i] = tb1[i - 64];
  else if (i < 192) b2c[i - 128] = gb2[i - 128];
  else              b2c[i - 128] = tb2[i - 192];
}

// MFMA GEMM, N=128 (8 n-tiles), M rows with guard, optional relu, bias add.
__global__ __launch_bounds__(256) void movie_gemm(
    const __hip_bfloat16* __restrict__ A, int lda, int M,
    const __hip_bfloat16* __restrict__ Bt, int K,
    const __hip_bfloat16* __restrict__ bias, int do_relu,
    __hip_bfloat16* __restrict__ out, int ldo, int ocol){
  int wave = threadIdx.x >> 6;
  int lane = threadIdx.x & 63;
  int l15 = lane & 15;
  int quad = lane >> 4;
  int rowbase = blockIdx.x * 64 + wave * 16;
  int ar = rowbase + l15; if (ar >= M) ar = M - 1;
  ffrag acc[8];
#pragma unroll
  for (int i = 0; i < 8; i++) acc[i] = (ffrag){0.f, 0.f, 0.f, 0.f};
  const short* As = (const short*)A;
  const short* Bs = (const short*)Bt;
  long arow = (long)ar * lda;
  for (int k0 = 0; k0 < K; k0 += 32) {
    int koff = k0 + quad * 8;
    bfrag af = *(const bfrag*)(As + arow + koff);
#pragma unroll
    for (int nt = 0; nt < 8; nt++) {
      bfrag bf = *(const bfrag*)(Bs + (long)(nt * 16 + l15) * K + koff);
      acc[nt] = __builtin_amdgcn_mfma_f32_16x16x32_bf16(af, bf, acc[nt], 0, 0, 0);
    }
  }
#pragma unroll
  for (int reg = 0; reg < 4; reg++) {
    int grow = rowbase + quad * 4 + reg;
    if (grow >= M) continue;
#pragma unroll
    for (int nt = 0; nt < 8; nt++) {
      float v = acc[nt][reg] + __bfloat162float(bias[nt * 16 + l15]);
      if (do_relu) v = fmaxf(v, 0.f);
      out[(long)grow * ldo + ocol + nt * 16 + l15] = __float2bfloat16(v);
    }
  }
}

// MFMA GEMM: A (M x K bf16) @ Bt^T -> Hout (M x 256 bf16) + als/ald (f32, M x natt).
__global__ __launch_bounds__(256) void gemm_fused(
    const __hip_bfloat16* __restrict__ A, const __hip_bfloat16* __restrict__ Bt,
    __hip_bfloat16* __restrict__ Hout, float* __restrict__ als, float* __restrict__ ald,
    int K, int natt){
  int wave = threadIdx.x >> 6;
  int lane = threadIdx.x & 63;
  int l15 = lane & 15;
  int quad = lane >> 4;
  int rowbase = blockIdx.x * 64 + wave * 16;
  ffrag acc[17];
#pragma unroll
  for (int i = 0; i < 17; i++) acc[i] = (ffrag){0.f, 0.f, 0.f, 0.f};
  const short* As = (const short*)A;
  const short* Bs = (const short*)Bt;
  long arow = (long)(rowbase + l15) * K;
  for (int k0 = 0; k0 < K; k0 += 32) {
    int koff = k0 + quad * 8;
    bfrag af = *(const bfrag*)(As + arow + koff);
#pragma unroll
    for (int nt = 0; nt < 17; nt++) {
      bfrag bf = *(const bfrag*)(Bs + (long)(nt * 16 + l15) * K + koff);
      acc[nt] = __builtin_amdgcn_mfma_f32_16x16x32_bf16(af, bf, acc[nt], 0, 0, 0);
    }
  }
  int col = l15;
#pragma unroll
  for (int reg = 0; reg < 4; reg++) {
    int grow = rowbase + quad * 4 + reg;
    long obase = (long)grow * 256;
#pragma unroll
    for (int nt = 0; nt < 16; nt++)
      Hout[obase + nt * 16 + col] = __float2bfloat16(acc[nt][reg]);
    float v = acc[16][reg];
    if (col < natt) als[grow * natt + col] = v;
    else if (col < 2 * natt) ald[grow * natt + (col - natt)] = v;
  }
}

// ---------- CSR build (in-edges per dst) ----------
__global__ void zero_deg(int* __restrict__ deg){
  int i = blockIdx.x * 256 + threadIdx.x;
  if (i < N_NODES_C) deg[i] = 0;
}

__global__ void deg_count(const int* __restrict__ ei, int* __restrict__ deg){
  int e = blockIdx.x * 256 + threadIdx.x;
  if (e >= E_TOT_C) return;
  int dst = ei[E_TOT_C + e];
  if (dst >= 0 && dst < N_NODES_C) atomicAdd(&deg[dst], 1);
}

// Hierarchical exclusive scan of deg -> ptrn (replaces 267us single-block scan_deg).
// Stage 1: per-block (256-wide) sums.
__global__ __launch_bounds__(256) void deg_bsum(const int* __restrict__ deg,
                                                int* __restrict__ bsum){
  int i = blockIdx.x * 256 + threadIdx.x;
  int v = (i < N_NODES_C) ? deg[i] : 0;
#pragma unroll
  for (int o = 32; o > 0; o >>= 1) v += __shfl_down(v, o, 64);
  __shared__ int ws[4];
  int wave = threadIdx.x >> 6, lane = threadIdx.x & 63;
  if (lane == 0) ws[wave] = v;
  __syncthreads();
  if (threadIdx.x == 0) bsum[blockIdx.x] = ws[0] + ws[1] + ws[2] + ws[3];
}

// Stage 2: single-block Hillis-Steele scan of 469 block sums -> exclusive offsets.
__global__ __launch_bounds__(512) void bsum_scan(int* __restrict__ bsum,
                                                 int* __restrict__ ptrn){
  __shared__ int sm[512];
  int t = threadIdx.x;
  int v = (t < NB_SCAN) ? bsum[t] : 0;
  sm[t] = v;
  __syncthreads();
  for (int o = 1; o < 512; o <<= 1) {
    int add = (t >= o) ? sm[t - o] : 0;
    __syncthreads();
    sm[t] += add;
    __syncthreads();
  }
  int excl = (t == 0) ? 0 : sm[t - 1];
  if (t < NB_SCAN) bsum[t] = excl;
  if (t == NB_SCAN - 1) ptrn[N_NODES_C] = sm[t];
}

// Stage 3: in-block exclusive scan + block offset -> ptrn.
__global__ __launch_bounds__(256) void deg_scan_final(const int* __restrict__ deg,
                                                      const int* __restrict__ bexcl,
                                                      int* __restrict__ ptrn){
  __shared__ int sm[256];
  int i = blockIdx.x * 256 + threadIdx.x;
  int t = threadIdx.x;
  int v = (i < N_NODES_C) ? deg[i] : 0;
  sm[t] = v;
  __syncthreads();
  for (int o = 1; o < 256; o <<= 1) {
    int add = (t >= o) ? sm[t - o] : 0;
    __syncthreads();
    sm[t] += add;
    __syncthreads();
  }
  int excl = (t == 0) ? 0 : sm[t - 1];
  if (i < N_NODES_C) ptrn[i] = bexcl[blockIdx.x] + excl;
}

__global__ void scatter_edges(const int* __restrict__ ei, const int* __restrict__ ptrn,
                              int* __restrict__ cursor, int* __restrict__ elist_src){
  int e = blockIdx.x * 256 + threadIdx.x;
  if (e >= E_TOT_C) return;
  int dst = ei[E_TOT_C + e];
  if (dst < 0 || dst >= N_NODES_C) return;
  int pos = atomicAdd(&cursor[dst], 1);
  elist_src[ptrn[dst] + pos] = ei[e];
}

// ---------- layer 1: per-node softmax aggregation (8 heads) + bias + elu ----------
__global__ __launch_bounds__(256) void aggregate1(
    const int* __restrict__ ptrn, const int* __restrict__ elist_src,
    const float* __restrict__ als, const float* __restrict__ ald,
    const __hip_bfloat16* __restrict__ hs, const __hip_bfloat16* __restrict__ bias,
    __hip_bfloat16* __restrict__ h1){
  int node = blockIdx.x * 4 + (threadIdx.x >> 6);
  if (node >= N_NODES_C) return;
  int lane = threadIdx.x & 63;
  int c0 = lane * 4;
  int h = lane >> 3;
  int beg = ptrn[node], end = ptrn[node + 1];
  float aldv = sane(ald[node * 8 + h]);
  float mx = -1e30f;
  for (int i = beg; i < end; i++) {
    int src = elist_src[i]; src = src < 0 ? 0 : (src >= N_NODES_C ? N_NODES_C - 1 : src);
    float ev = sane(als[src * 8 + h]) + aldv;
    ev = ev > 0.f ? ev : NEG_C * ev;
    mx = fmaxf(mx, ev);
  }
  float wsum = 0.f, a0 = 0.f, a1 = 0.f, a2 = 0.f, a3 = 0.f;
  for (int i = beg; i < end; i++) {
    int src = elist_src[i]; src = src < 0 ? 0 : (src >= N_NODES_C ? N_NODES_C - 1 : src);
    float ev = sane(als[src * 8 + h]) + aldv;
    ev = ev > 0.f ? ev : NEG_C * ev;
    float w = __expf(ev - mx);
    wsum += w;
    ushort4 hv = *(const ushort4*)((const unsigned short*)hs + (long)src * 256 + c0);
    a0 += w * bf2f(hv.x); a1 += w * bf2f(hv.y);
    a2 += w * bf2f(hv.z); a3 += w * bf2f(hv.w);
  }
  float inv = 1.f / (wsum + 1e-16f);
  float v0 = a0 * inv + __bfloat162float(bias[c0 + 0]);
  float v1 = a1 * inv + __bfloat162float(bias[c0 + 1]);
  float v2 = a2 * inv + __bfloat162float(bias[c0 + 2]);
  float v3 = a3 * inv + __bfloat162float(bias[c0 + 3]);
  v0 = v0 > 0.f ? v0 : (__expf(v0) - 1.f);
  v1 = v1 > 0.f ? v1 : (__expf(v1) - 1.f);
  v2 = v2 > 0.f ? v2 : (__expf(v2) - 1.f);
  v3 = v3 > 0.f ? v3 : (__expf(v3) - 1.f);
  v0 = fminf(fmaxf(v0, -CLAMP_C), CLAMP_C);
  v1 = fminf(fmaxf(v1, -CLAMP_C), CLAMP_C);
  v2 = fminf(fmaxf(v2, -CLAMP_C), CLAMP_C);
  v3 = fminf(fmaxf(v3, -CLAMP_C), CLAMP_C);
  long ob = (long)node * 256 + c0;
  h1[ob + 0] = __float2bfloat16(v0); h1[ob + 1] = __float2bfloat16(v1);
  h1[ob + 2] = __float2bfloat16(v2); h1[ob + 3] = __float2bfloat16(v3);
}

// ---------- layer 2: 1 head, no activation. OUTPUT IS FLOAT32. ----------
__global__ __launch_bounds__(256) void aggregate2(
    const int* __restrict__ ptrn, const int* __restrict__ elist_src,
    const float* __restrict__ als, const float* __restrict__ ald,
    const __hip_bfloat16* __restrict__ hs, const __hip_bfloat16* __restrict__ bias,
    float* __restrict__ out){
  int node = blockIdx.x * 4 + (threadIdx.x >> 6);
  if (node >= N_NODES_C) return;
  int lane = threadIdx.x & 63;
  int c0 = lane * 4;
  int beg = ptrn[node], end = ptrn[node + 1];
  float aldv = sane(ald[node]);
  float mx = -1e30f;
  for (int i = beg; i < end; i++) {
    int src = elist_src[i]; src = src < 0 ? 0 : (src >= N_NODES_C ? N_NODES_C - 1 : src);
    float ev = sane(als[src]) + aldv;
    ev = ev > 0.f ? ev : NEG_C * ev;
    mx = fmaxf(mx, ev);
  }
  float wsum = 0.f, a0 = 0.f, a1 = 0.f, a2 = 0.f, a3 = 0.f;
  for (int i = beg; i < end; i++) {
    int src = elist_src[i]; src = src < 0 ? 0 : (src >= N_NODES_C ? N_NODES_C - 1 : src);
    float ev = sane(als[src]) + aldv;
    ev = ev > 0.f ? ev : NEG_C * ev;
    float w = __expf(ev - mx);
    wsum += w;
    ushort4 hv = *(const ushort4*)((const unsigned short*)hs + (long)src * 256 + c0);
    a0 += w * bf2f(hv.x); a1 += w * bf2f(hv.y);
    a2 += w * bf2f(hv.z); a3 += w * bf2f(hv.w);
  }
  float inv = 1.f / (wsum + 1e-16f);
  float4 v;
  v.x = a0 * inv + __bfloat162float(bias[c0 + 0]);
  v.y = a1 * inv + __bfloat162float(bias[c0 + 1]);
  v.z = a2 * inv + __bfloat162float(bias[c0 + 2]);
  v.w = a3 * inv + __bfloat162float(bias[c0 + 3]);
  v.x = fminf(fmaxf(v.x, -CLAMP_C), CLAMP_C);
  v.y = fminf(fmaxf(v.y, -CLAMP_C), CLAMP_C);
  v.z = fminf(fmaxf(v.z, -CLAMP_C), CLAMP_C);
  v.w = fminf(fmaxf(v.w, -CLAMP_C), CLAMP_C);
  *(float4*)(out + (long)node * 256 + c0) = v;
}

__global__ void write_tail(float* __restrict__ out, int out_size){
  if (threadIdx.x == 0 && blockIdx.x == 0) {
    out[out_size - 3] = 0.f;
    out[out_size - 2] = (float)N_USERS_C;
    out[out_size - 1] = (float)N_NODES_C;
  }
}

extern "C" void kernel_launch(void* const* d_in, const int* in_sizes, int n_in,
                              void* d_out, int out_size, void* d_ws, size_t ws_size,
                              hipStream_t stream) {
  const void* mov_x    = d_in[2];
  const int*  ei       = (const int*)d_in[3];
  const void* user_emb = d_in[4];
  const void* item_emb = d_in[5];

  char* ws = (char*)d_ws;
  size_t off = 0;
  auto alloc = [&](size_t bytes) -> void* {
    void* p = ws + off; off += (bytes + 255) / 256 * 256; return p;
  };
  int* flag   = (int*)alloc(4);
  __hip_bfloat16* arena = (__hip_bfloat16*)alloc(312832 * 2);
  __hip_bfloat16* Bt1 = (__hip_bfloat16*)alloc(272 * 192 * 2);
  __hip_bfloat16* Bt2 = (__hip_bfloat16*)alloc(272 * 256 * 2);
  __hip_bfloat16* W1t = (__hip_bfloat16*)alloc(128 * KPAD_C * 2);
  __hip_bfloat16* W2t = (__hip_bfloat16*)alloc(128 * 128 * 2);
  __hip_bfloat16* b1c = (__hip_bfloat16*)alloc(128 * 2);
  __hip_bfloat16* b2c = (__hip_bfloat16*)alloc(128 * 2);
  int* ptrn   = (int*)alloc((N_NODES_C + 1) * 4);
  int* deg    = (int*)alloc(N_NODES_C * 4);
  int* bsum   = (int*)alloc(512 * 4);
  int* elist  = (int*)alloc(E_TOT_C * 4);
  float* als  = (float*)alloc((size_t)N_NODES_C * 8 * 4);
  float* ald  = (float*)alloc((size_t)N_NODES_C * 8 * 4);
  __hip_bfloat16* x  = (__hip_bfloat16*)alloc((size_t)N_NODES_C * D_IN_C * 2); // 46.08 MB
  __hip_bfloat16* hs = (__hip_bfloat16*)alloc((size_t)N_NODES_C * HID_C * 2);  // 61.44 MB
  // d_out (f32, 122.88 MB) hosts two dead-before-aggregate2 temporaries:
  //   h1 (bf16 61.44 MB) at byte 0; mov_bf (bf16 46.08 MB) at byte 61,440,000.
  __hip_bfloat16* h1     = (__hip_bfloat16*)d_out;
  __hip_bfloat16* mov_bf = (__hip_bfloat16*)((char*)d_out + 61440000);
  __hip_bfloat16* hid    = hs;  // movie hidden (20000x128) parks in hs

  const int oWs1=0, oWd1=49152, oas1=98304, oad1=98560, ob1=98816,
            oWs2=99072, oWd2=164608, oas2=230144, oad2=230400, ob2=230656,
            ogW1=230912, ogb1=232192, ogW2=232256, ogb2=236352,
            otW1=236416, otb1=308608, otW2=308672, otb2=312768;

  detect_dtype<<<1, 256, 0, stream>>>((const unsigned short*)user_emb, flag);

  ConvArgs ca;
  const int srcidx[NCONV] = {14,15,16,17,18,19,20,21,22,23,6,7,8,9,10,11,12,13};
  const int offs[NCONV]   = {oWs1,oWd1,oas1,oad1,ob1,oWs2,oWd2,oas2,oad2,ob2,
                             ogW1,ogb1,ogW2,ogb2,otW1,otb1,otW2,otb2};
  const int ns[NCONV]     = {49152,49152,256,256,256,65536,65536,256,256,256,
                             1280,64,4096,64,72192,64,4096,64};
  for (int i = 0; i < NCONV; i++) { ca.src[i] = d_in[srcidx[i]]; ca.n[i] = ns[i]; ca.off[i] = offs[i]; }
  conv_small<<<NCONV * 8, 256, 0, stream>>>(ca, arena, flag);

  // movie feature path (MFMA)
  conv_movx<<<(int)(((long)N_ITEMS_C * KPAD_C + 255) / 256), 256, 0, stream>>>(
      mov_x, mov_bf, flag);
  prep_w1t<<<(128 * KPAD_C + 255) / 256, 256, 0, stream>>>(arena + ogW1, arena + otW1, W1t);
  prep_w2t<<<(128 * 128 + 255) / 256, 256, 0, stream>>>(arena + ogW2, arena + otW2, W2t);
  prep_movie_bias<<<1, 256, 0, stream>>>(arena + ogb1, arena + otb1,
                                         arena + ogb2, arena + otb2, b1c, b2c);
  assemble_x<<<(int)(((long)N_NODES_C * D_IN_C + 255) / 256), 256, 0, stream>>>(
      user_emb, item_emb, x, flag);
  movie_gemm<<<(N_ITEMS_C + 63) / 64, 256, 0, stream>>>(
      mov_bf, KPAD_C, N_ITEMS_C, W1t, KPAD_C, b1c, 1, hid, 128, 0);
  movie_gemm<<<(N_ITEMS_C + 63) / 64, 256, 0, stream>>>(
      hid, 128, N_ITEMS_C, W2t, 128, b2c, 0,
      x + (long)N_USERS_C * D_IN_C, D_IN_C, 64);

  prep_bt<<<(272 * 192 + 255) / 256, 256, 0, stream>>>(
      arena + oWs1, arena + oWd1, arena + oas1, arena + oad1, Bt1, 192, 8, 32);
  prep_bt<<<(272 * 256 + 255) / 256, 256, 0, stream>>>(
      arena + oWs2, arena + oWd2, arena + oas2, arena + oad2, Bt2, 256, 1, 256);

  // CSR of in-edges
  zero_deg<<<(N_NODES_C + 255) / 256, 256, 0, stream>>>(deg);
  deg_count<<<(E_TOT_C + 255) / 256, 256, 0, stream>>>(ei, deg);
  deg_bsum<<<NB_SCAN, 256, 0, stream>>>(deg, bsum);
  bsum_scan<<<1, 512, 0, stream>>>(bsum, ptrn);
  deg_scan_final<<<NB_SCAN, 256, 0, stream>>>(deg, bsum, ptrn);
  zero_deg<<<(N_NODES_C + 255) / 256, 256, 0, stream>>>(deg);
  scatter_edges<<<(E_TOT_C + 255) / 256, 256, 0, stream>>>(ei, ptrn, deg, elist);

  // layer 1
  gemm_fused<<<N_NODES_C / 64, 256, 0, stream>>>(x, Bt1, hs, als, ald, 192, 8);
  aggregate1<<<N_NODES_C / 4, 256, 0, stream>>>(ptrn, elist, als, ald, hs, arena + ob1, h1);

  // layer 2
  gemm_fused<<<N_NODES_C / 64, 256, 0, stream>>>(h1, Bt2, hs, als, ald, 256, 1);
  aggregate2<<<N_NODES_C / 4, 256, 0, stream>>>(ptrn, elist, als, ald, hs, arena + ob2,
                                                (float*)d_out);
  write_tail<<<1, 64, 0, stream>>>((float*)d_out, out_size);
}

// Round 3
// 925.611 us; speedup vs baseline: 1.2917x; 1.0115x over previous
//
#include <hip/hip_runtime.h>
#include <hip/hip_bf16.h>

#define N_USERS_C 100000
#define N_ITEMS_C 20000
#define N_NODES_C 120000
#define E_TOT_C   400000
#define D_IN_C    192
#define HID_C     256
#define NEG_C     0.2f
#define CLAMP_C   1000.0f
#define KPAD_C    1152   // 1148 padded to multiple of 32
#define NB_SCAN   ((N_NODES_C + 255) / 256)   // 469 scan blocks

typedef __attribute__((ext_vector_type(8))) short bfrag;
typedef __attribute__((ext_vector_type(4))) float ffrag;

__device__ __forceinline__ float bf2f(unsigned short u){
  return __uint_as_float(((unsigned)u) << 16);
}
__device__ __forceinline__ float ldf(const void* p, long i, int isf32){
  return isf32 ? ((const float*)p)[i] : bf2f(((const unsigned short*)p)[i]);
}
__device__ __forceinline__ float sane(float v){
  return (v > -1e30f && v < 1e30f) ? v : 0.f;
}

// ---------- dtype discriminator (inputs) ----------
__global__ __launch_bounds__(256) void detect_dtype(const unsigned short* __restrict__ ue,
                                                    int* __restrict__ flag){
  __shared__ int cnt[256];
  int tid = threadIdx.x; int c = 0;
  for (int i = tid; i < 8192; i += 256){
    unsigned e = (ue[i] >> 7) & 0xFFu;
    if (e >= 129u) c++;
  }
  cnt[tid] = c; __syncthreads();
  if (tid == 0){
    int s = 0;
    for (int i = 0; i < 256; i++) s += cnt[i];
    *flag = (s > 100) ? 1 : 0;
  }
}

// ---------- convert small weight tensors into a bf16 arena ----------
#define NCONV 18
struct ConvArgs { const void* src[NCONV]; int n[NCONV]; int off[NCONV]; };

// grid = NCONV * 8 blocks; block handles tensor (b>>3), slice (b&7).
__global__ __launch_bounds__(256) void conv_small(ConvArgs a, __hip_bfloat16* __restrict__ arena,
                                                  const int* __restrict__ flag){
  int t = blockIdx.x >> 3, sub = blockIdx.x & 7;
  int f32 = *flag;
  const void* s = a.src[t];
  int n = a.n[t], off = a.off[t];
  for (int i = sub * 256 + threadIdx.x; i < n; i += 2048)
    arena[off + i] = __float2bfloat16(ldf(s, i, f32));
}

// Bt (272 x K): rows 0..255 = W^T; 256..256+H-1 = fold(Ws,a_s); next H = fold(Wd,a_d); rest 0.
__global__ void prep_bt(const __hip_bfloat16* __restrict__ Ws,
                        const __hip_bfloat16* __restrict__ Wd,
                        const __hip_bfloat16* __restrict__ as_,
                        const __hip_bfloat16* __restrict__ ad_,
                        __hip_bfloat16* __restrict__ Bt, int K, int H, int C){
  int idx = blockIdx.x * 256 + threadIdx.x;
  if (idx >= 272 * K) return;
  int col = idx / K, k = idx - col * K;
  float v;
  if (col < 256) {
    v = __bfloat162float(Ws[k * 256 + col]);
  } else if (col < 256 + H) {
    int h = col - 256; float s = 0.f;
    for (int c = 0; c < C; c++)
      s += __bfloat162float(Ws[k * 256 + h * C + c]) * __bfloat162float(as_[h * C + c]);
    v = s;
  } else if (col < 256 + 2 * H) {
    int h = col - 256 - H; float s = 0.f;
    for (int c = 0; c < C; c++)
      s += __bfloat162float(Wd[k * 256 + h * C + c]) * __bfloat162float(ad_[h * C + c]);
    v = s;
  } else v = 0.f;
  Bt[(long)col * K + k] = __float2bfloat16(v);
}

// x: (120000 x 192) bf16. Users: emb | zeros. Movies: item_emb cols 0..63.
__global__ void assemble_x(const void* __restrict__ ue, const void* __restrict__ ie,
                           __hip_bfloat16* __restrict__ x, const int* __restrict__ flag){
  long idx = (long)blockIdx.x * 256 + threadIdx.x;
  if (idx >= (long)N_NODES_C * D_IN_C) return;
  int f32 = *flag;
  int n = (int)(idx / D_IN_C); int c = (int)(idx - (long)n * D_IN_C);
  if (n < N_USERS_C) {
    x[idx] = __float2bfloat16((c < 64) ? ldf(ue, (long)n * 64 + c, f32) : 0.f);
  } else if (c < 64) {
    x[idx] = __float2bfloat16(ldf(ie, (long)(n - N_USERS_C) * 64 + c, f32));
  }
}

// ---------- movie feature path: MFMA instead of scalar MLP ----------
// mov_x (20000 x 1148) -> bf16 padded (20000 x 1152)
__global__ void conv_movx(const void* __restrict__ mv, __hip_bfloat16* __restrict__ out,
                          const int* __restrict__ flag){
  long idx = (long)blockIdx.x * 256 + threadIdx.x;
  if (idx >= (long)N_ITEMS_C * KPAD_C) return;
  int f32 = *flag;
  int m = (int)(idx / KPAD_C); int c = (int)(idx - (long)m * KPAD_C);
  float v = (c < 1148) ? ldf(mv, (long)m * 1148 + c, f32) : 0.f;
  out[idx] = __float2bfloat16(v);
}

// W1t (128 x 1152): row n<64 -> gW1 col n (k<20); row n>=64 -> tW1 col n-64 (20<=k<1148).
__global__ void prep_w1t(const __hip_bfloat16* __restrict__ gW1,
                         const __hip_bfloat16* __restrict__ tW1,
                         __hip_bfloat16* __restrict__ W1t){
  int idx = blockIdx.x * 256 + threadIdx.x;
  if (idx >= 128 * KPAD_C) return;
  int n = idx / KPAD_C, k = idx - n * KPAD_C;
  __hip_bfloat16 v = __float2bfloat16(0.f);
  if (n < 64) { if (k < 20) v = gW1[k * 64 + n]; }
  else       { if (k >= 20 && k < 1148) v = tW1[(k - 20) * 64 + (n - 64)]; }
  W1t[idx] = v;
}

// W2t (128 x 128) blockdiag of gW2 / tW2.
__global__ void prep_w2t(const __hip_bfloat16* __restrict__ gW2,
                         const __hip_bfloat16* __restrict__ tW2,
                         __hip_bfloat16* __restrict__ W2t){
  int idx = blockIdx.x * 256 + threadIdx.x;
  if (idx >= 128 * 128) return;
  int n = idx >> 7, k = idx & 127;
  __hip_bfloat16 v = __float2bfloat16(0.f);
  if (n < 64) { if (k < 64)  v = gW2[k * 64 + n]; }
  else        { if (k >= 64) v = tW2[(k - 64) * 64 + (n - 64)]; }
  W2t[idx] = v;
}

__global__ void prep_movie_bias(const __hip_bfloat16* __restrict__ gb1,
                                const __hip_bfloat16* __restrict__ tb1,
                                const __hip_bfloat16* __restrict__ gb2,
                                const __hip_bfloat16* __restrict__ tb2,
                                __hip_bfloat16* __restrict__ b1c,
                                __hip_bfloat16* __restrict__ b2c){
  int i = threadIdx.x;
  if (i < 64)       b1c[i] = gb1[i];
  else if (i < 128) b1c[i] = tb1[i - 64];
  else if (i < 192) b2c[i - 128] = gb2[i - 128];
  else              b2c[i - 128] = tb2[i - 192];
}

// MFMA GEMM, N=128 (8 n-tiles), M rows with guard, optional relu, bias add.
// Register-batched B loads: all 8 B-frags issued before MFMAs -> 1 vmcnt wait per k-step.
__global__ __launch_bounds__(256) void movie_gemm(
    const __hip_bfloat16* __restrict__ A, int lda, int M,
    const __hip_bfloat16* __restrict__ Bt, int K,
    const __hip_bfloat16* __restrict__ bias, int do_relu,
    __hip_bfloat16* __restrict__ out, int ldo, int ocol){
  int wave = threadIdx.x >> 6;
  int lane = threadIdx.x & 63;
  int l15 = lane & 15;
  int quad = lane >> 4;
  int rowbase = blockIdx.x * 64 + wave * 16;
  int ar = rowbase + l15; if (ar >= M) ar = M - 1;
  ffrag acc[8];
#pragma unroll
  for (int i = 0; i < 8; i++) acc[i] = (ffrag){0.f, 0.f, 0.f, 0.f};
  const short* As = (const short*)A;
  const short* Bs = (const short*)Bt;
  long arow = (long)ar * lda;
  long brow = (long)l15 * K;
  for (int k0 = 0; k0 < K; k0 += 32) {
    int koff = k0 + quad * 8;
    bfrag af = *(const bfrag*)(As + arow + koff);
    bfrag bfs[8];
#pragma unroll
    for (int nt = 0; nt < 8; nt++)
      bfs[nt] = *(const bfrag*)(Bs + brow + (long)nt * 16 * K + koff);
#pragma unroll
    for (int nt = 0; nt < 8; nt++)
      acc[nt] = __builtin_amdgcn_mfma_f32_16x16x32_bf16(af, bfs[nt], acc[nt], 0, 0, 0);
  }
#pragma unroll
  for (int reg = 0; reg < 4; reg++) {
    int grow = rowbase + quad * 4 + reg;
    if (grow >= M) continue;
#pragma unroll
    for (int nt = 0; nt < 8; nt++) {
      float v = acc[nt][reg] + __bfloat162float(bias[nt * 16 + l15]);
      if (do_relu) v = fmaxf(v, 0.f);
      out[(long)grow * ldo + ocol + nt * 16 + l15] = __float2bfloat16(v);
    }
  }
}

// MFMA GEMM: A (M x K bf16) @ Bt^T -> Hout (M x 256 bf16) + als/ald (f32, M x natt).
// Register-batched B loads: all 17 B-frags issued before MFMAs -> 1 vmcnt wait per k-step
// instead of 17 serialized L2 round-trips (VGPR 72 -> ~150, worth it: latency-bound).
__global__ __launch_bounds__(256) void gemm_fused(
    const __hip_bfloat16* __restrict__ A, const __hip_bfloat16* __restrict__ Bt,
    __hip_bfloat16* __restrict__ Hout, float* __restrict__ als, float* __restrict__ ald,
    int K, int natt){
  int wave = threadIdx.x >> 6;
  int lane = threadIdx.x & 63;
  int l15 = lane & 15;
  int quad = lane >> 4;
  int rowbase = blockIdx.x * 64 + wave * 16;
  ffrag acc[17];
#pragma unroll
  for (int i = 0; i < 17; i++) acc[i] = (ffrag){0.f, 0.f, 0.f, 0.f};
  const short* As = (const short*)A;
  const short* Bs = (const short*)Bt;
  long arow = (long)(rowbase + l15) * K;
  long brow = (long)l15 * K;
  for (int k0 = 0; k0 < K; k0 += 32) {
    int koff = k0 + quad * 8;
    bfrag af = *(const bfrag*)(As + arow + koff);
    bfrag bfs[17];
#pragma unroll
    for (int nt = 0; nt < 17; nt++)
      bfs[nt] = *(const bfrag*)(Bs + brow + (long)nt * 16 * K + koff);
#pragma unroll
    for (int nt = 0; nt < 17; nt++)
      acc[nt] = __builtin_amdgcn_mfma_f32_16x16x32_bf16(af, bfs[nt], acc[nt], 0, 0, 0);
  }
  int col = l15;
#pragma unroll
  for (int reg = 0; reg < 4; reg++) {
    int grow = rowbase + quad * 4 + reg;
    long obase = (long)grow * 256;
#pragma unroll
    for (int nt = 0; nt < 16; nt++)
      Hout[obase + nt * 16 + col] = __float2bfloat16(acc[nt][reg]);
    float v = acc[16][reg];
    if (col < natt) als[grow * natt + col] = v;
    else if (col < 2 * natt) ald[grow * natt + (col - natt)] = v;
  }
}

// ---------- CSR build (in-edges per dst) ----------
__global__ void zero_deg(int* __restrict__ deg){
  int i = blockIdx.x * 256 + threadIdx.x;
  if (i < N_NODES_C) deg[i] = 0;
}

__global__ void deg_count(const int* __restrict__ ei, int* __restrict__ deg){
  int e = blockIdx.x * 256 + threadIdx.x;
  if (e >= E_TOT_C) return;
  int dst = ei[E_TOT_C + e];
  if (dst >= 0 && dst < N_NODES_C) atomicAdd(&deg[dst], 1);
}

// Hierarchical exclusive scan of deg -> ptrn.
// Stage 1: per-block (256-wide) sums.
__global__ __launch_bounds__(256) void deg_bsum(const int* __restrict__ deg,
                                                int* __restrict__ bsum){
  int i = blockIdx.x * 256 + threadIdx.x;
  int v = (i < N_NODES_C) ? deg[i] : 0;
#pragma unroll
  for (int o = 32; o > 0; o >>= 1) v += __shfl_down(v, o, 64);
  __shared__ int ws[4];
  int wave = threadIdx.x >> 6, lane = threadIdx.x & 63;
  if (lane == 0) ws[wave] = v;
  __syncthreads();
  if (threadIdx.x == 0) bsum[blockIdx.x] = ws[0] + ws[1] + ws[2] + ws[3];
}

// Stage 2: single-block Hillis-Steele scan of 469 block sums -> exclusive offsets.
__global__ __launch_bounds__(512) void bsum_scan(int* __restrict__ bsum,
                                                 int* __restrict__ ptrn){
  __shared__ int sm[512];
  int t = threadIdx.x;
  int v = (t < NB_SCAN) ? bsum[t] : 0;
  sm[t] = v;
  __syncthreads();
  for (int o = 1; o < 512; o <<= 1) {
    int add = (t >= o) ? sm[t - o] : 0;
    __syncthreads();
    sm[t] += add;
    __syncthreads();
  }
  int excl = (t == 0) ? 0 : sm[t - 1];
  if (t < NB_SCAN) bsum[t] = excl;
  if (t == NB_SCAN - 1) ptrn[N_NODES_C] = sm[t];
}

// Stage 3: in-block exclusive scan + block offset -> ptrn.
__global__ __launch_bounds__(256) void deg_scan_final(const int* __restrict__ deg,
                                                      const int* __restrict__ bexcl,
                                                      int* __restrict__ ptrn){
  __shared__ int sm[256];
  int i = blockIdx.x * 256 + threadIdx.x;
  int t = threadIdx.x;
  int v = (i < N_NODES_C) ? deg[i] : 0;
  sm[t] = v;
  __syncthreads();
  for (int o = 1; o < 256; o <<= 1) {
    int add = (t >= o) ? sm[t - o] : 0;
    __syncthreads();
    sm[t] += add;
    __syncthreads();
  }
  int excl = (t == 0) ? 0 : sm[t - 1];
  if (i < N_NODES_C) ptrn[i] = bexcl[blockIdx.x] + excl;
}

__global__ void scatter_edges(const int* __restrict__ ei, const int* __restrict__ ptrn,
                              int* __restrict__ cursor, int* __restrict__ elist_src){
  int e = blockIdx.x * 256 + threadIdx.x;
  if (e >= E_TOT_C) return;
  int dst = ei[E_TOT_C + e];
  if (dst < 0 || dst >= N_NODES_C) return;
  int pos = atomicAdd(&cursor[dst], 1);
  elist_src[ptrn[dst] + pos] = ei[e];
}

// ---------- layer 1: per-node softmax aggregation (8 heads) + bias + elu ----------
__global__ __launch_bounds__(256) void aggregate1(
    const int* __restrict__ ptrn, const int* __restrict__ elist_src,
    const float* __restrict__ als, const float* __restrict__ ald,
    const __hip_bfloat16* __restrict__ hs, const __hip_bfloat16* __restrict__ bias,
    __hip_bfloat16* __restrict__ h1){
  int node = blockIdx.x * 4 + (threadIdx.x >> 6);
  if (node >= N_NODES_C) return;
  int lane = threadIdx.x & 63;
  int c0 = lane * 4;
  int h = lane >> 3;
  int beg = ptrn[node], end = ptrn[node + 1];
  float aldv = sane(ald[node * 8 + h]);
  float mx = -1e30f;
  for (int i = beg; i < end; i++) {
    int src = elist_src[i]; src = src < 0 ? 0 : (src >= N_NODES_C ? N_NODES_C - 1 : src);
    float ev = sane(als[src * 8 + h]) + aldv;
    ev = ev > 0.f ? ev : NEG_C * ev;
    mx = fmaxf(mx, ev);
  }
  float wsum = 0.f, a0 = 0.f, a1 = 0.f, a2 = 0.f, a3 = 0.f;
  for (int i = beg; i < end; i++) {
    int src = elist_src[i]; src = src < 0 ? 0 : (src >= N_NODES_C ? N_NODES_C - 1 : src);
    float ev = sane(als[src * 8 + h]) + aldv;
    ev = ev > 0.f ? ev : NEG_C * ev;
    float w = __expf(ev - mx);
    wsum += w;
    ushort4 hv = *(const ushort4*)((const unsigned short*)hs + (long)src * 256 + c0);
    a0 += w * bf2f(hv.x); a1 += w * bf2f(hv.y);
    a2 += w * bf2f(hv.z); a3 += w * bf2f(hv.w);
  }
  float inv = 1.f / (wsum + 1e-16f);
  float v0 = a0 * inv + __bfloat162float(bias[c0 + 0]);
  float v1 = a1 * inv + __bfloat162float(bias[c0 + 1]);
  float v2 = a2 * inv + __bfloat162float(bias[c0 + 2]);
  float v3 = a3 * inv + __bfloat162float(bias[c0 + 3]);
  v0 = v0 > 0.f ? v0 : (__expf(v0) - 1.f);
  v1 = v1 > 0.f ? v1 : (__expf(v1) - 1.f);
  v2 = v2 > 0.f ? v2 : (__expf(v2) - 1.f);
  v3 = v3 > 0.f ? v3 : (__expf(v3) - 1.f);
  v0 = fminf(fmaxf(v0, -CLAMP_C), CLAMP_C);
  v1 = fminf(fmaxf(v1, -CLAMP_C), CLAMP_C);
  v2 = fminf(fmaxf(v2, -CLAMP_C), CLAMP_C);
  v3 = fminf(fmaxf(v3, -CLAMP_C), CLAMP_C);
  long ob = (long)node * 256 + c0;
  h1[ob + 0] = __float2bfloat16(v0); h1[ob + 1] = __float2bfloat16(v1);
  h1[ob + 2] = __float2bfloat16(v2); h1[ob + 3] = __float2bfloat16(v3);
}

// ---------- layer 2: 1 head, no activation. OUTPUT IS FLOAT32. ----------
__global__ __launch_bounds__(256) void aggregate2(
    const int* __restrict__ ptrn, const int* __restrict__ elist_src,
    const float* __restrict__ als, const float* __restrict__ ald,
    const __hip_bfloat16* __restrict__ hs, const __hip_bfloat16* __restrict__ bias,
    float* __restrict__ out){
  int node = blockIdx.x * 4 + (threadIdx.x >> 6);
  if (node >= N_NODES_C) return;
  int lane = threadIdx.x & 63;
  int c0 = lane * 4;
  int beg = ptrn[node], end = ptrn[node + 1];
  float aldv = sane(ald[node]);
  float mx = -1e30f;
  for (int i = beg; i < end; i++) {
    int src = elist_src[i]; src = src < 0 ? 0 : (src >= N_NODES_C ? N_NODES_C - 1 : src);
    float ev = sane(als[src]) + aldv;
    ev = ev > 0.f ? ev : NEG_C * ev;
    mx = fmaxf(mx, ev);
  }
  float wsum = 0.f, a0 = 0.f, a1 = 0.f, a2 = 0.f, a3 = 0.f;
  for (int i = beg; i < end; i++) {
    int src = elist_src[i]; src = src < 0 ? 0 : (src >= N_NODES_C ? N_NODES_C - 1 : src);
    float ev = sane(als[src]) + aldv;
    ev = ev > 0.f ? ev : NEG_C * ev;
    float w = __expf(ev - mx);
    wsum += w;
    ushort4 hv = *(const ushort4*)((const unsigned short*)hs + (long)src * 256 + c0);
    a0 += w * bf2f(hv.x); a1 += w * bf2f(hv.y);
    a2 += w * bf2f(hv.z); a3 += w * bf2f(hv.w);
  }
  float inv = 1.f / (wsum + 1e-16f);
  float4 v;
  v.x = a0 * inv + __bfloat162float(bias[c0 + 0]);
  v.y = a1 * inv + __bfloat162float(bias[c0 + 1]);
  v.z = a2 * inv + __bfloat162float(bias[c0 + 2]);
  v.w = a3 * inv + __bfloat162float(bias[c0 + 3]);
  v.x = fminf(fmaxf(v.x, -CLAMP_C), CLAMP_C);
  v.y = fminf(fmaxf(v.y, -CLAMP_C), CLAMP_C);
  v.z = fminf(fmaxf(v.z, -CLAMP_C), CLAMP_C);
  v.w = fminf(fmaxf(v.w, -CLAMP_C), CLAMP_C);
  *(float4*)(out + (long)node * 256 + c0) = v;
}

__global__ void write_tail(float* __restrict__ out, int out_size){
  if (threadIdx.x == 0 && blockIdx.x == 0) {
    out[out_size - 3] = 0.f;
    out[out_size - 2] = (float)N_USERS_C;
    out[out_size - 1] = (float)N_NODES_C;
  }
}

extern "C" void kernel_launch(void* const* d_in, const int* in_sizes, int n_in,
                              void* d_out, int out_size, void* d_ws, size_t ws_size,
                              hipStream_t stream) {
  const void* mov_x    = d_in[2];
  const int*  ei       = (const int*)d_in[3];
  const void* user_emb = d_in[4];
  const void* item_emb = d_in[5];

  char* ws = (char*)d_ws;
  size_t off = 0;
  auto alloc = [&](size_t bytes) -> void* {
    void* p = ws + off; off += (bytes + 255) / 256 * 256; return p;
  };
  int* flag   = (int*)alloc(4);
  __hip_bfloat16* arena = (__hip_bfloat16*)alloc(312832 * 2);
  __hip_bfloat16* Bt1 = (__hip_bfloat16*)alloc(272 * 192 * 2);
  __hip_bfloat16* Bt2 = (__hip_bfloat16*)alloc(272 * 256 * 2);
  __hip_bfloat16* W1t = (__hip_bfloat16*)alloc(128 * KPAD_C * 2);
  __hip_bfloat16* W2t = (__hip_bfloat16*)alloc(128 * 128 * 2);
  __hip_bfloat16* b1c = (__hip_bfloat16*)alloc(128 * 2);
  __hip_bfloat16* b2c = (__hip_bfloat16*)alloc(128 * 2);
  int* ptrn   = (int*)alloc((N_NODES_C + 1) * 4);
  int* deg    = (int*)alloc(N_NODES_C * 4);
  int* bsum   = (int*)alloc(512 * 4);
  int* elist  = (int*)alloc(E_TOT_C * 4);
  float* als  = (float*)alloc((size_t)N_NODES_C * 8 * 4);
  float* ald  = (float*)alloc((size_t)N_NODES_C * 8 * 4);
  __hip_bfloat16* x  = (__hip_bfloat16*)alloc((size_t)N_NODES_C * D_IN_C * 2); // 46.08 MB
  __hip_bfloat16* hs = (__hip_bfloat16*)alloc((size_t)N_NODES_C * HID_C * 2);  // 61.44 MB
  // d_out (f32, 122.88 MB) hosts two dead-before-aggregate2 temporaries:
  //   h1 (bf16 61.44 MB) at byte 0; mov_bf (bf16 46.08 MB) at byte 61,440,000.
  __hip_bfloat16* h1     = (__hip_bfloat16*)d_out;
  __hip_bfloat16* mov_bf = (__hip_bfloat16*)((char*)d_out + 61440000);
  __hip_bfloat16* hid    = hs;  // movie hidden (20000x128) parks in hs

  const int oWs1=0, oWd1=49152, oas1=98304, oad1=98560, ob1=98816,
            oWs2=99072, oWd2=164608, oas2=230144, oad2=230400, ob2=230656,
            ogW1=230912, ogb1=232192, ogW2=232256, ogb2=236352,
            otW1=236416, otb1=308608, otW2=308672, otb2=312768;

  detect_dtype<<<1, 256, 0, stream>>>((const unsigned short*)user_emb, flag);

  ConvArgs ca;
  const int srcidx[NCONV] = {14,15,16,17,18,19,20,21,22,23,6,7,8,9,10,11,12,13};
  const int offs[NCONV]   = {oWs1,oWd1,oas1,oad1,ob1,oWs2,oWd2,oas2,oad2,ob2,
                             ogW1,ogb1,ogW2,ogb2,otW1,otb1,otW2,otb2};
  const int ns[NCONV]     = {49152,49152,256,256,256,65536,65536,256,256,256,
                             1280,64,4096,64,72192,64,4096,64};
  for (int i = 0; i < NCONV; i++) { ca.src[i] = d_in[srcidx[i]]; ca.n[i] = ns[i]; ca.off[i] = offs[i]; }
  conv_small<<<NCONV * 8, 256, 0, stream>>>(ca, arena, flag);

  // movie feature path (MFMA)
  conv_movx<<<(int)(((long)N_ITEMS_C * KPAD_C + 255) / 256), 256, 0, stream>>>(
      mov_x, mov_bf, flag);
  prep_w1t<<<(128 * KPAD_C + 255) / 256, 256, 0, stream>>>(arena + ogW1, arena + otW1, W1t);
  prep_w2t<<<(128 * 128 + 255) / 256, 256, 0, stream>>>(arena + ogW2, arena + otW2, W2t);
  prep_movie_bias<<<1, 256, 0, stream>>>(arena + ogb1, arena + otb1,
                                         arena + ogb2, arena + otb2, b1c, b2c);
  assemble_x<<<(int)(((long)N_NODES_C * D_IN_C + 255) / 256), 256, 0, stream>>>(
      user_emb, item_emb, x, flag);
  movie_gemm<<<(N_ITEMS_C + 63) / 64, 256, 0, stream>>>(
      mov_bf, KPAD_C, N_ITEMS_C, W1t, KPAD_C, b1c, 1, hid, 128, 0);
  movie_gemm<<<(N_ITEMS_C + 63) / 64, 256, 0, stream>>>(
      hid, 128, N_ITEMS_C, W2t, 128, b2c, 0,
      x + (long)N_USERS_C * D_IN_C, D_IN_C, 64);

  prep_bt<<<(272 * 192 + 255) / 256, 256, 0, stream>>>(
      arena + oWs1, arena + oWd1, arena + oas1, arena + oad1, Bt1, 192, 8, 32);
  prep_bt<<<(272 * 256 + 255) / 256, 256, 0, stream>>>(
      arena + oWs2, arena + oWd2, arena + oas2, arena + oad2, Bt2, 256, 1, 256);

  // CSR of in-edges
  zero_deg<<<(N_NODES_C + 255) / 256, 256, 0, stream>>>(deg);
  deg_count<<<(E_TOT_C + 255) / 256, 256, 0, stream>>>(ei, deg);
  deg_bsum<<<NB_SCAN, 256, 0, stream>>>(deg, bsum);
  bsum_scan<<<1, 512, 0, stream>>>(bsum, ptrn);
  deg_scan_final<<<NB_SCAN, 256, 0, stream>>>(deg, bsum, ptrn);
  zero_deg<<<(N_NODES_C + 255) / 256, 256, 0, stream>>>(deg);
  scatter_edges<<<(E_TOT_C + 255) / 256, 256, 0, stream>>>(ei, ptrn, deg, elist);

  // layer 1
  gemm_fused<<<N_NODES_C / 64, 256, 0, stream>>>(x, Bt1, hs, als, ald, 192, 8);
  aggregate1<<<N_NODES_C / 4, 256, 0, stream>>>(ptrn, elist, als, ald, hs, arena + ob1, h1);

  // layer 2
  gemm_fused<<<N_NODES_C / 64, 256, 0, stream>>>(h1, Bt2, hs, als, ald, 256, 1);
  aggregate2<<<N_NODES_C / 4, 256, 0, stream>>>(ptrn, elist, als, ald, hs, arena + ob2,
                                                (float*)d_out);
  write_tail<<<1, 64, 0, stream>>>((float*)d_out, out_size);
}

// Round 4
// 748.066 us; speedup vs baseline: 1.5983x; 1.2373x over previous
//
#include <hip/hip_runtime.h>
#include <hip/hip_bf16.h>

#define N_USERS_C 100000
#define N_ITEMS_C 20000
#define N_NODES_C 120000
#define E_TOT_C   400000
#define D_IN_C    192
#define HID_C     256
#define NEG_C     0.2f
#define CLAMP_C   1000.0f
#define KPAD_C    1152   // 1148 padded to multiple of 32
#define NB_SCAN   ((N_NODES_C + 255) / 256)   // 469 scan blocks
#define ROWE      40     // LDS row length in shorts: 32 k-elems + 8 pad (80B, 16B-aligned)

typedef __attribute__((ext_vector_type(8))) short bfrag;
typedef __attribute__((ext_vector_type(4))) float ffrag;

__device__ __forceinline__ float bf2f(unsigned short u){
  return __uint_as_float(((unsigned)u) << 16);
}
__device__ __forceinline__ float ldf(const void* p, long i, int isf32){
  return isf32 ? ((const float*)p)[i] : bf2f(((const unsigned short*)p)[i]);
}
__device__ __forceinline__ float sane(float v){
  return (v > -1e30f && v < 1e30f) ? v : 0.f;
}

// ---------- dtype discriminator (inputs) ----------
__global__ __launch_bounds__(256) void detect_dtype(const unsigned short* __restrict__ ue,
                                                    int* __restrict__ flag){
  __shared__ int cnt[256];
  int tid = threadIdx.x; int c = 0;
  for (int i = tid; i < 8192; i += 256){
    unsigned e = (ue[i] >> 7) & 0xFFu;
    if (e >= 129u) c++;
  }
  cnt[tid] = c; __syncthreads();
  if (tid == 0){
    int s = 0;
    for (int i = 0; i < 256; i++) s += cnt[i];
    *flag = (s > 100) ? 1 : 0;
  }
}

// ---------- convert small weight tensors into a bf16 arena ----------
#define NCONV 18
struct ConvArgs { const void* src[NCONV]; int n[NCONV]; int off[NCONV]; };

// grid = NCONV * 8 blocks; block handles tensor (b>>3), slice (b&7).
__global__ __launch_bounds__(256) void conv_small(ConvArgs a, __hip_bfloat16* __restrict__ arena,
                                                  const int* __restrict__ flag){
  int t = blockIdx.x >> 3, sub = blockIdx.x & 7;
  int f32 = *flag;
  const void* s = a.src[t];
  int n = a.n[t], off = a.off[t];
  for (int i = sub * 256 + threadIdx.x; i < n; i += 2048)
    arena[off + i] = __float2bfloat16(ldf(s, i, f32));
}

// Bt (272 x K): rows 0..255 = W^T; 256..256+H-1 = fold(Ws,a_s); next H = fold(Wd,a_d); rest 0.
__global__ void prep_bt(const __hip_bfloat16* __restrict__ Ws,
                        const __hip_bfloat16* __restrict__ Wd,
                        const __hip_bfloat16* __restrict__ as_,
                        const __hip_bfloat16* __restrict__ ad_,
                        __hip_bfloat16* __restrict__ Bt, int K, int H, int C){
  int idx = blockIdx.x * 256 + threadIdx.x;
  if (idx >= 272 * K) return;
  int col = idx / K, k = idx - col * K;
  float v;
  if (col < 256) {
    v = __bfloat162float(Ws[k * 256 + col]);
  } else if (col < 256 + H) {
    int h = col - 256; float s = 0.f;
    for (int c = 0; c < C; c++)
      s += __bfloat162float(Ws[k * 256 + h * C + c]) * __bfloat162float(as_[h * C + c]);
    v = s;
  } else if (col < 256 + 2 * H) {
    int h = col - 256 - H; float s = 0.f;
    for (int c = 0; c < C; c++)
      s += __bfloat162float(Wd[k * 256 + h * C + c]) * __bfloat162float(ad_[h * C + c]);
    v = s;
  } else v = 0.f;
  Bt[(long)col * K + k] = __float2bfloat16(v);
}

// x: (120000 x 192) bf16. Users: emb | zeros. Movies: item_emb cols 0..63.
__global__ void assemble_x(const void* __restrict__ ue, const void* __restrict__ ie,
                           __hip_bfloat16* __restrict__ x, const int* __restrict__ flag){
  long idx = (long)blockIdx.x * 256 + threadIdx.x;
  if (idx >= (long)N_NODES_C * D_IN_C) return;
  int f32 = *flag;
  int n = (int)(idx / D_IN_C); int c = (int)(idx - (long)n * D_IN_C);
  if (n < N_USERS_C) {
    x[idx] = __float2bfloat16((c < 64) ? ldf(ue, (long)n * 64 + c, f32) : 0.f);
  } else if (c < 64) {
    x[idx] = __float2bfloat16(ldf(ie, (long)(n - N_USERS_C) * 64 + c, f32));
  }
}

// ---------- movie feature path: MFMA instead of scalar MLP ----------
// mov_x (20000 x 1148) -> bf16 padded (20000 x 1152)
__global__ void conv_movx(const void* __restrict__ mv, __hip_bfloat16* __restrict__ out,
                          const int* __restrict__ flag){
  long idx = (long)blockIdx.x * 256 + threadIdx.x;
  if (idx >= (long)N_ITEMS_C * KPAD_C) return;
  int f32 = *flag;
  int m = (int)(idx / KPAD_C); int c = (int)(idx - (long)m * KPAD_C);
  float v = (c < 1148) ? ldf(mv, (long)m * 1148 + c, f32) : 0.f;
  out[idx] = __float2bfloat16(v);
}

// W1t (128 x 1152): row n<64 -> gW1 col n (k<20); row n>=64 -> tW1 col n-64 (20<=k<1148).
__global__ void prep_w1t(const __hip_bfloat16* __restrict__ gW1,
                         const __hip_bfloat16* __restrict__ tW1,
                         __hip_bfloat16* __restrict__ W1t){
  int idx = blockIdx.x * 256 + threadIdx.x;
  if (idx >= 128 * KPAD_C) return;
  int n = idx / KPAD_C, k = idx - n * KPAD_C;
  __hip_bfloat16 v = __float2bfloat16(0.f);
  if (n < 64) { if (k < 20) v = gW1[k * 64 + n]; }
  else       { if (k >= 20 && k < 1148) v = tW1[(k - 20) * 64 + (n - 64)]; }
  W1t[idx] = v;
}

// W2t (128 x 128) blockdiag of gW2 / tW2.
__global__ void prep_w2t(const __hip_bfloat16* __restrict__ gW2,
                         const __hip_bfloat16* __restrict__ tW2,
                         __hip_bfloat16* __restrict__ W2t){
  int idx = blockIdx.x * 256 + threadIdx.x;
  if (idx >= 128 * 128) return;
  int n = idx >> 7, k = idx & 127;
  __hip_bfloat16 v = __float2bfloat16(0.f);
  if (n < 64) { if (k < 64)  v = gW2[k * 64 + n]; }
  else        { if (k >= 64) v = tW2[(k - 64) * 64 + (n - 64)]; }
  W2t[idx] = v;
}

__global__ void prep_movie_bias(const __hip_bfloat16* __restrict__ gb1,
                                const __hip_bfloat16* __restrict__ tb1,
                                const __hip_bfloat16* __restrict__ gb2,
                                const __hip_bfloat16* __restrict__ tb2,
                                __hip_bfloat16* __restrict__ b1c,
                                __hip_bfloat16* __restrict__ b2c){
  int i = threadIdx.x;
  if (i < 64)       b1c[i] = gb1[i];
  else if (i < 128) b1c[i] = tb1[i - 64];
  else if (i < 192) b2c[i - 128] = gb2[i - 128];
  else              b2c[i - 128] = tb2[i - 192];
}

// MFMA GEMM, N=128 (8 n-tiles), M rows with guard, optional relu, bias add.
// LDS-staged A and B tiles per k-step: B shared across all 4 waves (4x line-traffic cut),
// staging loads wave-coalesced 16B chunks.
__global__ __launch_bounds__(256) void movie_gemm(
    const __hip_bfloat16* __restrict__ A, int lda, int M,
    const __hip_bfloat16* __restrict__ Bt, int K,
    const __hip_bfloat16* __restrict__ bias, int do_relu,
    __hip_bfloat16* __restrict__ out, int ldo, int ocol){
  __shared__ short Bls[128 * ROWE];   // 10.0 KB
  __shared__ short Als[64 * ROWE];    //  5.0 KB
  int tid = threadIdx.x;
  int wave = tid >> 6;
  int lane = tid & 63;
  int l15 = lane & 15;
  int quad = lane >> 4;
  int rowbase_blk = blockIdx.x * 64;
  int rowbase = rowbase_blk + wave * 16;
  ffrag acc[8];
#pragma unroll
  for (int i = 0; i < 8; i++) acc[i] = (ffrag){0.f, 0.f, 0.f, 0.f};
  const short* As = (const short*)A;
  const short* Bs = (const short*)Bt;
  int sr = tid >> 2, sc = tid & 3;              // A-staging: row sr in [0,64), 16B chunk sc
  int arow_st = rowbase_blk + sr; if (arow_st >= M) arow_st = M - 1;
  for (int k0 = 0; k0 < K; k0 += 32) {
    __syncthreads();   // previous iter's LDS reads done before overwrite
    // stage B: 128 rows x 4 chunks = 512 tasks
    for (int t = tid; t < 512; t += 256) {
      int r = t >> 2, c = t & 3;
      *(float4*)(&Bls[r * ROWE + c * 8]) = *(const float4*)(Bs + (long)r * K + k0 + c * 8);
    }
    // stage A: 64 rows x 4 chunks = 256 tasks (one per thread)
    *(float4*)(&Als[sr * ROWE + sc * 8]) =
        *(const float4*)(As + (long)arow_st * lda + k0 + sc * 8);
    __syncthreads();
    int koff = quad * 8;
    bfrag af = *(const bfrag*)(&Als[(wave * 16 + l15) * ROWE + koff]);
#pragma unroll
    for (int nt = 0; nt < 8; nt++) {
      bfrag bf = *(const bfrag*)(&Bls[(nt * 16 + l15) * ROWE + koff]);
      acc[nt] = __builtin_amdgcn_mfma_f32_16x16x32_bf16(af, bf, acc[nt], 0, 0, 0);
    }
  }
#pragma unroll
  for (int reg = 0; reg < 4; reg++) {
    int grow = rowbase + quad * 4 + reg;
    if (grow >= M) continue;
#pragma unroll
    for (int nt = 0; nt < 8; nt++) {
      float v = acc[nt][reg] + __bfloat162float(bias[nt * 16 + l15]);
      if (do_relu) v = fmaxf(v, 0.f);
      out[(long)grow * ldo + ocol + nt * 16 + l15] = __float2bfloat16(v);
    }
  }
}

// MFMA GEMM: A (M x K bf16) @ Bt^T -> Hout (M x 256 bf16) + als/ald (f32, M x natt).
// LDS-staged A and B per k-step; B (272 rows) shared by all 4 waves instead of each wave
// gathering the full Bt from L1/L2 (16 discontiguous lines per load was the bottleneck).
__global__ __launch_bounds__(256) void gemm_fused(
    const __hip_bfloat16* __restrict__ A, const __hip_bfloat16* __restrict__ Bt,
    __hip_bfloat16* __restrict__ Hout, float* __restrict__ als, float* __restrict__ ald,
    int K, int natt){
  __shared__ short Bls[272 * ROWE];   // 21.25 KB
  __shared__ short Als[64 * ROWE];    //  5.0 KB
  int tid = threadIdx.x;
  int wave = tid >> 6;
  int lane = tid & 63;
  int l15 = lane & 15;
  int quad = lane >> 4;
  int rowbase_blk = blockIdx.x * 64;
  int rowbase = rowbase_blk + wave * 16;
  ffrag acc[17];
#pragma unroll
  for (int i = 0; i < 17; i++) acc[i] = (ffrag){0.f, 0.f, 0.f, 0.f};
  const short* As = (const short*)A;
  const short* Bs = (const short*)Bt;
  int sr = tid >> 2, sc = tid & 3;   // A-staging row/chunk
  for (int k0 = 0; k0 < K; k0 += 32) {
    __syncthreads();
    // stage B: 272 rows x 4 chunks = 1088 tasks
    for (int t = tid; t < 1088; t += 256) {
      int r = t >> 2, c = t & 3;
      *(float4*)(&Bls[r * ROWE + c * 8]) = *(const float4*)(Bs + (long)r * K + k0 + c * 8);
    }
    // stage A: 64 rows x 4 chunks (grid is exact: rowbase_blk+63 < 120000)
    *(float4*)(&Als[sr * ROWE + sc * 8]) =
        *(const float4*)(As + (long)(rowbase_blk + sr) * K + k0 + sc * 8);
    __syncthreads();
    int koff = quad * 8;
    bfrag af = *(const bfrag*)(&Als[(wave * 16 + l15) * ROWE + koff]);
#pragma unroll
    for (int nt = 0; nt < 17; nt++) {
      bfrag bf = *(const bfrag*)(&Bls[(nt * 16 + l15) * ROWE + koff]);
      acc[nt] = __builtin_amdgcn_mfma_f32_16x16x32_bf16(af, bf, acc[nt], 0, 0, 0);
    }
  }
  int col = l15;
#pragma unroll
  for (int reg = 0; reg < 4; reg++) {
    int grow = rowbase + quad * 4 + reg;
    long obase = (long)grow * 256;
#pragma unroll
    for (int nt = 0; nt < 16; nt++)
      Hout[obase + nt * 16 + col] = __float2bfloat16(acc[nt][reg]);
    float v = acc[16][reg];
    if (col < natt) als[grow * natt + col] = v;
    else if (col < 2 * natt) ald[grow * natt + (col - natt)] = v;
  }
}

// ---------- CSR build (in-edges per dst) ----------
__global__ void zero_deg(int* __restrict__ deg){
  int i = blockIdx.x * 256 + threadIdx.x;
  if (i < N_NODES_C) deg[i] = 0;
}

__global__ void deg_count(const int* __restrict__ ei, int* __restrict__ deg){
  int e = blockIdx.x * 256 + threadIdx.x;
  if (e >= E_TOT_C) return;
  int dst = ei[E_TOT_C + e];
  if (dst >= 0 && dst < N_NODES_C) atomicAdd(&deg[dst], 1);
}

// Hierarchical exclusive scan of deg -> ptrn.
// Stage 1: per-block (256-wide) sums.
__global__ __launch_bounds__(256) void deg_bsum(const int* __restrict__ deg,
                                                int* __restrict__ bsum){
  int i = blockIdx.x * 256 + threadIdx.x;
  int v = (i < N_NODES_C) ? deg[i] : 0;
#pragma unroll
  for (int o = 32; o > 0; o >>= 1) v += __shfl_down(v, o, 64);
  __shared__ int ws[4];
  int wave = threadIdx.x >> 6, lane = threadIdx.x & 63;
  if (lane == 0) ws[wave] = v;
  __syncthreads();
  if (threadIdx.x == 0) bsum[blockIdx.x] = ws[0] + ws[1] + ws[2] + ws[3];
}

// Stage 2: single-block Hillis-Steele scan of 469 block sums -> exclusive offsets.
__global__ __launch_bounds__(512) void bsum_scan(int* __restrict__ bsum,
                                                 int* __restrict__ ptrn){
  __shared__ int sm[512];
  int t = threadIdx.x;
  int v = (t < NB_SCAN) ? bsum[t] : 0;
  sm[t] = v;
  __syncthreads();
  for (int o = 1; o < 512; o <<= 1) {
    int add = (t >= o) ? sm[t - o] : 0;
    __syncthreads();
    sm[t] += add;
    __syncthreads();
  }
  int excl = (t == 0) ? 0 : sm[t - 1];
  if (t < NB_SCAN) bsum[t] = excl;
  if (t == NB_SCAN - 1) ptrn[N_NODES_C] = sm[t];
}

// Stage 3: in-block exclusive scan + block offset -> ptrn.
__global__ __launch_bounds__(256) void deg_scan_final(const int* __restrict__ deg,
                                                      const int* __restrict__ bexcl,
                                                      int* __restrict__ ptrn){
  __shared__ int sm[256];
  int i = blockIdx.x * 256 + threadIdx.x;
  int t = threadIdx.x;
  int v = (i < N_NODES_C) ? deg[i] : 0;
  sm[t] = v;
  __syncthreads();
  for (int o = 1; o < 256; o <<= 1) {
    int add = (t >= o) ? sm[t - o] : 0;
    __syncthreads();
    sm[t] += add;
    __syncthreads();
  }
  int excl = (t == 0) ? 0 : sm[t - 1];
  if (i < N_NODES_C) ptrn[i] = bexcl[blockIdx.x] + excl;
}

__global__ void scatter_edges(const int* __restrict__ ei, const int* __restrict__ ptrn,
                              int* __restrict__ cursor, int* __restrict__ elist_src){
  int e = blockIdx.x * 256 + threadIdx.x;
  if (e >= E_TOT_C) return;
  int dst = ei[E_TOT_C + e];
  if (dst < 0 || dst >= N_NODES_C) return;
  int pos = atomicAdd(&cursor[dst], 1);
  elist_src[ptrn[dst] + pos] = ei[e];
}

// ---------- layer 1: per-node softmax aggregation (8 heads) + bias + elu ----------
__global__ __launch_bounds__(256) void aggregate1(
    const int* __restrict__ ptrn, const int* __restrict__ elist_src,
    const float* __restrict__ als, const float* __restrict__ ald,
    const __hip_bfloat16* __restrict__ hs, const __hip_bfloat16* __restrict__ bias,
    __hip_bfloat16* __restrict__ h1){
  int node = blockIdx.x * 4 + (threadIdx.x >> 6);
  if (node >= N_NODES_C) return;
  int lane = threadIdx.x & 63;
  int c0 = lane * 4;
  int h = lane >> 3;
  int beg = ptrn[node], end = ptrn[node + 1];
  float aldv = sane(ald[node * 8 + h]);
  float mx = -1e30f;
  for (int i = beg; i < end; i++) {
    int src = elist_src[i]; src = src < 0 ? 0 : (src >= N_NODES_C ? N_NODES_C - 1 : src);
    float ev = sane(als[src * 8 + h]) + aldv;
    ev = ev > 0.f ? ev : NEG_C * ev;
    mx = fmaxf(mx, ev);
  }
  float wsum = 0.f, a0 = 0.f, a1 = 0.f, a2 = 0.f, a3 = 0.f;
  for (int i = beg; i < end; i++) {
    int src = elist_src[i]; src = src < 0 ? 0 : (src >= N_NODES_C ? N_NODES_C - 1 : src);
    float ev = sane(als[src * 8 + h]) + aldv;
    ev = ev > 0.f ? ev : NEG_C * ev;
    float w = __expf(ev - mx);
    wsum += w;
    ushort4 hv = *(const ushort4*)((const unsigned short*)hs + (long)src * 256 + c0);
    a0 += w * bf2f(hv.x); a1 += w * bf2f(hv.y);
    a2 += w * bf2f(hv.z); a3 += w * bf2f(hv.w);
  }
  float inv = 1.f / (wsum + 1e-16f);
  float v0 = a0 * inv + __bfloat162float(bias[c0 + 0]);
  float v1 = a1 * inv + __bfloat162float(bias[c0 + 1]);
  float v2 = a2 * inv + __bfloat162float(bias[c0 + 2]);
  float v3 = a3 * inv + __bfloat162float(bias[c0 + 3]);
  v0 = v0 > 0.f ? v0 : (__expf(v0) - 1.f);
  v1 = v1 > 0.f ? v1 : (__expf(v1) - 1.f);
  v2 = v2 > 0.f ? v2 : (__expf(v2) - 1.f);
  v3 = v3 > 0.f ? v3 : (__expf(v3) - 1.f);
  v0 = fminf(fmaxf(v0, -CLAMP_C), CLAMP_C);
  v1 = fminf(fmaxf(v1, -CLAMP_C), CLAMP_C);
  v2 = fminf(fmaxf(v2, -CLAMP_C), CLAMP_C);
  v3 = fminf(fmaxf(v3, -CLAMP_C), CLAMP_C);
  long ob = (long)node * 256 + c0;
  h1[ob + 0] = __float2bfloat16(v0); h1[ob + 1] = __float2bfloat16(v1);
  h1[ob + 2] = __float2bfloat16(v2); h1[ob + 3] = __float2bfloat16(v3);
}

// ---------- layer 2: 1 head, no activation. OUTPUT IS FLOAT32. ----------
__global__ __launch_bounds__(256) void aggregate2(
    const int* __restrict__ ptrn, const int* __restrict__ elist_src,
    const float* __restrict__ als, const float* __restrict__ ald,
    const __hip_bfloat16* __restrict__ hs, const __hip_bfloat16* __restrict__ bias,
    float* __restrict__ out){
  int node = blockIdx.x * 4 + (threadIdx.x >> 6);
  if (node >= N_NODES_C) return;
  int lane = threadIdx.x & 63;
  int c0 = lane * 4;
  int beg = ptrn[node], end = ptrn[node + 1];
  float aldv = sane(ald[node]);
  float mx = -1e30f;
  for (int i = beg; i < end; i++) {
    int src = elist_src[i]; src = src < 0 ? 0 : (src >= N_NODES_C ? N_NODES_C - 1 : src);
    float ev = sane(als[src]) + aldv;
    ev = ev > 0.f ? ev : NEG_C * ev;
    mx = fmaxf(mx, ev);
  }
  float wsum = 0.f, a0 = 0.f, a1 = 0.f, a2 = 0.f, a3 = 0.f;
  for (int i = beg; i < end; i++) {
    int src = elist_src[i]; src = src < 0 ? 0 : (src >= N_NODES_C ? N_NODES_C - 1 : src);
    float ev = sane(als[src]) + aldv;
    ev = ev > 0.f ? ev : NEG_C * ev;
    float w = __expf(ev - mx);
    wsum += w;
    ushort4 hv = *(const ushort4*)((const unsigned short*)hs + (long)src * 256 + c0);
    a0 += w * bf2f(hv.x); a1 += w * bf2f(hv.y);
    a2 += w * bf2f(hv.z); a3 += w * bf2f(hv.w);
  }
  float inv = 1.f / (wsum + 1e-16f);
  float4 v;
  v.x = a0 * inv + __bfloat162float(bias[c0 + 0]);
  v.y = a1 * inv + __bfloat162float(bias[c0 + 1]);
  v.z = a2 * inv + __bfloat162float(bias[c0 + 2]);
  v.w = a3 * inv + __bfloat162float(bias[c0 + 3]);
  v.x = fminf(fmaxf(v.x, -CLAMP_C), CLAMP_C);
  v.y = fminf(fmaxf(v.y, -CLAMP_C), CLAMP_C);
  v.z = fminf(fmaxf(v.z, -CLAMP_C), CLAMP_C);
  v.w = fminf(fmaxf(v.w, -CLAMP_C), CLAMP_C);
  *(float4*)(out + (long)node * 256 + c0) = v;
}

__global__ void write_tail(float* __restrict__ out, int out_size){
  if (threadIdx.x == 0 && blockIdx.x == 0) {
    out[out_size - 3] = 0.f;
    out[out_size - 2] = (float)N_USERS_C;
    out[out_size - 1] = (float)N_NODES_C;
  }
}

extern "C" void kernel_launch(void* const* d_in, const int* in_sizes, int n_in,
                              void* d_out, int out_size, void* d_ws, size_t ws_size,
                              hipStream_t stream) {
  const void* mov_x    = d_in[2];
  const int*  ei       = (const int*)d_in[3];
  const void* user_emb = d_in[4];
  const void* item_emb = d_in[5];

  char* ws = (char*)d_ws;
  size_t off = 0;
  auto alloc = [&](size_t bytes) -> void* {
    void* p = ws + off; off += (bytes + 255) / 256 * 256; return p;
  };
  int* flag   = (int*)alloc(4);
  __hip_bfloat16* arena = (__hip_bfloat16*)alloc(312832 * 2);
  __hip_bfloat16* Bt1 = (__hip_bfloat16*)alloc(272 * 192 * 2);
  __hip_bfloat16* Bt2 = (__hip_bfloat16*)alloc(272 * 256 * 2);
  __hip_bfloat16* W1t = (__hip_bfloat16*)alloc(128 * KPAD_C * 2);
  __hip_bfloat16* W2t = (__hip_bfloat16*)alloc(128 * 128 * 2);
  __hip_bfloat16* b1c = (__hip_bfloat16*)alloc(128 * 2);
  __hip_bfloat16* b2c = (__hip_bfloat16*)alloc(128 * 2);
  int* ptrn   = (int*)alloc((N_NODES_C + 1) * 4);
  int* deg    = (int*)alloc(N_NODES_C * 4);
  int* bsum   = (int*)alloc(512 * 4);
  int* elist  = (int*)alloc(E_TOT_C * 4);
  float* als  = (float*)alloc((size_t)N_NODES_C * 8 * 4);
  float* ald  = (float*)alloc((size_t)N_NODES_C * 8 * 4);
  __hip_bfloat16* x  = (__hip_bfloat16*)alloc((size_t)N_NODES_C * D_IN_C * 2); // 46.08 MB
  __hip_bfloat16* hs = (__hip_bfloat16*)alloc((size_t)N_NODES_C * HID_C * 2);  // 61.44 MB
  // d_out (f32, 122.88 MB) hosts two dead-before-aggregate2 temporaries:
  //   h1 (bf16 61.44 MB) at byte 0; mov_bf (bf16 46.08 MB) at byte 61,440,000.
  __hip_bfloat16* h1     = (__hip_bfloat16*)d_out;
  __hip_bfloat16* mov_bf = (__hip_bfloat16*)((char*)d_out + 61440000);
  __hip_bfloat16* hid    = hs;  // movie hidden (20000x128) parks in hs

  const int oWs1=0, oWd1=49152, oas1=98304, oad1=98560, ob1=98816,
            oWs2=99072, oWd2=164608, oas2=230144, oad2=230400, ob2=230656,
            ogW1=230912, ogb1=232192, ogW2=232256, ogb2=236352,
            otW1=236416, otb1=308608, otW2=308672, otb2=312768;

  detect_dtype<<<1, 256, 0, stream>>>((const unsigned short*)user_emb, flag);

  ConvArgs ca;
  const int srcidx[NCONV] = {14,15,16,17,18,19,20,21,22,23,6,7,8,9,10,11,12,13};
  const int offs[NCONV]   = {oWs1,oWd1,oas1,oad1,ob1,oWs2,oWd2,oas2,oad2,ob2,
                             ogW1,ogb1,ogW2,ogb2,otW1,otb1,otW2,otb2};
  const int ns[NCONV]     = {49152,49152,256,256,256,65536,65536,256,256,256,
                             1280,64,4096,64,72192,64,4096,64};
  for (int i = 0; i < NCONV; i++) { ca.src[i] = d_in[srcidx[i]]; ca.n[i] = ns[i]; ca.off[i] = offs[i]; }
  conv_small<<<NCONV * 8, 256, 0, stream>>>(ca, arena, flag);

  // movie feature path (MFMA)
  conv_movx<<<(int)(((long)N_ITEMS_C * KPAD_C + 255) / 256), 256, 0, stream>>>(
      mov_x, mov_bf, flag);
  prep_w1t<<<(128 * KPAD_C + 255) / 256, 256, 0, stream>>>(arena + ogW1, arena + otW1, W1t);
  prep_w2t<<<(128 * 128 + 255) / 256, 256, 0, stream>>>(arena + ogW2, arena + otW2, W2t);
  prep_movie_bias<<<1, 256, 0, stream>>>(arena + ogb1, arena + otb1,
                                         arena + ogb2, arena + otb2, b1c, b2c);
  assemble_x<<<(int)(((long)N_NODES_C * D_IN_C + 255) / 256), 256, 0, stream>>>(
      user_emb, item_emb, x, flag);
  movie_gemm<<<(N_ITEMS_C + 63) / 64, 256, 0, stream>>>(
      mov_bf, KPAD_C, N_ITEMS_C, W1t, KPAD_C, b1c, 1, hid, 128, 0);
  movie_gemm<<<(N_ITEMS_C + 63) / 64, 256, 0, stream>>>(
      hid, 128, N_ITEMS_C, W2t, 128, b2c, 0,
      x + (long)N_USERS_C * D_IN_C, D_IN_C, 64);

  prep_bt<<<(272 * 192 + 255) / 256, 256, 0, stream>>>(
      arena + oWs1, arena + oWd1, arena + oas1, arena + oad1, Bt1, 192, 8, 32);
  prep_bt<<<(272 * 256 + 255) / 256, 256, 0, stream>>>(
      arena + oWs2, arena + oWd2, arena + oas2, arena + oad2, Bt2, 256, 1, 256);

  // CSR of in-edges
  zero_deg<<<(N_NODES_C + 255) / 256, 256, 0, stream>>>(deg);
  deg_count<<<(E_TOT_C + 255) / 256, 256, 0, stream>>>(ei, deg);
  deg_bsum<<<NB_SCAN, 256, 0, stream>>>(deg, bsum);
  bsum_scan<<<1, 512, 0, stream>>>(bsum, ptrn);
  deg_scan_final<<<NB_SCAN, 256, 0, stream>>>(deg, bsum, ptrn);
  zero_deg<<<(N_NODES_C + 255) / 256, 256, 0, stream>>>(deg);
  scatter_edges<<<(E_TOT_C + 255) / 256, 256, 0, stream>>>(ei, ptrn, deg, elist);

  // layer 1
  gemm_fused<<<N_NODES_C / 64, 256, 0, stream>>>(x, Bt1, hs, als, ald, 192, 8);
  aggregate1<<<N_NODES_C / 4, 256, 0, stream>>>(ptrn, elist, als, ald, hs, arena + ob1, h1);

  // layer 2
  gemm_fused<<<N_NODES_C / 64, 256, 0, stream>>>(h1, Bt2, hs, als, ald, 256, 1);
  aggregate2<<<N_NODES_C / 4, 256, 0, stream>>>(ptrn, elist, als, ald, hs, arena + ob2,
                                                (float*)d_out);
  write_tail<<<1, 64, 0, stream>>>((float*)d_out, out_size);
}

// Round 5
// 713.765 us; speedup vs baseline: 1.6751x; 1.0481x over previous
//
#include <hip/hip_runtime.h>
#include <hip/hip_bf16.h>

#define N_USERS_C 100000
#define N_ITEMS_C 20000
#define N_NODES_C 120000
#define E_TOT_C   400000
#define D_IN_C    192
#define HID_C     256
#define NEG_C     0.2f
#define CLAMP_C   1000.0f
#define KPAD_C    1152   // 1148 padded to multiple of 32
#define NB_SCAN   ((N_NODES_C + 255) / 256)   // 469 scan blocks
#define ROWE      40     // LDS row length in shorts: 32 k-elems + 8 pad (80B, 16B-aligned)

typedef __attribute__((ext_vector_type(8))) short bfrag;
typedef __attribute__((ext_vector_type(4))) float ffrag;

__device__ __forceinline__ float bf2f(unsigned short u){
  return __uint_as_float(((unsigned)u) << 16);
}
__device__ __forceinline__ float ldf(const void* p, long i, int isf32){
  return isf32 ? ((const float*)p)[i] : bf2f(((const unsigned short*)p)[i]);
}
__device__ __forceinline__ float sane(float v){
  return (v > -1e30f && v < 1e30f) ? v : 0.f;
}

// ---------- dtype discriminator (inputs) ----------
__global__ __launch_bounds__(256) void detect_dtype(const unsigned short* __restrict__ ue,
                                                    int* __restrict__ flag){
  __shared__ int cnt[256];
  int tid = threadIdx.x; int c = 0;
  for (int i = tid; i < 8192; i += 256){
    unsigned e = (ue[i] >> 7) & 0xFFu;
    if (e >= 129u) c++;
  }
  cnt[tid] = c; __syncthreads();
  if (tid == 0){
    int s = 0;
    for (int i = 0; i < 256; i++) s += cnt[i];
    *flag = (s > 100) ? 1 : 0;
  }
}

// ---------- convert small weight tensors into a bf16 arena ----------
#define NCONV 18
struct ConvArgs { const void* src[NCONV]; int n[NCONV]; int off[NCONV]; };

// grid = NCONV * 8 blocks; block handles tensor (b>>3), slice (b&7).
__global__ __launch_bounds__(256) void conv_small(ConvArgs a, __hip_bfloat16* __restrict__ arena,
                                                  const int* __restrict__ flag){
  int t = blockIdx.x >> 3, sub = blockIdx.x & 7;
  int f32 = *flag;
  const void* s = a.src[t];
  int n = a.n[t], off = a.off[t];
  for (int i = sub * 256 + threadIdx.x; i < n; i += 2048)
    arena[off + i] = __float2bfloat16(ldf(s, i, f32));
}

// Bt (272 x K): rows 0..255 = W^T; 256..256+H-1 = fold(Ws,a_s); next H = fold(Wd,a_d); rest 0.
__global__ void prep_bt(const __hip_bfloat16* __restrict__ Ws,
                        const __hip_bfloat16* __restrict__ Wd,
                        const __hip_bfloat16* __restrict__ as_,
                        const __hip_bfloat16* __restrict__ ad_,
                        __hip_bfloat16* __restrict__ Bt, int K, int H, int C){
  int idx = blockIdx.x * 256 + threadIdx.x;
  if (idx >= 272 * K) return;
  int col = idx / K, k = idx - col * K;
  float v;
  if (col < 256) {
    v = __bfloat162float(Ws[k * 256 + col]);
  } else if (col < 256 + H) {
    int h = col - 256; float s = 0.f;
    for (int c = 0; c < C; c++)
      s += __bfloat162float(Ws[k * 256 + h * C + c]) * __bfloat162float(as_[h * C + c]);
    v = s;
  } else if (col < 256 + 2 * H) {
    int h = col - 256 - H; float s = 0.f;
    for (int c = 0; c < C; c++)
      s += __bfloat162float(Wd[k * 256 + h * C + c]) * __bfloat162float(ad_[h * C + c]);
    v = s;
  } else v = 0.f;
  Bt[(long)col * K + k] = __float2bfloat16(v);
}

// x: (120000 x 192) bf16. Users: emb | zeros. Movies: item_emb cols 0..63.
__global__ void assemble_x(const void* __restrict__ ue, const void* __restrict__ ie,
                           __hip_bfloat16* __restrict__ x, const int* __restrict__ flag){
  long idx = (long)blockIdx.x * 256 + threadIdx.x;
  if (idx >= (long)N_NODES_C * D_IN_C) return;
  int f32 = *flag;
  int n = (int)(idx / D_IN_C); int c = (int)(idx - (long)n * D_IN_C);
  if (n < N_USERS_C) {
    x[idx] = __float2bfloat16((c < 64) ? ldf(ue, (long)n * 64 + c, f32) : 0.f);
  } else if (c < 64) {
    x[idx] = __float2bfloat16(ldf(ie, (long)(n - N_USERS_C) * 64 + c, f32));
  }
}

// ---------- movie feature path: MFMA instead of scalar MLP ----------
// mov_x (20000 x 1148) -> bf16 padded (20000 x 1152)
__global__ void conv_movx(const void* __restrict__ mv, __hip_bfloat16* __restrict__ out,
                          const int* __restrict__ flag){
  long idx = (long)blockIdx.x * 256 + threadIdx.x;
  if (idx >= (long)N_ITEMS_C * KPAD_C) return;
  int f32 = *flag;
  int m = (int)(idx / KPAD_C); int c = (int)(idx - (long)m * KPAD_C);
  float v = (c < 1148) ? ldf(mv, (long)m * 1148 + c, f32) : 0.f;
  out[idx] = __float2bfloat16(v);
}

// W1t (128 x 1152): row n<64 -> gW1 col n (k<20); row n>=64 -> tW1 col n-64 (20<=k<1148).
__global__ void prep_w1t(const __hip_bfloat16* __restrict__ gW1,
                         const __hip_bfloat16* __restrict__ tW1,
                         __hip_bfloat16* __restrict__ W1t){
  int idx = blockIdx.x * 256 + threadIdx.x;
  if (idx >= 128 * KPAD_C) return;
  int n = idx / KPAD_C, k = idx - n * KPAD_C;
  __hip_bfloat16 v = __float2bfloat16(0.f);
  if (n < 64) { if (k < 20) v = gW1[k * 64 + n]; }
  else       { if (k >= 20 && k < 1148) v = tW1[(k - 20) * 64 + (n - 64)]; }
  W1t[idx] = v;
}

// W2t (128 x 128) blockdiag of gW2 / tW2.
__global__ void prep_w2t(const __hip_bfloat16* __restrict__ gW2,
                         const __hip_bfloat16* __restrict__ tW2,
                         __hip_bfloat16* __restrict__ W2t){
  int idx = blockIdx.x * 256 + threadIdx.x;
  if (idx >= 128 * 128) return;
  int n = idx >> 7, k = idx & 127;
  __hip_bfloat16 v = __float2bfloat16(0.f);
  if (n < 64) { if (k < 64)  v = gW2[k * 64 + n]; }
  else        { if (k >= 64) v = tW2[(k - 64) * 64 + (n - 64)]; }
  W2t[idx] = v;
}

__global__ void prep_movie_bias(const __hip_bfloat16* __restrict__ gb1,
                                const __hip_bfloat16* __restrict__ tb1,
                                const __hip_bfloat16* __restrict__ gb2,
                                const __hip_bfloat16* __restrict__ tb2,
                                __hip_bfloat16* __restrict__ b1c,
                                __hip_bfloat16* __restrict__ b2c){
  int i = threadIdx.x;
  if (i < 64)       b1c[i] = gb1[i];
  else if (i < 128) b1c[i] = tb1[i - 64];
  else if (i < 192) b2c[i - 128] = gb2[i - 128];
  else              b2c[i - 128] = tb2[i - 192];
}

// MFMA GEMM, N=128 (8 n-tiles), M rows with guard, optional relu, bias add.
// LDS-staged A and B tiles per k-step: B shared across all 4 waves (4x line-traffic cut),
// staging loads wave-coalesced 16B chunks.
__global__ __launch_bounds__(256) void movie_gemm(
    const __hip_bfloat16* __restrict__ A, int lda, int M,
    const __hip_bfloat16* __restrict__ Bt, int K,
    const __hip_bfloat16* __restrict__ bias, int do_relu,
    __hip_bfloat16* __restrict__ out, int ldo, int ocol){
  __shared__ short Bls[128 * ROWE];   // 10.0 KB
  __shared__ short Als[64 * ROWE];    //  5.0 KB
  int tid = threadIdx.x;
  int wave = tid >> 6;
  int lane = tid & 63;
  int l15 = lane & 15;
  int quad = lane >> 4;
  int rowbase_blk = blockIdx.x * 64;
  int rowbase = rowbase_blk + wave * 16;
  ffrag acc[8];
#pragma unroll
  for (int i = 0; i < 8; i++) acc[i] = (ffrag){0.f, 0.f, 0.f, 0.f};
  const short* As = (const short*)A;
  const short* Bs = (const short*)Bt;
  int sr = tid >> 2, sc = tid & 3;              // A-staging: row sr in [0,64), 16B chunk sc
  int arow_st = rowbase_blk + sr; if (arow_st >= M) arow_st = M - 1;
  for (int k0 = 0; k0 < K; k0 += 32) {
    __syncthreads();   // previous iter's LDS reads done before overwrite
    // stage B: 128 rows x 4 chunks = 512 tasks
    for (int t = tid; t < 512; t += 256) {
      int r = t >> 2, c = t & 3;
      *(float4*)(&Bls[r * ROWE + c * 8]) = *(const float4*)(Bs + (long)r * K + k0 + c * 8);
    }
    // stage A: 64 rows x 4 chunks = 256 tasks (one per thread)
    *(float4*)(&Als[sr * ROWE + sc * 8]) =
        *(const float4*)(As + (long)arow_st * lda + k0 + sc * 8);
    __syncthreads();
    int koff = quad * 8;
    bfrag af = *(const bfrag*)(&Als[(wave * 16 + l15) * ROWE + koff]);
#pragma unroll
    for (int nt = 0; nt < 8; nt++) {
      bfrag bf = *(const bfrag*)(&Bls[(nt * 16 + l15) * ROWE + koff]);
      acc[nt] = __builtin_amdgcn_mfma_f32_16x16x32_bf16(af, bf, acc[nt], 0, 0, 0);
    }
  }
#pragma unroll
  for (int reg = 0; reg < 4; reg++) {
    int grow = rowbase + quad * 4 + reg;
    if (grow >= M) continue;
#pragma unroll
    for (int nt = 0; nt < 8; nt++) {
      float v = acc[nt][reg] + __bfloat162float(bias[nt * 16 + l15]);
      if (do_relu) v = fmaxf(v, 0.f);
      out[(long)grow * ldo + ocol + nt * 16 + l15] = __float2bfloat16(v);
    }
  }
}

// MFMA GEMM: A (M x K bf16) @ Bt^T -> Hout (M x 256 bf16) + als/ald (f32, M x natt).
// LDS-staged A and B per k-step; B (272 rows) shared by all 4 waves.
__global__ __launch_bounds__(256) void gemm_fused(
    const __hip_bfloat16* __restrict__ A, const __hip_bfloat16* __restrict__ Bt,
    __hip_bfloat16* __restrict__ Hout, float* __restrict__ als, float* __restrict__ ald,
    int K, int natt){
  __shared__ short Bls[272 * ROWE];   // 21.25 KB
  __shared__ short Als[64 * ROWE];    //  5.0 KB
  int tid = threadIdx.x;
  int wave = tid >> 6;
  int lane = tid & 63;
  int l15 = lane & 15;
  int quad = lane >> 4;
  int rowbase_blk = blockIdx.x * 64;
  int rowbase = rowbase_blk + wave * 16;
  ffrag acc[17];
#pragma unroll
  for (int i = 0; i < 17; i++) acc[i] = (ffrag){0.f, 0.f, 0.f, 0.f};
  const short* As = (const short*)A;
  const short* Bs = (const short*)Bt;
  int sr = tid >> 2, sc = tid & 3;   // A-staging row/chunk
  for (int k0 = 0; k0 < K; k0 += 32) {
    __syncthreads();
    // stage B: 272 rows x 4 chunks = 1088 tasks
    for (int t = tid; t < 1088; t += 256) {
      int r = t >> 2, c = t & 3;
      *(float4*)(&Bls[r * ROWE + c * 8]) = *(const float4*)(Bs + (long)r * K + k0 + c * 8);
    }
    // stage A: 64 rows x 4 chunks (grid is exact: rowbase_blk+63 < 120000)
    *(float4*)(&Als[sr * ROWE + sc * 8]) =
        *(const float4*)(As + (long)(rowbase_blk + sr) * K + k0 + sc * 8);
    __syncthreads();
    int koff = quad * 8;
    bfrag af = *(const bfrag*)(&Als[(wave * 16 + l15) * ROWE + koff]);
#pragma unroll
    for (int nt = 0; nt < 17; nt++) {
      bfrag bf = *(const bfrag*)(&Bls[(nt * 16 + l15) * ROWE + koff]);
      acc[nt] = __builtin_amdgcn_mfma_f32_16x16x32_bf16(af, bf, acc[nt], 0, 0, 0);
    }
  }
  int col = l15;
#pragma unroll
  for (int reg = 0; reg < 4; reg++) {
    int grow = rowbase + quad * 4 + reg;
    long obase = (long)grow * 256;
#pragma unroll
    for (int nt = 0; nt < 16; nt++)
      Hout[obase + nt * 16 + col] = __float2bfloat16(acc[nt][reg]);
    float v = acc[16][reg];
    if (col < natt) als[grow * natt + col] = v;
    else if (col < 2 * natt) ald[grow * natt + (col - natt)] = v;
  }
}

// ---------- CSR build (in-edges per dst) ----------
__global__ void zero_deg(int* __restrict__ deg){
  int i = blockIdx.x * 256 + threadIdx.x;
  if (i < N_NODES_C) deg[i] = 0;
}

__global__ void deg_count(const int* __restrict__ ei, int* __restrict__ deg){
  int e = blockIdx.x * 256 + threadIdx.x;
  if (e >= E_TOT_C) return;
  int dst = ei[E_TOT_C + e];
  if (dst >= 0 && dst < N_NODES_C) atomicAdd(&deg[dst], 1);
}

// Hierarchical exclusive scan of deg -> ptrn.
// Stage 1: per-block (256-wide) sums.
__global__ __launch_bounds__(256) void deg_bsum(const int* __restrict__ deg,
                                                int* __restrict__ bsum){
  int i = blockIdx.x * 256 + threadIdx.x;
  int v = (i < N_NODES_C) ? deg[i] : 0;
#pragma unroll
  for (int o = 32; o > 0; o >>= 1) v += __shfl_down(v, o, 64);
  __shared__ int ws[4];
  int wave = threadIdx.x >> 6, lane = threadIdx.x & 63;
  if (lane == 0) ws[wave] = v;
  __syncthreads();
  if (threadIdx.x == 0) bsum[blockIdx.x] = ws[0] + ws[1] + ws[2] + ws[3];
}

// Stage 2: single-block Hillis-Steele scan of 469 block sums -> exclusive offsets.
__global__ __launch_bounds__(512) void bsum_scan(int* __restrict__ bsum,
                                                 int* __restrict__ ptrn){
  __shared__ int sm[512];
  int t = threadIdx.x;
  int v = (t < NB_SCAN) ? bsum[t] : 0;
  sm[t] = v;
  __syncthreads();
  for (int o = 1; o < 512; o <<= 1) {
    int add = (t >= o) ? sm[t - o] : 0;
    __syncthreads();
    sm[t] += add;
    __syncthreads();
  }
  int excl = (t == 0) ? 0 : sm[t - 1];
  if (t < NB_SCAN) bsum[t] = excl;
  if (t == NB_SCAN - 1) ptrn[N_NODES_C] = sm[t];
}

// Stage 3: in-block exclusive scan + block offset -> ptrn.
__global__ __launch_bounds__(256) void deg_scan_final(const int* __restrict__ deg,
                                                      const int* __restrict__ bexcl,
                                                      int* __restrict__ ptrn){
  __shared__ int sm[256];
  int i = blockIdx.x * 256 + threadIdx.x;
  int t = threadIdx.x;
  int v = (i < N_NODES_C) ? deg[i] : 0;
  sm[t] = v;
  __syncthreads();
  for (int o = 1; o < 256; o <<= 1) {
    int add = (t >= o) ? sm[t - o] : 0;
    __syncthreads();
    sm[t] += add;
    __syncthreads();
  }
  int excl = (t == 0) ? 0 : sm[t - 1];
  if (i < N_NODES_C) ptrn[i] = bexcl[blockIdx.x] + excl;
}

__global__ void scatter_edges(const int* __restrict__ ei, const int* __restrict__ ptrn,
                              int* __restrict__ cursor, int* __restrict__ elist_src){
  int e = blockIdx.x * 256 + threadIdx.x;
  if (e >= E_TOT_C) return;
  int dst = ei[E_TOT_C + e];
  if (dst < 0 || dst >= N_NODES_C) return;
  int pos = atomicAdd(&cursor[dst], 1);
  elist_src[ptrn[dst] + pos] = ei[e];
}

// ---------- layer 1: single-pass ONLINE-softmax aggregation (8 heads) + bias + elu ----
// Branchless running-max rescale (flash style): removes the separate max pass
// (one elist read + one als gather + leaky per edge eliminated).
__global__ __launch_bounds__(256) void aggregate1(
    const int* __restrict__ ptrn, const int* __restrict__ elist_src,
    const float* __restrict__ als, const float* __restrict__ ald,
    const __hip_bfloat16* __restrict__ hs, const __hip_bfloat16* __restrict__ bias,
    __hip_bfloat16* __restrict__ h1){
  int node = blockIdx.x * 4 + (threadIdx.x >> 6);
  if (node >= N_NODES_C) return;
  int lane = threadIdx.x & 63;
  int c0 = lane * 4;
  int h = lane >> 3;
  int beg = ptrn[node], end = ptrn[node + 1];
  float aldv = sane(ald[node * 8 + h]);
  float m = -1e30f;
  float wsum = 0.f, a0 = 0.f, a1 = 0.f, a2 = 0.f, a3 = 0.f;
  for (int i = beg; i < end; i++) {
    int src = elist_src[i]; src = src < 0 ? 0 : (src >= N_NODES_C ? N_NODES_C - 1 : src);
    float ev = sane(als[src * 8 + h]) + aldv;
    ev = ev > 0.f ? ev : NEG_C * ev;
    float mnew = fmaxf(m, ev);
    float corr = __expf(m - mnew);   // first iter: exp(-inf)=0 zeroes the (empty) history
    float w = __expf(ev - mnew);
    m = mnew;
    wsum = wsum * corr + w;
    ushort4 hv = *(const ushort4*)((const unsigned short*)hs + (long)src * 256 + c0);
    a0 = a0 * corr + w * bf2f(hv.x); a1 = a1 * corr + w * bf2f(hv.y);
    a2 = a2 * corr + w * bf2f(hv.z); a3 = a3 * corr + w * bf2f(hv.w);
  }
  float inv = 1.f / (wsum + 1e-16f);
  float v0 = a0 * inv + __bfloat162float(bias[c0 + 0]);
  float v1 = a1 * inv + __bfloat162float(bias[c0 + 1]);
  float v2 = a2 * inv + __bfloat162float(bias[c0 + 2]);
  float v3 = a3 * inv + __bfloat162float(bias[c0 + 3]);
  v0 = v0 > 0.f ? v0 : (__expf(v0) - 1.f);
  v1 = v1 > 0.f ? v1 : (__expf(v1) - 1.f);
  v2 = v2 > 0.f ? v2 : (__expf(v2) - 1.f);
  v3 = v3 > 0.f ? v3 : (__expf(v3) - 1.f);
  v0 = fminf(fmaxf(v0, -CLAMP_C), CLAMP_C);
  v1 = fminf(fmaxf(v1, -CLAMP_C), CLAMP_C);
  v2 = fminf(fmaxf(v2, -CLAMP_C), CLAMP_C);
  v3 = fminf(fmaxf(v3, -CLAMP_C), CLAMP_C);
  long ob = (long)node * 256 + c0;
  h1[ob + 0] = __float2bfloat16(v0); h1[ob + 1] = __float2bfloat16(v1);
  h1[ob + 2] = __float2bfloat16(v2); h1[ob + 3] = __float2bfloat16(v3);
}

// ---------- layer 2: single-pass online softmax, 1 head, f32 output ----------
__global__ __launch_bounds__(256) void aggregate2(
    const int* __restrict__ ptrn, const int* __restrict__ elist_src,
    const float* __restrict__ als, const float* __restrict__ ald,
    const __hip_bfloat16* __restrict__ hs, const __hip_bfloat16* __restrict__ bias,
    float* __restrict__ out){
  int node = blockIdx.x * 4 + (threadIdx.x >> 6);
  if (node >= N_NODES_C) return;
  int lane = threadIdx.x & 63;
  int c0 = lane * 4;
  int beg = ptrn[node], end = ptrn[node + 1];
  float aldv = sane(ald[node]);
  float m = -1e30f;
  float wsum = 0.f, a0 = 0.f, a1 = 0.f, a2 = 0.f, a3 = 0.f;
  for (int i = beg; i < end; i++) {
    int src = elist_src[i]; src = src < 0 ? 0 : (src >= N_NODES_C ? N_NODES_C - 1 : src);
    float ev = sane(als[src]) + aldv;
    ev = ev > 0.f ? ev : NEG_C * ev;
    float mnew = fmaxf(m, ev);
    float corr = __expf(m - mnew);
    float w = __expf(ev - mnew);
    m = mnew;
    wsum = wsum * corr + w;
    ushort4 hv = *(const ushort4*)((const unsigned short*)hs + (long)src * 256 + c0);
    a0 = a0 * corr + w * bf2f(hv.x); a1 = a1 * corr + w * bf2f(hv.y);
    a2 = a2 * corr + w * bf2f(hv.z); a3 = a3 * corr + w * bf2f(hv.w);
  }
  float inv = 1.f / (wsum + 1e-16f);
  float4 v;
  v.x = a0 * inv + __bfloat162float(bias[c0 + 0]);
  v.y = a1 * inv + __bfloat162float(bias[c0 + 1]);
  v.z = a2 * inv + __bfloat162float(bias[c0 + 2]);
  v.w = a3 * inv + __bfloat162float(bias[c0 + 3]);
  v.x = fminf(fmaxf(v.x, -CLAMP_C), CLAMP_C);
  v.y = fminf(fmaxf(v.y, -CLAMP_C), CLAMP_C);
  v.z = fminf(fmaxf(v.z, -CLAMP_C), CLAMP_C);
  v.w = fminf(fmaxf(v.w, -CLAMP_C), CLAMP_C);
  *(float4*)(out + (long)node * 256 + c0) = v;
}

__global__ void write_tail(float* __restrict__ out, int out_size){
  if (threadIdx.x == 0 && blockIdx.x == 0) {
    out[out_size - 3] = 0.f;
    out[out_size - 2] = (float)N_USERS_C;
    out[out_size - 1] = (float)N_NODES_C;
  }
}

extern "C" void kernel_launch(void* const* d_in, const int* in_sizes, int n_in,
                              void* d_out, int out_size, void* d_ws, size_t ws_size,
                              hipStream_t stream) {
  const void* mov_x    = d_in[2];
  const int*  ei       = (const int*)d_in[3];
  const void* user_emb = d_in[4];
  const void* item_emb = d_in[5];

  char* ws = (char*)d_ws;
  size_t off = 0;
  auto alloc = [&](size_t bytes) -> void* {
    void* p = ws + off; off += (bytes + 255) / 256 * 256; return p;
  };
  int* flag   = (int*)alloc(4);
  __hip_bfloat16* arena = (__hip_bfloat16*)alloc(312832 * 2);
  __hip_bfloat16* Bt1 = (__hip_bfloat16*)alloc(272 * 192 * 2);
  __hip_bfloat16* Bt2 = (__hip_bfloat16*)alloc(272 * 256 * 2);
  __hip_bfloat16* W1t = (__hip_bfloat16*)alloc(128 * KPAD_C * 2);
  __hip_bfloat16* W2t = (__hip_bfloat16*)alloc(128 * 128 * 2);
  __hip_bfloat16* b1c = (__hip_bfloat16*)alloc(128 * 2);
  __hip_bfloat16* b2c = (__hip_bfloat16*)alloc(128 * 2);
  int* ptrn   = (int*)alloc((N_NODES_C + 1) * 4);
  int* deg    = (int*)alloc(N_NODES_C * 4);
  int* bsum   = (int*)alloc(512 * 4);
  int* elist  = (int*)alloc(E_TOT_C * 4);
  float* als  = (float*)alloc((size_t)N_NODES_C * 8 * 4);
  float* ald  = (float*)alloc((size_t)N_NODES_C * 8 * 4);
  __hip_bfloat16* x  = (__hip_bfloat16*)alloc((size_t)N_NODES_C * D_IN_C * 2); // 46.08 MB
  __hip_bfloat16* hs = (__hip_bfloat16*)alloc((size_t)N_NODES_C * HID_C * 2);  // 61.44 MB
  // d_out (f32, 122.88 MB) hosts two dead-before-aggregate2 temporaries:
  //   h1 (bf16 61.44 MB) at byte 0; mov_bf (bf16 46.08 MB) at byte 61,440,000.
  __hip_bfloat16* h1     = (__hip_bfloat16*)d_out;
  __hip_bfloat16* mov_bf = (__hip_bfloat16*)((char*)d_out + 61440000);
  __hip_bfloat16* hid    = hs;  // movie hidden (20000x128) parks in hs

  const int oWs1=0, oWd1=49152, oas1=98304, oad1=98560, ob1=98816,
            oWs2=99072, oWd2=164608, oas2=230144, oad2=230400, ob2=230656,
            ogW1=230912, ogb1=232192, ogW2=232256, ogb2=236352,
            otW1=236416, otb1=308608, otW2=308672, otb2=312768;

  detect_dtype<<<1, 256, 0, stream>>>((const unsigned short*)user_emb, flag);

  ConvArgs ca;
  const int srcidx[NCONV] = {14,15,16,17,18,19,20,21,22,23,6,7,8,9,10,11,12,13};
  const int offs[NCONV]   = {oWs1,oWd1,oas1,oad1,ob1,oWs2,oWd2,oas2,oad2,ob2,
                             ogW1,ogb1,ogW2,ogb2,otW1,otb1,otW2,otb2};
  const int ns[NCONV]     = {49152,49152,256,256,256,65536,65536,256,256,256,
                             1280,64,4096,64,72192,64,4096,64};
  for (int i = 0; i < NCONV; i++) { ca.src[i] = d_in[srcidx[i]]; ca.n[i] = ns[i]; ca.off[i] = offs[i]; }
  conv_small<<<NCONV * 8, 256, 0, stream>>>(ca, arena, flag);

  // movie feature path (MFMA)
  conv_movx<<<(int)(((long)N_ITEMS_C * KPAD_C + 255) / 256), 256, 0, stream>>>(
      mov_x, mov_bf, flag);
  prep_w1t<<<(128 * KPAD_C + 255) / 256, 256, 0, stream>>>(arena + ogW1, arena + otW1, W1t);
  prep_w2t<<<(128 * 128 + 255) / 256, 256, 0, stream>>>(arena + ogW2, arena + otW2, W2t);
  prep_movie_bias<<<1, 256, 0, stream>>>(arena + ogb1, arena + otb1,
                                         arena + ogb2, arena + otb2, b1c, b2c);
  assemble_x<<<(int)(((long)N_NODES_C * D_IN_C + 255) / 256), 256, 0, stream>>>(
      user_emb, item_emb, x, flag);
  movie_gemm<<<(N_ITEMS_C + 63) / 64, 256, 0, stream>>>(
      mov_bf, KPAD_C, N_ITEMS_C, W1t, KPAD_C, b1c, 1, hid, 128, 0);
  movie_gemm<<<(N_ITEMS_C + 63) / 64, 256, 0, stream>>>(
      hid, 128, N_ITEMS_C, W2t, 128, b2c, 0,
      x + (long)N_USERS_C * D_IN_C, D_IN_C, 64);

  prep_bt<<<(272 * 192 + 255) / 256, 256, 0, stream>>>(
      arena + oWs1, arena + oWd1, arena + oas1, arena + oad1, Bt1, 192, 8, 32);
  prep_bt<<<(272 * 256 + 255) / 256, 256, 0, stream>>>(
      arena + oWs2, arena + oWd2, arena + oas2, arena + oad2, Bt2, 256, 1, 256);

  // CSR of in-edges
  zero_deg<<<(N_NODES_C + 255) / 256, 256, 0, stream>>>(deg);
  deg_count<<<(E_TOT_C + 255) / 256, 256, 0, stream>>>(ei, deg);
  deg_bsum<<<NB_SCAN, 256, 0, stream>>>(deg, bsum);
  bsum_scan<<<1, 512, 0, stream>>>(bsum, ptrn);
  deg_scan_final<<<NB_SCAN, 256, 0, stream>>>(deg, bsum, ptrn);
  zero_deg<<<(N_NODES_C + 255) / 256, 256, 0, stream>>>(deg);
  scatter_edges<<<(E_TOT_C + 255) / 256, 256, 0, stream>>>(ei, ptrn, deg, elist);

  // layer 1
  gemm_fused<<<N_NODES_C / 64, 256, 0, stream>>>(x, Bt1, hs, als, ald, 192, 8);
  aggregate1<<<N_NODES_C / 4, 256, 0, stream>>>(ptrn, elist, als, ald, hs, arena + ob1, h1);

  // layer 2
  gemm_fused<<<N_NODES_C / 64, 256, 0, stream>>>(h1, Bt2, hs, als, ald, 256, 1);
  aggregate2<<<N_NODES_C / 4, 256, 0, stream>>>(ptrn, elist, als, ald, hs, arena + ob2,
                                                (float*)d_out);
  write_tail<<<1, 64, 0, stream>>>((float*)d_out, out_size);
}

// Round 6
// 677.196 us; speedup vs baseline: 1.7656x; 1.0540x over previous
//
#include <hip/hip_runtime.h>
#include <hip/hip_bf16.h>

#define N_USERS_C 100000
#define N_ITEMS_C 20000
#define N_NODES_C 120000
#define E_TOT_C   400000
#define D_IN_C    192
#define HID_C     256
#define NEG_C     0.2f
#define CLAMP_C   1000.0f
#define KPAD_C    1152   // 1148 padded to multiple of 32
#define NB_SCAN   ((N_NODES_C + 255) / 256)   // 469 scan blocks
#define ROWE      40     // LDS row length in shorts: 32 k-elems + 8 pad (80B, 16B-aligned)

typedef __attribute__((ext_vector_type(8))) short bfrag;
typedef __attribute__((ext_vector_type(4))) float ffrag;

__device__ __forceinline__ float bf2f(unsigned short u){
  return __uint_as_float(((unsigned)u) << 16);
}
__device__ __forceinline__ float ldf(const void* p, long i, int isf32){
  return isf32 ? ((const float*)p)[i] : bf2f(((const unsigned short*)p)[i]);
}
__device__ __forceinline__ float sane(float v){
  return (v > -1e30f && v < 1e30f) ? v : 0.f;
}
__device__ __forceinline__ int clampsrc(int s){
  return s < 0 ? 0 : (s >= N_NODES_C ? N_NODES_C - 1 : s);
}

// ---------- dtype discriminator (inputs) ----------
__global__ __launch_bounds__(256) void detect_dtype(const unsigned short* __restrict__ ue,
                                                    int* __restrict__ flag){
  __shared__ int cnt[256];
  int tid = threadIdx.x; int c = 0;
  for (int i = tid; i < 8192; i += 256){
    unsigned e = (ue[i] >> 7) & 0xFFu;
    if (e >= 129u) c++;
  }
  cnt[tid] = c; __syncthreads();
  if (tid == 0){
    int s = 0;
    for (int i = 0; i < 256; i++) s += cnt[i];
    *flag = (s > 100) ? 1 : 0;
  }
}

// ---------- convert small weight tensors into a bf16 arena ----------
#define NCONV 18
struct ConvArgs { const void* src[NCONV]; int n[NCONV]; int off[NCONV]; };

// grid = NCONV * 8 blocks; block handles tensor (b>>3), slice (b&7).
__global__ __launch_bounds__(256) void conv_small(ConvArgs a, __hip_bfloat16* __restrict__ arena,
                                                  const int* __restrict__ flag){
  int t = blockIdx.x >> 3, sub = blockIdx.x & 7;
  int f32 = *flag;
  const void* s = a.src[t];
  int n = a.n[t], off = a.off[t];
  for (int i = sub * 256 + threadIdx.x; i < n; i += 2048)
    arena[off + i] = __float2bfloat16(ldf(s, i, f32));
}

// Bt (272 x K): rows 0..255 = W^T; 256..256+H-1 = fold(Ws,a_s); next H = fold(Wd,a_d); rest 0.
__global__ void prep_bt(const __hip_bfloat16* __restrict__ Ws,
                        const __hip_bfloat16* __restrict__ Wd,
                        const __hip_bfloat16* __restrict__ as_,
                        const __hip_bfloat16* __restrict__ ad_,
                        __hip_bfloat16* __restrict__ Bt, int K, int H, int C){
  int idx = blockIdx.x * 256 + threadIdx.x;
  if (idx >= 272 * K) return;
  int col = idx / K, k = idx - col * K;
  float v;
  if (col < 256) {
    v = __bfloat162float(Ws[k * 256 + col]);
  } else if (col < 256 + H) {
    int h = col - 256; float s = 0.f;
    for (int c = 0; c < C; c++)
      s += __bfloat162float(Ws[k * 256 + h * C + c]) * __bfloat162float(as_[h * C + c]);
    v = s;
  } else if (col < 256 + 2 * H) {
    int h = col - 256 - H; float s = 0.f;
    for (int c = 0; c < C; c++)
      s += __bfloat162float(Wd[k * 256 + h * C + c]) * __bfloat162float(ad_[h * C + c]);
    v = s;
  } else v = 0.f;
  Bt[(long)col * K + k] = __float2bfloat16(v);
}

// x: (120000 x 192) bf16. Users: emb | zeros. Movies: item_emb cols 0..63.
__global__ void assemble_x(const void* __restrict__ ue, const void* __restrict__ ie,
                           __hip_bfloat16* __restrict__ x, const int* __restrict__ flag){
  long idx = (long)blockIdx.x * 256 + threadIdx.x;
  if (idx >= (long)N_NODES_C * D_IN_C) return;
  int f32 = *flag;
  int n = (int)(idx / D_IN_C); int c = (int)(idx - (long)n * D_IN_C);
  if (n < N_USERS_C) {
    x[idx] = __float2bfloat16((c < 64) ? ldf(ue, (long)n * 64 + c, f32) : 0.f);
  } else if (c < 64) {
    x[idx] = __float2bfloat16(ldf(ie, (long)(n - N_USERS_C) * 64 + c, f32));
  }
}

// ---------- movie feature path: MFMA instead of scalar MLP ----------
// mov_x (20000 x 1148) -> bf16 padded (20000 x 1152)
__global__ void conv_movx(const void* __restrict__ mv, __hip_bfloat16* __restrict__ out,
                          const int* __restrict__ flag){
  long idx = (long)blockIdx.x * 256 + threadIdx.x;
  if (idx >= (long)N_ITEMS_C * KPAD_C) return;
  int f32 = *flag;
  int m = (int)(idx / KPAD_C); int c = (int)(idx - (long)m * KPAD_C);
  float v = (c < 1148) ? ldf(mv, (long)m * 1148 + c, f32) : 0.f;
  out[idx] = __float2bfloat16(v);
}

// W1t (128 x 1152): row n<64 -> gW1 col n (k<20); row n>=64 -> tW1 col n-64 (20<=k<1148).
__global__ void prep_w1t(const __hip_bfloat16* __restrict__ gW1,
                         const __hip_bfloat16* __restrict__ tW1,
                         __hip_bfloat16* __restrict__ W1t){
  int idx = blockIdx.x * 256 + threadIdx.x;
  if (idx >= 128 * KPAD_C) return;
  int n = idx / KPAD_C, k = idx - n * KPAD_C;
  __hip_bfloat16 v = __float2bfloat16(0.f);
  if (n < 64) { if (k < 20) v = gW1[k * 64 + n]; }
  else       { if (k >= 20 && k < 1148) v = tW1[(k - 20) * 64 + (n - 64)]; }
  W1t[idx] = v;
}

// W2t (128 x 128) blockdiag of gW2 / tW2.
__global__ void prep_w2t(const __hip_bfloat16* __restrict__ gW2,
                         const __hip_bfloat16* __restrict__ tW2,
                         __hip_bfloat16* __restrict__ W2t){
  int idx = blockIdx.x * 256 + threadIdx.x;
  if (idx >= 128 * 128) return;
  int n = idx >> 7, k = idx & 127;
  __hip_bfloat16 v = __float2bfloat16(0.f);
  if (n < 64) { if (k < 64)  v = gW2[k * 64 + n]; }
  else        { if (k >= 64) v = tW2[(k - 64) * 64 + (n - 64)]; }
  W2t[idx] = v;
}

__global__ void prep_movie_bias(const __hip_bfloat16* __restrict__ gb1,
                                const __hip_bfloat16* __restrict__ tb1,
                                const __hip_bfloat16* __restrict__ gb2,
                                const __hip_bfloat16* __restrict__ tb2,
                                __hip_bfloat16* __restrict__ b1c,
                                __hip_bfloat16* __restrict__ b2c){
  int i = threadIdx.x;
  if (i < 64)       b1c[i] = gb1[i];
  else if (i < 128) b1c[i] = tb1[i - 64];
  else if (i < 192) b2c[i - 128] = gb2[i - 128];
  else              b2c[i - 128] = tb2[i - 192];
}

// MFMA GEMM, N=128 (8 n-tiles), M rows with guard, optional relu, bias add.
// LDS-staged A and B tiles per k-step: B shared across all 4 waves.
__global__ __launch_bounds__(256) void movie_gemm(
    const __hip_bfloat16* __restrict__ A, int lda, int M,
    const __hip_bfloat16* __restrict__ Bt, int K,
    const __hip_bfloat16* __restrict__ bias, int do_relu,
    __hip_bfloat16* __restrict__ out, int ldo, int ocol){
  __shared__ short Bls[128 * ROWE];   // 10.0 KB
  __shared__ short Als[64 * ROWE];    //  5.0 KB
  int tid = threadIdx.x;
  int wave = tid >> 6;
  int lane = tid & 63;
  int l15 = lane & 15;
  int quad = lane >> 4;
  int rowbase_blk = blockIdx.x * 64;
  int rowbase = rowbase_blk + wave * 16;
  ffrag acc[8];
#pragma unroll
  for (int i = 0; i < 8; i++) acc[i] = (ffrag){0.f, 0.f, 0.f, 0.f};
  const short* As = (const short*)A;
  const short* Bs = (const short*)Bt;
  int sr = tid >> 2, sc = tid & 3;              // A-staging: row sr in [0,64), 16B chunk sc
  int arow_st = rowbase_blk + sr; if (arow_st >= M) arow_st = M - 1;
  for (int k0 = 0; k0 < K; k0 += 32) {
    __syncthreads();   // previous iter's LDS reads done before overwrite
    // stage B: 128 rows x 4 chunks = 512 tasks
    for (int t = tid; t < 512; t += 256) {
      int r = t >> 2, c = t & 3;
      *(float4*)(&Bls[r * ROWE + c * 8]) = *(const float4*)(Bs + (long)r * K + k0 + c * 8);
    }
    // stage A: 64 rows x 4 chunks = 256 tasks (one per thread)
    *(float4*)(&Als[sr * ROWE + sc * 8]) =
        *(const float4*)(As + (long)arow_st * lda + k0 + sc * 8);
    __syncthreads();
    int koff = quad * 8;
    bfrag af = *(const bfrag*)(&Als[(wave * 16 + l15) * ROWE + koff]);
#pragma unroll
    for (int nt = 0; nt < 8; nt++) {
      bfrag bf = *(const bfrag*)(&Bls[(nt * 16 + l15) * ROWE + koff]);
      acc[nt] = __builtin_amdgcn_mfma_f32_16x16x32_bf16(af, bf, acc[nt], 0, 0, 0);
    }
  }
#pragma unroll
  for (int reg = 0; reg < 4; reg++) {
    int grow = rowbase + quad * 4 + reg;
    if (grow >= M) continue;
#pragma unroll
    for (int nt = 0; nt < 8; nt++) {
      float v = acc[nt][reg] + __bfloat162float(bias[nt * 16 + l15]);
      if (do_relu) v = fmaxf(v, 0.f);
      out[(long)grow * ldo + ocol + nt * 16 + l15] = __float2bfloat16(v);
    }
  }
}

// MFMA GEMM: A (M x K bf16) @ Bt^T -> Hout (M x 256 bf16) + als/ald (f32, M x natt).
// LDS-staged A and B per k-step; B shared by all 4 waves.
// ukmax: K-bound for blocks whose 64 rows are ALL users (x cols 64..K-1 are zero by
// construction for user rows -> skipped K-range contributes exactly 0). Layer 1 passes
// 64; layer 2 passes K (no-op).
__global__ __launch_bounds__(256) void gemm_fused(
    const __hip_bfloat16* __restrict__ A, const __hip_bfloat16* __restrict__ Bt,
    __hip_bfloat16* __restrict__ Hout, float* __restrict__ als, float* __restrict__ ald,
    int K, int natt, int ukmax){
  __shared__ short Bls[272 * ROWE];   // 21.25 KB
  __shared__ short Als[64 * ROWE];    //  5.0 KB
  int tid = threadIdx.x;
  int wave = tid >> 6;
  int lane = tid & 63;
  int l15 = lane & 15;
  int quad = lane >> 4;
  int rowbase_blk = blockIdx.x * 64;
  int rowbase = rowbase_blk + wave * 16;
  int kmax = (rowbase_blk + 64 <= N_USERS_C) ? ukmax : K;
  ffrag acc[17];
#pragma unroll
  for (int i = 0; i < 17; i++) acc[i] = (ffrag){0.f, 0.f, 0.f, 0.f};
  const short* As = (const short*)A;
  const short* Bs = (const short*)Bt;
  int sr = tid >> 2, sc = tid & 3;   // A-staging row/chunk
  for (int k0 = 0; k0 < kmax; k0 += 32) {
    __syncthreads();
    // stage B: 272 rows x 4 chunks = 1088 tasks
    for (int t = tid; t < 1088; t += 256) {
      int r = t >> 2, c = t & 3;
      *(float4*)(&Bls[r * ROWE + c * 8]) = *(const float4*)(Bs + (long)r * K + k0 + c * 8);
    }
    // stage A: 64 rows x 4 chunks (grid is exact: rowbase_blk+63 < 120000)
    *(float4*)(&Als[sr * ROWE + sc * 8]) =
        *(const float4*)(As + (long)(rowbase_blk + sr) * K + k0 + sc * 8);
    __syncthreads();
    int koff = quad * 8;
    bfrag af = *(const bfrag*)(&Als[(wave * 16 + l15) * ROWE + koff]);
#pragma unroll
    for (int nt = 0; nt < 17; nt++) {
      bfrag bf = *(const bfrag*)(&Bls[(nt * 16 + l15) * ROWE + koff]);
      acc[nt] = __builtin_amdgcn_mfma_f32_16x16x32_bf16(af, bf, acc[nt], 0, 0, 0);
    }
  }
  int col = l15;
#pragma unroll
  for (int reg = 0; reg < 4; reg++) {
    int grow = rowbase + quad * 4 + reg;
    long obase = (long)grow * 256;
#pragma unroll
    for (int nt = 0; nt < 16; nt++)
      Hout[obase + nt * 16 + col] = __float2bfloat16(acc[nt][reg]);
    float v = acc[16][reg];
    if (col < natt) als[grow * natt + col] = v;
    else if (col < 2 * natt) ald[grow * natt + (col - natt)] = v;
  }
}

// ---------- CSR build (in-edges per dst) ----------
__global__ void zero_deg(int* __restrict__ deg){
  int i = blockIdx.x * 256 + threadIdx.x;
  if (i < N_NODES_C) deg[i] = 0;
}

__global__ void deg_count(const int* __restrict__ ei, int* __restrict__ deg){
  int e = blockIdx.x * 256 + threadIdx.x;
  if (e >= E_TOT_C) return;
  int dst = ei[E_TOT_C + e];
  if (dst >= 0 && dst < N_NODES_C) atomicAdd(&deg[dst], 1);
}

// Hierarchical exclusive scan of deg -> ptrn.
// Stage 1: per-block (256-wide) sums.
__global__ __launch_bounds__(256) void deg_bsum(const int* __restrict__ deg,
                                                int* __restrict__ bsum){
  int i = blockIdx.x * 256 + threadIdx.x;
  int v = (i < N_NODES_C) ? deg[i] : 0;
#pragma unroll
  for (int o = 32; o > 0; o >>= 1) v += __shfl_down(v, o, 64);
  __shared__ int ws[4];
  int wave = threadIdx.x >> 6, lane = threadIdx.x & 63;
  if (lane == 0) ws[wave] = v;
  __syncthreads();
  if (threadIdx.x == 0) bsum[blockIdx.x] = ws[0] + ws[1] + ws[2] + ws[3];
}

// Stage 2: single-block Hillis-Steele scan of 469 block sums -> exclusive offsets.
__global__ __launch_bounds__(512) void bsum_scan(int* __restrict__ bsum,
                                                 int* __restrict__ ptrn){
  __shared__ int sm[512];
  int t = threadIdx.x;
  int v = (t < NB_SCAN) ? bsum[t] : 0;
  sm[t] = v;
  __syncthreads();
  for (int o = 1; o < 512; o <<= 1) {
    int add = (t >= o) ? sm[t - o] : 0;
    __syncthreads();
    sm[t] += add;
    __syncthreads();
  }
  int excl = (t == 0) ? 0 : sm[t - 1];
  if (t < NB_SCAN) bsum[t] = excl;
  if (t == NB_SCAN - 1) ptrn[N_NODES_C] = sm[t];
}

// Stage 3: in-block exclusive scan + block offset -> ptrn.
__global__ __launch_bounds__(256) void deg_scan_final(const int* __restrict__ deg,
                                                      const int* __restrict__ bexcl,
                                                      int* __restrict__ ptrn){
  __shared__ int sm[256];
  int i = blockIdx.x * 256 + threadIdx.x;
  int t = threadIdx.x;
  int v = (i < N_NODES_C) ? deg[i] : 0;
  sm[t] = v;
  __syncthreads();
  for (int o = 1; o < 256; o <<= 1) {
    int add = (t >= o) ? sm[t - o] : 0;
    __syncthreads();
    sm[t] += add;
    __syncthreads();
  }
  int excl = (t == 0) ? 0 : sm[t - 1];
  if (i < N_NODES_C) ptrn[i] = bexcl[blockIdx.x] + excl;
}

__global__ void scatter_edges(const int* __restrict__ ei, const int* __restrict__ ptrn,
                              int* __restrict__ cursor, int* __restrict__ elist_src){
  int e = blockIdx.x * 256 + threadIdx.x;
  if (e >= E_TOT_C) return;
  int dst = ei[E_TOT_C + e];
  if (dst < 0 || dst >= N_NODES_C) return;
  int pos = atomicAdd(&cursor[dst], 1);
  elist_src[ptrn[dst] + pos] = ei[e];
}

// ---------- layer 1: online-softmax aggregation, 2-deep software-pipelined gathers ----
// src index runs one edge ahead of the als/hs gathers; gathers run one edge ahead of
// the exp chain -> gather latency hides under compute (latency-bound fix, G7).
__global__ __launch_bounds__(256) void aggregate1(
    const int* __restrict__ ptrn, const int* __restrict__ elist_src,
    const float* __restrict__ als, const float* __restrict__ ald,
    const __hip_bfloat16* __restrict__ hs, const __hip_bfloat16* __restrict__ bias,
    __hip_bfloat16* __restrict__ h1){
  int node = blockIdx.x * 4 + (threadIdx.x >> 6);
  if (node >= N_NODES_C) return;
  int lane = threadIdx.x & 63;
  int c0 = lane * 4;
  int h = lane >> 3;
  int beg = ptrn[node], end = ptrn[node + 1];
  float aldv = sane(ald[node * 8 + h]);
  float m = -1e30f;
  float wsum = 0.f, a0 = 0.f, a1 = 0.f, a2 = 0.f, a3 = 0.f;
  const unsigned short* hsu = (const unsigned short*)hs;
  float alsv_p = 0.f;
  ushort4 hv_p = {0, 0, 0, 0};
  int src_b = 0;
  if (beg < end) {
    int s0 = clampsrc(elist_src[beg]);
    alsv_p = als[(long)s0 * 8 + h];
    hv_p = *(const ushort4*)(hsu + (long)s0 * 256 + c0);
    if (beg + 1 < end) src_b = clampsrc(elist_src[beg + 1]);
  }
  for (int i = beg; i < end; i++) {
    float alsv = alsv_p;
    ushort4 hv = hv_p;
    if (i + 1 < end) {           // issue next-edge gathers before this edge's compute
      alsv_p = als[(long)src_b * 8 + h];
      hv_p = *(const ushort4*)(hsu + (long)src_b * 256 + c0);
    }
    if (i + 2 < end)             // and the src index one further ahead
      src_b = clampsrc(elist_src[i + 2]);
    float ev = sane(alsv) + aldv;
    ev = ev > 0.f ? ev : NEG_C * ev;
    float mnew = fmaxf(m, ev);
    float corr = __expf(m - mnew);   // first iter: exp(-inf)=0 zeroes empty history
    float w = __expf(ev - mnew);
    m = mnew;
    wsum = wsum * corr + w;
    a0 = a0 * corr + w * bf2f(hv.x); a1 = a1 * corr + w * bf2f(hv.y);
    a2 = a2 * corr + w * bf2f(hv.z); a3 = a3 * corr + w * bf2f(hv.w);
  }
  float inv = 1.f / (wsum + 1e-16f);
  float v0 = a0 * inv + __bfloat162float(bias[c0 + 0]);
  float v1 = a1 * inv + __bfloat162float(bias[c0 + 1]);
  float v2 = a2 * inv + __bfloat162float(bias[c0 + 2]);
  float v3 = a3 * inv + __bfloat162float(bias[c0 + 3]);
  v0 = v0 > 0.f ? v0 : (__expf(v0) - 1.f);
  v1 = v1 > 0.f ? v1 : (__expf(v1) - 1.f);
  v2 = v2 > 0.f ? v2 : (__expf(v2) - 1.f);
  v3 = v3 > 0.f ? v3 : (__expf(v3) - 1.f);
  v0 = fminf(fmaxf(v0, -CLAMP_C), CLAMP_C);
  v1 = fminf(fmaxf(v1, -CLAMP_C), CLAMP_C);
  v2 = fminf(fmaxf(v2, -CLAMP_C), CLAMP_C);
  v3 = fminf(fmaxf(v3, -CLAMP_C), CLAMP_C);
  long ob = (long)node * 256 + c0;
  h1[ob + 0] = __float2bfloat16(v0); h1[ob + 1] = __float2bfloat16(v1);
  h1[ob + 2] = __float2bfloat16(v2); h1[ob + 3] = __float2bfloat16(v3);
}

// ---------- layer 2: online softmax, pipelined, 1 head, f32 output ----------
__global__ __launch_bounds__(256) void aggregate2(
    const int* __restrict__ ptrn, const int* __restrict__ elist_src,
    const float* __restrict__ als, const float* __restrict__ ald,
    const __hip_bfloat16* __restrict__ hs, const __hip_bfloat16* __restrict__ bias,
    float* __restrict__ out){
  int node = blockIdx.x * 4 + (threadIdx.x >> 6);
  if (node >= N_NODES_C) return;
  int lane = threadIdx.x & 63;
  int c0 = lane * 4;
  int beg = ptrn[node], end = ptrn[node + 1];
  float aldv = sane(ald[node]);
  float m = -1e30f;
  float wsum = 0.f, a0 = 0.f, a1 = 0.f, a2 = 0.f, a3 = 0.f;
  const unsigned short* hsu = (const unsigned short*)hs;
  float alsv_p = 0.f;
  ushort4 hv_p = {0, 0, 0, 0};
  int src_b = 0;
  if (beg < end) {
    int s0 = clampsrc(elist_src[beg]);
    alsv_p = als[s0];
    hv_p = *(const ushort4*)(hsu + (long)s0 * 256 + c0);
    if (beg + 1 < end) src_b = clampsrc(elist_src[beg + 1]);
  }
  for (int i = beg; i < end; i++) {
    float alsv = alsv_p;
    ushort4 hv = hv_p;
    if (i + 1 < end) {
      alsv_p = als[src_b];
      hv_p = *(const ushort4*)(hsu + (long)src_b * 256 + c0);
    }
    if (i + 2 < end)
      src_b = clampsrc(elist_src[i + 2]);
    float ev = sane(alsv) + aldv;
    ev = ev > 0.f ? ev : NEG_C * ev;
    float mnew = fmaxf(m, ev);
    float corr = __expf(m - mnew);
    float w = __expf(ev - mnew);
    m = mnew;
    wsum = wsum * corr + w;
    a0 = a0 * corr + w * bf2f(hv.x); a1 = a1 * corr + w * bf2f(hv.y);
    a2 = a2 * corr + w * bf2f(hv.z); a3 = a3 * corr + w * bf2f(hv.w);
  }
  float inv = 1.f / (wsum + 1e-16f);
  float4 v;
  v.x = a0 * inv + __bfloat162float(bias[c0 + 0]);
  v.y = a1 * inv + __bfloat162float(bias[c0 + 1]);
  v.z = a2 * inv + __bfloat162float(bias[c0 + 2]);
  v.w = a3 * inv + __bfloat162float(bias[c0 + 3]);
  v.x = fminf(fmaxf(v.x, -CLAMP_C), CLAMP_C);
  v.y = fminf(fmaxf(v.y, -CLAMP_C), CLAMP_C);
  v.z = fminf(fmaxf(v.z, -CLAMP_C), CLAMP_C);
  v.w = fminf(fmaxf(v.w, -CLAMP_C), CLAMP_C);
  *(float4*)(out + (long)node * 256 + c0) = v;
}

__global__ void write_tail(float* __restrict__ out, int out_size){
  if (threadIdx.x == 0 && blockIdx.x == 0) {
    out[out_size - 3] = 0.f;
    out[out_size - 2] = (float)N_USERS_C;
    out[out_size - 1] = (float)N_NODES_C;
  }
}

extern "C" void kernel_launch(void* const* d_in, const int* in_sizes, int n_in,
                              void* d_out, int out_size, void* d_ws, size_t ws_size,
                              hipStream_t stream) {
  const void* mov_x    = d_in[2];
  const int*  ei       = (const int*)d_in[3];
  const void* user_emb = d_in[4];
  const void* item_emb = d_in[5];

  char* ws = (char*)d_ws;
  size_t off = 0;
  auto alloc = [&](size_t bytes) -> void* {
    void* p = ws + off; off += (bytes + 255) / 256 * 256; return p;
  };
  int* flag   = (int*)alloc(4);
  __hip_bfloat16* arena = (__hip_bfloat16*)alloc(312832 * 2);
  __hip_bfloat16* Bt1 = (__hip_bfloat16*)alloc(272 * 192 * 2);
  __hip_bfloat16* Bt2 = (__hip_bfloat16*)alloc(272 * 256 * 2);
  __hip_bfloat16* W1t = (__hip_bfloat16*)alloc(128 * KPAD_C * 2);
  __hip_bfloat16* W2t = (__hip_bfloat16*)alloc(128 * 128 * 2);
  __hip_bfloat16* b1c = (__hip_bfloat16*)alloc(128 * 2);
  __hip_bfloat16* b2c = (__hip_bfloat16*)alloc(128 * 2);
  int* ptrn   = (int*)alloc((N_NODES_C + 1) * 4);
  int* deg    = (int*)alloc(N_NODES_C * 4);
  int* bsum   = (int*)alloc(512 * 4);
  int* elist  = (int*)alloc(E_TOT_C * 4);
  float* als  = (float*)alloc((size_t)N_NODES_C * 8 * 4);
  float* ald  = (float*)alloc((size_t)N_NODES_C * 8 * 4);
  __hip_bfloat16* x  = (__hip_bfloat16*)alloc((size_t)N_NODES_C * D_IN_C * 2); // 46.08 MB
  __hip_bfloat16* hs = (__hip_bfloat16*)alloc((size_t)N_NODES_C * HID_C * 2);  // 61.44 MB
  // d_out (f32, 122.88 MB) hosts two dead-before-aggregate2 temporaries:
  //   h1 (bf16 61.44 MB) at byte 0; mov_bf (bf16 46.08 MB) at byte 61,440,000.
  __hip_bfloat16* h1     = (__hip_bfloat16*)d_out;
  __hip_bfloat16* mov_bf = (__hip_bfloat16*)((char*)d_out + 61440000);
  __hip_bfloat16* hid    = hs;  // movie hidden (20000x128) parks in hs

  const int oWs1=0, oWd1=49152, oas1=98304, oad1=98560, ob1=98816,
            oWs2=99072, oWd2=164608, oas2=230144, oad2=230400, ob2=230656,
            ogW1=230912, ogb1=232192, ogW2=232256, ogb2=236352,
            otW1=236416, otb1=308608, otW2=308672, otb2=312768;

  detect_dtype<<<1, 256, 0, stream>>>((const unsigned short*)user_emb, flag);

  ConvArgs ca;
  const int srcidx[NCONV] = {14,15,16,17,18,19,20,21,22,23,6,7,8,9,10,11,12,13};
  const int offs[NCONV]   = {oWs1,oWd1,oas1,oad1,ob1,oWs2,oWd2,oas2,oad2,ob2,
                             ogW1,ogb1,ogW2,ogb2,otW1,otb1,otW2,otb2};
  const int ns[NCONV]     = {49152,49152,256,256,256,65536,65536,256,256,256,
                             1280,64,4096,64,72192,64,4096,64};
  for (int i = 0; i < NCONV; i++) { ca.src[i] = d_in[srcidx[i]]; ca.n[i] = ns[i]; ca.off[i] = offs[i]; }
  conv_small<<<NCONV * 8, 256, 0, stream>>>(ca, arena, flag);

  // movie feature path (MFMA)
  conv_movx<<<(int)(((long)N_ITEMS_C * KPAD_C + 255) / 256), 256, 0, stream>>>(
      mov_x, mov_bf, flag);
  prep_w1t<<<(128 * KPAD_C + 255) / 256, 256, 0, stream>>>(arena + ogW1, arena + otW1, W1t);
  prep_w2t<<<(128 * 128 + 255) / 256, 256, 0, stream>>>(arena + ogW2, arena + otW2, W2t);
  prep_movie_bias<<<1, 256, 0, stream>>>(arena + ogb1, arena + otb1,
                                         arena + ogb2, arena + otb2, b1c, b2c);
  assemble_x<<<(int)(((long)N_NODES_C * D_IN_C + 255) / 256), 256, 0, stream>>>(
      user_emb, item_emb, x, flag);
  movie_gemm<<<(N_ITEMS_C + 63) / 64, 256, 0, stream>>>(
      mov_bf, KPAD_C, N_ITEMS_C, W1t, KPAD_C, b1c, 1, hid, 128, 0);
  movie_gemm<<<(N_ITEMS_C + 63) / 64, 256, 0, stream>>>(
      hid, 128, N_ITEMS_C, W2t, 128, b2c, 0,
      x + (long)N_USERS_C * D_IN_C, D_IN_C, 64);

  prep_bt<<<(272 * 192 + 255) / 256, 256, 0, stream>>>(
      arena + oWs1, arena + oWd1, arena + oas1, arena + oad1, Bt1, 192, 8, 32);
  prep_bt<<<(272 * 256 + 255) / 256, 256, 0, stream>>>(
      arena + oWs2, arena + oWd2, arena + oas2, arena + oad2, Bt2, 256, 1, 256);

  // CSR of in-edges
  zero_deg<<<(N_NODES_C + 255) / 256, 256, 0, stream>>>(deg);
  deg_count<<<(E_TOT_C + 255) / 256, 256, 0, stream>>>(ei, deg);
  deg_bsum<<<NB_SCAN, 256, 0, stream>>>(deg, bsum);
  bsum_scan<<<1, 512, 0, stream>>>(bsum, ptrn);
  deg_scan_final<<<NB_SCAN, 256, 0, stream>>>(deg, bsum, ptrn);
  zero_deg<<<(N_NODES_C + 255) / 256, 256, 0, stream>>>(deg);
  scatter_edges<<<(E_TOT_C + 255) / 256, 256, 0, stream>>>(ei, ptrn, deg, elist);

  // layer 1 (ukmax=64: pure-user blocks skip the zero K-range)
  gemm_fused<<<N_NODES_C / 64, 256, 0, stream>>>(x, Bt1, hs, als, ald, 192, 8, 64);
  aggregate1<<<N_NODES_C / 4, 256, 0, stream>>>(ptrn, elist, als, ald, hs, arena + ob1, h1);

  // layer 2 (ukmax=K: disabled)
  gemm_fused<<<N_NODES_C / 64, 256, 0, stream>>>(h1, Bt2, hs, als, ald, 256, 1, 256);
  aggregate2<<<N_NODES_C / 4, 256, 0, stream>>>(ptrn, elist, als, ald, hs, arena + ob2,
                                                (float*)d_out);
  write_tail<<<1, 64, 0, stream>>>((float*)d_out, out_size);
}

// Round 7
// 621.291 us; speedup vs baseline: 1.9245x; 1.0900x over previous
//
#include <hip/hip_runtime.h>
#include <hip/hip_bf16.h>

#define N_USERS_C 100000
#define N_ITEMS_C 20000
#define N_NODES_C 120000
#define E_TOT_C   400000
#define D_IN_C    192
#define HID_C     256
#define NEG_C     0.2f
#define CLAMP_C   1000.0f
#define KPAD_C    1152   // 1148 padded to multiple of 32
#define NB_SCAN   ((N_NODES_C + 255) / 256)   // 469 scan blocks
#define ROWE      40     // LDS row length in shorts: 32 k-elems + 8 pad (80B, 16B-aligned)

typedef __attribute__((ext_vector_type(8))) short bfrag;
typedef __attribute__((ext_vector_type(4))) float ffrag;

__device__ __forceinline__ float bf2f(unsigned short u){
  return __uint_as_float(((unsigned)u) << 16);
}
__device__ __forceinline__ float ldf(const void* p, long i, int isf32){
  return isf32 ? ((const float*)p)[i] : bf2f(((const unsigned short*)p)[i]);
}
__device__ __forceinline__ float sane(float v){
  return (v > -1e30f && v < 1e30f) ? v : 0.f;
}
__device__ __forceinline__ int clampsrc(int s){
  return s < 0 ? 0 : (s >= N_NODES_C ? N_NODES_C - 1 : s);
}
__device__ __forceinline__ short f2bs(float f){
  __hip_bfloat16 h = __float2bfloat16(f);
  return *reinterpret_cast<short*>(&h);
}

// ---------- dtype discriminator (inputs) ----------
__global__ __launch_bounds__(256) void detect_dtype(const unsigned short* __restrict__ ue,
                                                    int* __restrict__ flag){
  __shared__ int cnt[256];
  int tid = threadIdx.x; int c = 0;
  for (int i = tid; i < 8192; i += 256){
    unsigned e = (ue[i] >> 7) & 0xFFu;
    if (e >= 129u) c++;
  }
  cnt[tid] = c; __syncthreads();
  if (tid == 0){
    int s = 0;
    for (int i = 0; i < 256; i++) s += cnt[i];
    *flag = (s > 100) ? 1 : 0;
  }
}

// ---------- MEGA-PREP: one launch for all independent prep work ----------
// Fuses: assemble_x (users+movies), prep_bt1/2, prep_w1t, prep_w2t, biases,
// deg/cursor zeroing. All read raw d_in via ldf(flag) -> no arena, no chains.
struct PrepArgs {
  const void *ue, *ie;
  const void *gW1, *gb1, *gW2, *gb2, *tW1, *tb1, *tW2, *tb2;
  const void *Ws1, *Wd1, *as1, *ad1, *b1, *Ws2, *Wd2, *as2, *ad2, *b2;
  __hip_bfloat16 *x, *Bt1, *Bt2, *W1t, *W2t, *b1c, *b2c, *bg1, *bg2;
  int *deg, *cursor;
  const int* flag;
};

#define NB_USER 75000   // 100000*192/256
#define NB_MOVE 5000    // 20000*64/256
#define NB_BT1  204     // 272*192/256
#define NB_BT2  272     // 272*256/256
#define NB_W1T  576     // 128*1152/256
#define NB_W2T  64      // 128*128/256
#define NB_ZERO 938     // ceil(240000/256)
#define NB_PREP (NB_USER + NB_MOVE + NB_BT1 + NB_BT2 + NB_W1T + NB_W2T + 1 + NB_ZERO)

__global__ __launch_bounds__(256) void mega_prep(PrepArgs a){
  int b = blockIdx.x, tid = threadIdx.x;
  int f32 = *a.flag;
  if (b < NB_USER) {                     // x user rows: emb | zeros
    int idx = b * 256 + tid;
    int n = idx / 192, c = idx - n * 192;
    a.x[idx] = __float2bfloat16(c < 64 ? ldf(a.ue, (long)n * 64 + c, f32) : 0.f);
    return;
  }
  b -= NB_USER;
  if (b < NB_MOVE) {                     // x movie rows, cols 0..63 = item_emb
    int idx = b * 256 + tid;
    int m = idx >> 6, c = idx & 63;
    a.x[(long)(N_USERS_C + m) * 192 + c] =
        __float2bfloat16(ldf(a.ie, (long)m * 64 + c, f32));
    return;
  }
  b -= NB_MOVE;
  if (b < NB_BT1) {                      // Bt1 (272 x 192): W^T | fold(Ws,a_s) | fold(Wd,a_d)
    int idx = b * 256 + tid;
    if (idx < 272 * 192) {
      int col = idx / 192, k = idx - col * 192;
      float v;
      if (col < 256) v = ldf(a.Ws1, k * 256 + col, f32);
      else if (col < 264) {
        int h = col - 256; float s = 0.f;
        for (int c = 0; c < 32; c++)
          s += ldf(a.Ws1, k * 256 + h * 32 + c, f32) * ldf(a.as1, h * 32 + c, f32);
        v = s;
      } else {
        int h = col - 264; float s = 0.f;
        for (int c = 0; c < 32; c++)
          s += ldf(a.Wd1, k * 256 + h * 32 + c, f32) * ldf(a.ad1, h * 32 + c, f32);
        v = s;
      }
      a.Bt1[col * 192 + k] = __float2bfloat16(v);
    }
    return;
  }
  b -= NB_BT1;
  if (b < NB_BT2) {                      // Bt2 (272 x 256), H=1, C=256
    int idx = b * 256 + tid;
    int col = idx / 256, k = idx & 255;
    float v;
    if (col < 256) v = ldf(a.Ws2, k * 256 + col, f32);
    else if (col == 256) {
      float s = 0.f;
      for (int c = 0; c < 256; c++)
        s += ldf(a.Ws2, k * 256 + c, f32) * ldf(a.as2, c, f32);
      v = s;
    } else if (col == 257) {
      float s = 0.f;
      for (int c = 0; c < 256; c++)
        s += ldf(a.Wd2, k * 256 + c, f32) * ldf(a.ad2, c, f32);
      v = s;
    } else v = 0.f;
    a.Bt2[col * 256 + k] = __float2bfloat16(v);
    return;
  }
  b -= NB_BT2;
  if (b < NB_W1T) {                      // W1t (128 x 1152)
    int idx = b * 256 + tid;
    int n = idx / 1152, k = idx - n * 1152;
    float v = 0.f;
    if (n < 64) { if (k < 20) v = ldf(a.gW1, k * 64 + n, f32); }
    else        { if (k >= 20 && k < 1148) v = ldf(a.tW1, (k - 20) * 64 + (n - 64), f32); }
    a.W1t[idx] = __float2bfloat16(v);
    return;
  }
  b -= NB_W1T;
  if (b < NB_W2T) {                      // W2t (128 x 128) blockdiag
    int idx = b * 256 + tid;
    int n = idx >> 7, k = idx & 127;
    float v = 0.f;
    if (n < 64) { if (k < 64)  v = ldf(a.gW2, k * 64 + n, f32); }
    else        { if (k >= 64) v = ldf(a.tW2, (k - 64) * 64 + (n - 64), f32); }
    a.W2t[idx] = __float2bfloat16(v);
    return;
  }
  b -= NB_W2T;
  if (b < 1) {                           // all bias vectors
    int i = tid;
    if (i < 64)       a.b1c[i] = __float2bfloat16(ldf(a.gb1, i, f32));
    else if (i < 128) a.b1c[i] = __float2bfloat16(ldf(a.tb1, i - 64, f32));
    else if (i < 192) a.b2c[i - 128] = __float2bfloat16(ldf(a.gb2, i - 128, f32));
    else              a.b2c[i - 128] = __float2bfloat16(ldf(a.tb2, i - 192, f32));
    a.bg1[tid] = __float2bfloat16(ldf(a.b1, tid, f32));
    a.bg2[tid] = __float2bfloat16(ldf(a.b2, tid, f32));
    return;
  }
  b -= 1;
  {                                      // zero deg + cursor
    int idx = b * 256 + tid;
    if (idx < N_NODES_C) a.deg[idx] = 0;
    else if (idx < 2 * N_NODES_C) a.cursor[idx - N_NODES_C] = 0;
  }
}

// MFMA GEMM, N=128 (8 n-tiles), M rows with guard, optional relu, bias add.
// LDS-staged A and B tiles per k-step; B shared across all 4 waves.
// rawA != nullptr: A is raw mov_x (20000 x 1148, f32-or-bf16 per *flag) converted
// during staging (conv_movx kernel + 138 MB of round-trip traffic eliminated).
__global__ __launch_bounds__(256) void movie_gemm(
    const __hip_bfloat16* __restrict__ A, int lda, int M,
    const void* __restrict__ rawA, const int* __restrict__ flag,
    const __hip_bfloat16* __restrict__ Bt, int K,
    const __hip_bfloat16* __restrict__ bias, int do_relu,
    __hip_bfloat16* __restrict__ out, int ldo, int ocol){
  __shared__ short Bls[128 * ROWE];   // 10.0 KB
  __shared__ short Als[64 * ROWE];    //  5.0 KB
  int tid = threadIdx.x;
  int wave = tid >> 6;
  int lane = tid & 63;
  int l15 = lane & 15;
  int quad = lane >> 4;
  int rowbase_blk = blockIdx.x * 64;
  int rowbase = rowbase_blk + wave * 16;
  int f32v = rawA ? *flag : 0;
  ffrag acc[8];
#pragma unroll
  for (int i = 0; i < 8; i++) acc[i] = (ffrag){0.f, 0.f, 0.f, 0.f};
  const short* As = (const short*)A;
  const short* Bs = (const short*)Bt;
  int sr = tid >> 2, sc = tid & 3;              // A-staging: row sr in [0,64), 16B chunk sc
  int arow_st = rowbase_blk + sr; if (arow_st >= M) arow_st = M - 1;
  for (int k0 = 0; k0 < K; k0 += 32) {
    __syncthreads();   // previous iter's LDS reads done before overwrite
    // stage B: 128 rows x 4 chunks = 512 tasks
    for (int t = tid; t < 512; t += 256) {
      int r = t >> 2, c = t & 3;
      *(float4*)(&Bls[r * ROWE + c * 8]) = *(const float4*)(Bs + (long)r * K + k0 + c * 8);
    }
    // stage A: 64 rows x 4 chunks = 256 tasks (one per thread)
    int kc = k0 + sc * 8;
    if (rawA) {
      union { short s[8]; float4 f; } u;
      long base = (long)arow_st * 1148 + kc;
      if (kc + 8 <= 1148) {
        if (f32v) {
          const float* rf = (const float*)rawA + base;   // 16B-aligned (4592%16==0, kc%8==0)
          float4 x0 = *(const float4*)rf;
          float4 x1 = *(const float4*)(rf + 4);
          u.s[0]=f2bs(x0.x); u.s[1]=f2bs(x0.y); u.s[2]=f2bs(x0.z); u.s[3]=f2bs(x0.w);
          u.s[4]=f2bs(x1.x); u.s[5]=f2bs(x1.y); u.s[6]=f2bs(x1.z); u.s[7]=f2bs(x1.w);
        } else {
          const unsigned short* rs = (const unsigned short*)rawA + base;  // 8B-aligned
          ushort4 a0 = *(const ushort4*)rs;
          ushort4 a1 = *(const ushort4*)(rs + 4);
          u.s[0]=(short)a0.x; u.s[1]=(short)a0.y; u.s[2]=(short)a0.z; u.s[3]=(short)a0.w;
          u.s[4]=(short)a1.x; u.s[5]=(short)a1.y; u.s[6]=(short)a1.z; u.s[7]=(short)a1.w;
        }
      } else {
#pragma unroll
        for (int j = 0; j < 8; j++) {
          float v = (kc + j < 1148) ? ldf(rawA, base + j, f32v) : 0.f;
          u.s[j] = f2bs(v);
        }
      }
      *(float4*)(&Als[sr * ROWE + sc * 8]) = u.f;
    } else {
      *(float4*)(&Als[sr * ROWE + sc * 8]) =
          *(const float4*)(As + (long)arow_st * lda + kc);
    }
    __syncthreads();
    int koff = quad * 8;
    bfrag af = *(const bfrag*)(&Als[(wave * 16 + l15) * ROWE + koff]);
#pragma unroll
    for (int nt = 0; nt < 8; nt++) {
      bfrag bf = *(const bfrag*)(&Bls[(nt * 16 + l15) * ROWE + koff]);
      acc[nt] = __builtin_amdgcn_mfma_f32_16x16x32_bf16(af, bf, acc[nt], 0, 0, 0);
    }
  }
#pragma unroll
  for (int reg = 0; reg < 4; reg++) {
    int grow = rowbase + quad * 4 + reg;
    if (grow >= M) continue;
#pragma unroll
    for (int nt = 0; nt < 8; nt++) {
      float v = acc[nt][reg] + __bfloat162float(bias[nt * 16 + l15]);
      if (do_relu) v = fmaxf(v, 0.f);
      out[(long)grow * ldo + ocol + nt * 16 + l15] = __float2bfloat16(v);
    }
  }
}

// MFMA GEMM: A (M x K bf16) @ Bt^T -> Hout (M x 256 bf16) + als/ald (f32, M x natt).
// LDS-staged A and B per k-step; B shared by all 4 waves.
// ukmax: K-bound for blocks whose 64 rows are ALL users (x cols 64..K-1 are zero ->
// skipped K-range contributes exactly 0). Layer 1 passes 64; layer 2 passes K.
__global__ __launch_bounds__(256) void gemm_fused(
    const __hip_bfloat16* __restrict__ A, const __hip_bfloat16* __restrict__ Bt,
    __hip_bfloat16* __restrict__ Hout, float* __restrict__ als, float* __restrict__ ald,
    int K, int natt, int ukmax){
  __shared__ short Bls[272 * ROWE];   // 21.25 KB
  __shared__ short Als[64 * ROWE];    //  5.0 KB
  int tid = threadIdx.x;
  int wave = tid >> 6;
  int lane = tid & 63;
  int l15 = lane & 15;
  int quad = lane >> 4;
  int rowbase_blk = blockIdx.x * 64;
  int rowbase = rowbase_blk + wave * 16;
  int kmax = (rowbase_blk + 64 <= N_USERS_C) ? ukmax : K;
  ffrag acc[17];
#pragma unroll
  for (int i = 0; i < 17; i++) acc[i] = (ffrag){0.f, 0.f, 0.f, 0.f};
  const short* As = (const short*)A;
  const short* Bs = (const short*)Bt;
  int sr = tid >> 2, sc = tid & 3;   // A-staging row/chunk
  for (int k0 = 0; k0 < kmax; k0 += 32) {
    __syncthreads();
    // stage B: 272 rows x 4 chunks = 1088 tasks
    for (int t = tid; t < 1088; t += 256) {
      int r = t >> 2, c = t & 3;
      *(float4*)(&Bls[r * ROWE + c * 8]) = *(const float4*)(Bs + (long)r * K + k0 + c * 8);
    }
    // stage A: 64 rows x 4 chunks (grid is exact: rowbase_blk+63 < 120000)
    *(float4*)(&Als[sr * ROWE + sc * 8]) =
        *(const float4*)(As + (long)(rowbase_blk + sr) * K + k0 + sc * 8);
    __syncthreads();
    int koff = quad * 8;
    bfrag af = *(const bfrag*)(&Als[(wave * 16 + l15) * ROWE + koff]);
#pragma unroll
    for (int nt = 0; nt < 17; nt++) {
      bfrag bf = *(const bfrag*)(&Bls[(nt * 16 + l15) * ROWE + koff]);
      acc[nt] = __builtin_amdgcn_mfma_f32_16x16x32_bf16(af, bf, acc[nt], 0, 0, 0);
    }
  }
  int col = l15;
#pragma unroll
  for (int reg = 0; reg < 4; reg++) {
    int grow = rowbase + quad * 4 + reg;
    long obase = (long)grow * 256;
#pragma unroll
    for (int nt = 0; nt < 16; nt++)
      Hout[obase + nt * 16 + col] = __float2bfloat16(acc[nt][reg]);
    float v = acc[16][reg];
    if (col < natt) als[grow * natt + col] = v;
    else if (col < 2 * natt) ald[grow * natt + (col - natt)] = v;
  }
}

// ---------- CSR build (in-edges per dst) ----------
__global__ void deg_count(const int* __restrict__ ei, int* __restrict__ deg){
  int e = blockIdx.x * 256 + threadIdx.x;
  if (e >= E_TOT_C) return;
  int dst = ei[E_TOT_C + e];
  if (dst >= 0 && dst < N_NODES_C) atomicAdd(&deg[dst], 1);
}

// Stage 1: per-block (256-wide) sums.
__global__ __launch_bounds__(256) void deg_bsum(const int* __restrict__ deg,
                                                int* __restrict__ bsum){
  int i = blockIdx.x * 256 + threadIdx.x;
  int v = (i < N_NODES_C) ? deg[i] : 0;
#pragma unroll
  for (int o = 32; o > 0; o >>= 1) v += __shfl_down(v, o, 64);
  __shared__ int ws[4];
  int wave = threadIdx.x >> 6, lane = threadIdx.x & 63;
  if (lane == 0) ws[wave] = v;
  __syncthreads();
  if (threadIdx.x == 0) bsum[blockIdx.x] = ws[0] + ws[1] + ws[2] + ws[3];
}

// Stage 2: single-block Hillis-Steele scan of 469 block sums -> exclusive offsets.
__global__ __launch_bounds__(512) void bsum_scan(int* __restrict__ bsum,
                                                 int* __restrict__ ptrn){
  __shared__ int sm[512];
  int t = threadIdx.x;
  int v = (t < NB_SCAN) ? bsum[t] : 0;
  sm[t] = v;
  __syncthreads();
  for (int o = 1; o < 512; o <<= 1) {
    int add = (t >= o) ? sm[t - o] : 0;
    __syncthreads();
    sm[t] += add;
    __syncthreads();
  }
  int excl = (t == 0) ? 0 : sm[t - 1];
  if (t < NB_SCAN) bsum[t] = excl;
  if (t == NB_SCAN - 1) ptrn[N_NODES_C] = sm[t];
}

// Stage 3: in-block exclusive scan + block offset -> ptrn.
__global__ __launch_bounds__(256) void deg_scan_final(const int* __restrict__ deg,
                                                      const int* __restrict__ bexcl,
                                                      int* __restrict__ ptrn){
  __shared__ int sm[256];
  int i = blockIdx.x * 256 + threadIdx.x;
  int t = threadIdx.x;
  int v = (i < N_NODES_C) ? deg[i] : 0;
  sm[t] = v;
  __syncthreads();
  for (int o = 1; o < 256; o <<= 1) {
    int add = (t >= o) ? sm[t - o] : 0;
    __syncthreads();
    sm[t] += add;
    __syncthreads();
  }
  int excl = (t == 0) ? 0 : sm[t - 1];
  if (i < N_NODES_C) ptrn[i] = bexcl[blockIdx.x] + excl;
}

__global__ void scatter_edges(const int* __restrict__ ei, const int* __restrict__ ptrn,
                              int* __restrict__ cursor, int* __restrict__ elist_src){
  int e = blockIdx.x * 256 + threadIdx.x;
  if (e >= E_TOT_C) return;
  int dst = ei[E_TOT_C + e];
  if (dst < 0 || dst >= N_NODES_C) return;
  int pos = atomicAdd(&cursor[dst], 1);
  elist_src[ptrn[dst] + pos] = ei[e];
}

// ---------- layer 1: online-softmax aggregation, 2-deep software-pipelined gathers ----
__global__ __launch_bounds__(256) void aggregate1(
    const int* __restrict__ ptrn, const int* __restrict__ elist_src,
    const float* __restrict__ als, const float* __restrict__ ald,
    const __hip_bfloat16* __restrict__ hs, const __hip_bfloat16* __restrict__ bias,
    __hip_bfloat16* __restrict__ h1){
  int node = blockIdx.x * 4 + (threadIdx.x >> 6);
  if (node >= N_NODES_C) return;
  int lane = threadIdx.x & 63;
  int c0 = lane * 4;
  int h = lane >> 3;
  int beg = ptrn[node], end = ptrn[node + 1];
  float aldv = sane(ald[node * 8 + h]);
  float m = -1e30f;
  float wsum = 0.f, a0 = 0.f, a1 = 0.f, a2 = 0.f, a3 = 0.f;
  const unsigned short* hsu = (const unsigned short*)hs;
  float alsv_p = 0.f;
  ushort4 hv_p = {0, 0, 0, 0};
  int src_b = 0;
  if (beg < end) {
    int s0 = clampsrc(elist_src[beg]);
    alsv_p = als[(long)s0 * 8 + h];
    hv_p = *(const ushort4*)(hsu + (long)s0 * 256 + c0);
    if (beg + 1 < end) src_b = clampsrc(elist_src[beg + 1]);
  }
  for (int i = beg; i < end; i++) {
    float alsv = alsv_p;
    ushort4 hv = hv_p;
    if (i + 1 < end) {           // issue next-edge gathers before this edge's compute
      alsv_p = als[(long)src_b * 8 + h];
      hv_p = *(const ushort4*)(hsu + (long)src_b * 256 + c0);
    }
    if (i + 2 < end)             // and the src index one further ahead
      src_b = clampsrc(elist_src[i + 2]);
    float ev = sane(alsv) + aldv;
    ev = ev > 0.f ? ev : NEG_C * ev;
    float mnew = fmaxf(m, ev);
    float corr = __expf(m - mnew);   // first iter: exp(-inf)=0 zeroes empty history
    float w = __expf(ev - mnew);
    m = mnew;
    wsum = wsum * corr + w;
    a0 = a0 * corr + w * bf2f(hv.x); a1 = a1 * corr + w * bf2f(hv.y);
    a2 = a2 * corr + w * bf2f(hv.z); a3 = a3 * corr + w * bf2f(hv.w);
  }
  float inv = 1.f / (wsum + 1e-16f);
  float v0 = a0 * inv + __bfloat162float(bias[c0 + 0]);
  float v1 = a1 * inv + __bfloat162float(bias[c0 + 1]);
  float v2 = a2 * inv + __bfloat162float(bias[c0 + 2]);
  float v3 = a3 * inv + __bfloat162float(bias[c0 + 3]);
  v0 = v0 > 0.f ? v0 : (__expf(v0) - 1.f);
  v1 = v1 > 0.f ? v1 : (__expf(v1) - 1.f);
  v2 = v2 > 0.f ? v2 : (__expf(v2) - 1.f);
  v3 = v3 > 0.f ? v3 : (__expf(v3) - 1.f);
  v0 = fminf(fmaxf(v0, -CLAMP_C), CLAMP_C);
  v1 = fminf(fmaxf(v1, -CLAMP_C), CLAMP_C);
  v2 = fminf(fmaxf(v2, -CLAMP_C), CLAMP_C);
  v3 = fminf(fmaxf(v3, -CLAMP_C), CLAMP_C);
  long ob = (long)node * 256 + c0;
  h1[ob + 0] = __float2bfloat16(v0); h1[ob + 1] = __float2bfloat16(v1);
  h1[ob + 2] = __float2bfloat16(v2); h1[ob + 3] = __float2bfloat16(v3);
}

// ---------- layer 2: online softmax, pipelined, 1 head, f32 output (+tail fold) -----
__global__ __launch_bounds__(256) void aggregate2(
    const int* __restrict__ ptrn, const int* __restrict__ elist_src,
    const float* __restrict__ als, const float* __restrict__ ald,
    const __hip_bfloat16* __restrict__ hs, const __hip_bfloat16* __restrict__ bias,
    float* __restrict__ out, int out_size){
  if (blockIdx.x == 0 && threadIdx.x == 0) {   // write_tail folded (disjoint indices)
    out[out_size - 3] = 0.f;
    out[out_size - 2] = (float)N_USERS_C;
    out[out_size - 1] = (float)N_NODES_C;
  }
  int node = blockIdx.x * 4 + (threadIdx.x >> 6);
  if (node >= N_NODES_C) return;
  int lane = threadIdx.x & 63;
  int c0 = lane * 4;
  int beg = ptrn[node], end = ptrn[node + 1];
  float aldv = sane(ald[node]);
  float m = -1e30f;
  float wsum = 0.f, a0 = 0.f, a1 = 0.f, a2 = 0.f, a3 = 0.f;
  const unsigned short* hsu = (const unsigned short*)hs;
  float alsv_p = 0.f;
  ushort4 hv_p = {0, 0, 0, 0};
  int src_b = 0;
  if (beg < end) {
    int s0 = clampsrc(elist_src[beg]);
    alsv_p = als[s0];
    hv_p = *(const ushort4*)(hsu + (long)s0 * 256 + c0);
    if (beg + 1 < end) src_b = clampsrc(elist_src[beg + 1]);
  }
  for (int i = beg; i < end; i++) {
    float alsv = alsv_p;
    ushort4 hv = hv_p;
    if (i + 1 < end) {
      alsv_p = als[src_b];
      hv_p = *(const ushort4*)(hsu + (long)src_b * 256 + c0);
    }
    if (i + 2 < end)
      src_b = clampsrc(elist_src[i + 2]);
    float ev = sane(alsv) + aldv;
    ev = ev > 0.f ? ev : NEG_C * ev;
    float mnew = fmaxf(m, ev);
    float corr = __expf(m - mnew);
    float w = __expf(ev - mnew);
    m = mnew;
    wsum = wsum * corr + w;
    a0 = a0 * corr + w * bf2f(hv.x); a1 = a1 * corr + w * bf2f(hv.y);
    a2 = a2 * corr + w * bf2f(hv.z); a3 = a3 * corr + w * bf2f(hv.w);
  }
  float inv = 1.f / (wsum + 1e-16f);
  float4 v;
  v.x = a0 * inv + __bfloat162float(bias[c0 + 0]);
  v.y = a1 * inv + __bfloat162float(bias[c0 + 1]);
  v.z = a2 * inv + __bfloat162float(bias[c0 + 2]);
  v.w = a3 * inv + __bfloat162float(bias[c0 + 3]);
  v.x = fminf(fmaxf(v.x, -CLAMP_C), CLAMP_C);
  v.y = fminf(fmaxf(v.y, -CLAMP_C), CLAMP_C);
  v.z = fminf(fmaxf(v.z, -CLAMP_C), CLAMP_C);
  v.w = fminf(fmaxf(v.w, -CLAMP_C), CLAMP_C);
  *(float4*)(out + (long)node * 256 + c0) = v;
}

extern "C" void kernel_launch(void* const* d_in, const int* in_sizes, int n_in,
                              void* d_out, int out_size, void* d_ws, size_t ws_size,
                              hipStream_t stream) {
  const void* mov_x    = d_in[2];
  const int*  ei       = (const int*)d_in[3];
  const void* user_emb = d_in[4];
  const void* item_emb = d_in[5];

  char* ws = (char*)d_ws;
  size_t off = 0;
  auto alloc = [&](size_t bytes) -> void* {
    void* p = ws + off; off += (bytes + 255) / 256 * 256; return p;
  };
  int* flag   = (int*)alloc(4);
  __hip_bfloat16* Bt1 = (__hip_bfloat16*)alloc(272 * 192 * 2);
  __hip_bfloat16* Bt2 = (__hip_bfloat16*)alloc(272 * 256 * 2);
  __hip_bfloat16* W1t = (__hip_bfloat16*)alloc(128 * KPAD_C * 2);
  __hip_bfloat16* W2t = (__hip_bfloat16*)alloc(128 * 128 * 2);
  __hip_bfloat16* b1c = (__hip_bfloat16*)alloc(128 * 2);
  __hip_bfloat16* b2c = (__hip_bfloat16*)alloc(128 * 2);
  __hip_bfloat16* bg1 = (__hip_bfloat16*)alloc(256 * 2);
  __hip_bfloat16* bg2 = (__hip_bfloat16*)alloc(256 * 2);
  int* ptrn   = (int*)alloc((N_NODES_C + 1) * 4);
  int* deg    = (int*)alloc(N_NODES_C * 4);
  int* cursor = (int*)alloc(N_NODES_C * 4);
  int* bsum   = (int*)alloc(512 * 4);
  int* elist  = (int*)alloc(E_TOT_C * 4);
  float* als  = (float*)alloc((size_t)N_NODES_C * 8 * 4);
  float* ald  = (float*)alloc((size_t)N_NODES_C * 8 * 4);
  __hip_bfloat16* x  = (__hip_bfloat16*)alloc((size_t)N_NODES_C * D_IN_C * 2); // 46.08 MB
  __hip_bfloat16* hs = (__hip_bfloat16*)alloc((size_t)N_NODES_C * HID_C * 2);  // 61.44 MB
  // d_out (f32, 122.88 MB) hosts h1 (bf16, dead before aggregate2) at byte 0.
  __hip_bfloat16* h1  = (__hip_bfloat16*)d_out;
  __hip_bfloat16* hid = hs;  // movie hidden (20000x128) parks in hs

  detect_dtype<<<1, 256, 0, stream>>>((const unsigned short*)user_emb, flag);

  PrepArgs pa;
  pa.ue = user_emb; pa.ie = item_emb;
  pa.gW1 = d_in[6];  pa.gb1 = d_in[7];  pa.gW2 = d_in[8];  pa.gb2 = d_in[9];
  pa.tW1 = d_in[10]; pa.tb1 = d_in[11]; pa.tW2 = d_in[12]; pa.tb2 = d_in[13];
  pa.Ws1 = d_in[14]; pa.Wd1 = d_in[15]; pa.as1 = d_in[16]; pa.ad1 = d_in[17]; pa.b1 = d_in[18];
  pa.Ws2 = d_in[19]; pa.Wd2 = d_in[20]; pa.as2 = d_in[21]; pa.ad2 = d_in[22]; pa.b2 = d_in[23];
  pa.x = x; pa.Bt1 = Bt1; pa.Bt2 = Bt2; pa.W1t = W1t; pa.W2t = W2t;
  pa.b1c = b1c; pa.b2c = b2c; pa.bg1 = bg1; pa.bg2 = bg2;
  pa.deg = deg; pa.cursor = cursor; pa.flag = flag;
  mega_prep<<<NB_PREP, 256, 0, stream>>>(pa);

  // movie feature path (raw mov_x converted during staging; conv_movx eliminated)
  movie_gemm<<<(N_ITEMS_C + 63) / 64, 256, 0, stream>>>(
      nullptr, 0, N_ITEMS_C, mov_x, flag, W1t, KPAD_C, b1c, 1, hid, 128, 0);
  movie_gemm<<<(N_ITEMS_C + 63) / 64, 256, 0, stream>>>(
      hid, 128, N_ITEMS_C, nullptr, flag, W2t, 128, b2c, 0,
      x + (long)N_USERS_C * D_IN_C, D_IN_C, 64);

  // CSR of in-edges (deg/cursor pre-zeroed by mega_prep)
  deg_count<<<(E_TOT_C + 255) / 256, 256, 0, stream>>>(ei, deg);
  deg_bsum<<<NB_SCAN, 256, 0, stream>>>(deg, bsum);
  bsum_scan<<<1, 512, 0, stream>>>(bsum, ptrn);
  deg_scan_final<<<NB_SCAN, 256, 0, stream>>>(deg, bsum, ptrn);
  scatter_edges<<<(E_TOT_C + 255) / 256, 256, 0, stream>>>(ei, ptrn, cursor, elist);

  // layer 1 (ukmax=64: pure-user blocks skip the zero K-range)
  gemm_fused<<<N_NODES_C / 64, 256, 0, stream>>>(x, Bt1, hs, als, ald, 192, 8, 64);
  aggregate1<<<N_NODES_C / 4, 256, 0, stream>>>(ptrn, elist, als, ald, hs, bg1, h1);

  // layer 2 (ukmax=K: disabled)
  gemm_fused<<<N_NODES_C / 64, 256, 0, stream>>>(h1, Bt2, hs, als, ald, 256, 1, 256);
  aggregate2<<<N_NODES_C / 4, 256, 0, stream>>>(ptrn, elist, als, ald, hs, bg2,
                                                (float*)d_out, out_size);
}

// Round 8
// 588.019 us; speedup vs baseline: 2.0334x; 1.0566x over previous
//
#include <hip/hip_runtime.h>
#include <hip/hip_bf16.h>

#define N_USERS_C 100000
#define N_ITEMS_C 20000
#define N_NODES_C 120000
#define E_TOT_C   400000
#define D_IN_C    192
#define HID_C     256
#define NEG_C     0.2f
#define CLAMP_C   1000.0f
#define KPAD_C    1152   // 1148 padded to multiple of 32
#define NB_SCAN   ((N_NODES_C + 255) / 256)   // 469 scan blocks
#define ROWE      40     // LDS row length in shorts: 32 k-elems + 8 pad (80B, 16B-aligned)

typedef __attribute__((ext_vector_type(8))) short bfrag;
typedef __attribute__((ext_vector_type(4))) float ffrag;

__device__ __forceinline__ float bf2f(unsigned short u){
  return __uint_as_float(((unsigned)u) << 16);
}
__device__ __forceinline__ float ldf(const void* p, long i, int isf32){
  return isf32 ? ((const float*)p)[i] : bf2f(((const unsigned short*)p)[i]);
}
__device__ __forceinline__ float sane(float v){
  return (v > -1e30f && v < 1e30f) ? v : 0.f;
}
__device__ __forceinline__ int clampsrc(int s){
  return s < 0 ? 0 : (s >= N_NODES_C ? N_NODES_C - 1 : s);
}
__device__ __forceinline__ short f2bs(float f){
  __hip_bfloat16 h = __float2bfloat16(f);
  return *reinterpret_cast<short*>(&h);
}

// ---------- dtype discriminator (inputs) ----------
__global__ __launch_bounds__(256) void detect_dtype(const unsigned short* __restrict__ ue,
                                                    int* __restrict__ flag){
  __shared__ int cnt[256];
  int tid = threadIdx.x; int c = 0;
  for (int i = tid; i < 8192; i += 256){
    unsigned e = (ue[i] >> 7) & 0xFFu;
    if (e >= 129u) c++;
  }
  cnt[tid] = c; __syncthreads();
  if (tid == 0){
    int s = 0;
    for (int i = 0; i < 256; i++) s += cnt[i];
    *flag = (s > 100) ? 1 : 0;
  }
}

// ---------- MEGA-PREP: one launch, 8-elems/thread vectorized (G13) ----------
// assemble_x writes ONLY what is later read: user cols 0..63, boundary-block user rows
// 99968..99999 cols 64..191 (zeros), movie cols 0..63. Pure-user gemm blocks run
// kmax=64 and never touch user cols 64..191.
struct PrepArgs {
  const void *ue, *ie;
  const void *gW1, *gb1, *gW2, *gb2, *tW1, *tb1, *tW2, *tb2;
  const void *Ws1, *Wd1, *as1, *ad1, *b1, *Ws2, *Wd2, *as2, *ad2, *b2;
  __hip_bfloat16 *x, *Bt1, *Bt2, *W1t, *W2t, *b1c, *b2c, *bg1, *bg2;
  int *deg, *cursor;
  const int* flag;
};

#define NB_UEMB  3125   // 100000*64 /8 /256
#define NB_UZERO 2      // 32 rows x 128 cols /8 /256
#define NB_MOVE  625    // 20000*64 /8 /256
#define NB_BT1   204    // 272*192 /256 (scalar)
#define NB_BT2   272    // 272*256 /256 (scalar)
#define NB_W1T   72     // 128*1152 /8 /256
#define NB_W2T   8      // 128*128 /8 /256
#define NB_ZERO  235    // 240000 ints /4 /256
#define NB_PREP (NB_UEMB+NB_UZERO+NB_MOVE+NB_BT1+NB_BT2+NB_W1T+NB_W2T+1+NB_ZERO)

__global__ __launch_bounds__(256) void mega_prep(PrepArgs a){
  int b = blockIdx.x, tid = threadIdx.x;
  int f32 = *a.flag;
  if (b < NB_UEMB) {                     // x user rows cols 0..63, 8 elems/thread
    int idx = b * 256 + tid;             // < 800000
    int n = idx >> 3, c0 = (idx & 7) * 8;
    union { short s[8]; float4 f; } u;
    if (f32) {
      const float* rf = (const float*)a.ue + (long)n * 64 + c0;   // 32B-aligned
      float4 x0 = *(const float4*)rf, x1 = *(const float4*)(rf + 4);
      u.s[0]=f2bs(x0.x); u.s[1]=f2bs(x0.y); u.s[2]=f2bs(x0.z); u.s[3]=f2bs(x0.w);
      u.s[4]=f2bs(x1.x); u.s[5]=f2bs(x1.y); u.s[6]=f2bs(x1.z); u.s[7]=f2bs(x1.w);
    } else {
      u.f = *(const float4*)((const unsigned short*)a.ue + (long)n * 64 + c0);
    }
    *(float4*)(&a.x[(long)n * 192 + c0]) = u.f;
    return;
  }
  b -= NB_UEMB;
  if (b < NB_UZERO) {                    // boundary user rows 99968..99999, cols 64..191 = 0
    int idx = b * 256 + tid;             // < 512
    int r = idx >> 4, c0 = 64 + (idx & 15) * 8;
    float4 z = {0.f, 0.f, 0.f, 0.f};
    *(float4*)(&a.x[(long)(99968 + r) * 192 + c0]) = z;
    return;
  }
  b -= NB_UZERO;
  if (b < NB_MOVE) {                     // x movie rows cols 0..63 = item_emb
    int idx = b * 256 + tid;             // < 160000
    int m = idx >> 3, c0 = (idx & 7) * 8;
    union { short s[8]; float4 f; } u;
    if (f32) {
      const float* rf = (const float*)a.ie + (long)m * 64 + c0;
      float4 x0 = *(const float4*)rf, x1 = *(const float4*)(rf + 4);
      u.s[0]=f2bs(x0.x); u.s[1]=f2bs(x0.y); u.s[2]=f2bs(x0.z); u.s[3]=f2bs(x0.w);
      u.s[4]=f2bs(x1.x); u.s[5]=f2bs(x1.y); u.s[6]=f2bs(x1.z); u.s[7]=f2bs(x1.w);
    } else {
      u.f = *(const float4*)((const unsigned short*)a.ie + (long)m * 64 + c0);
    }
    *(float4*)(&a.x[(long)(N_USERS_C + m) * 192 + c0]) = u.f;
    return;
  }
  b -= NB_MOVE;
  if (b < NB_BT1) {                      // Bt1 (272 x 192): W^T | fold(Ws,a_s) | fold(Wd,a_d)
    int idx = b * 256 + tid;             // exact: 204*256 == 272*192
    int col = idx / 192, k = idx - col * 192;
    float v;
    if (col < 256) v = ldf(a.Ws1, k * 256 + col, f32);
    else if (col < 264) {
      int h = col - 256; float s = 0.f;
      for (int c = 0; c < 32; c++)
        s += ldf(a.Ws1, k * 256 + h * 32 + c, f32) * ldf(a.as1, h * 32 + c, f32);
      v = s;
    } else {
      int h = col - 264; float s = 0.f;
      for (int c = 0; c < 32; c++)
        s += ldf(a.Wd1, k * 256 + h * 32 + c, f32) * ldf(a.ad1, h * 32 + c, f32);
      v = s;
    }
    a.Bt1[col * 192 + k] = __float2bfloat16(v);
    return;
  }
  b -= NB_BT1;
  if (b < NB_BT2) {                      // Bt2 (272 x 256), H=1, C=256
    int idx = b * 256 + tid;
    int col = idx / 256, k = idx & 255;
    float v;
    if (col < 256) v = ldf(a.Ws2, k * 256 + col, f32);
    else if (col == 256) {
      float s = 0.f;
      for (int c = 0; c < 256; c++)
        s += ldf(a.Ws2, k * 256 + c, f32) * ldf(a.as2, c, f32);
      v = s;
    } else if (col == 257) {
      float s = 0.f;
      for (int c = 0; c < 256; c++)
        s += ldf(a.Wd2, k * 256 + c, f32) * ldf(a.ad2, c, f32);
      v = s;
    } else v = 0.f;
    a.Bt2[col * 256 + k] = __float2bfloat16(v);
    return;
  }
  b -= NB_BT2;
  if (b < NB_W1T) {                      // W1t (128 x 1152), 8 elems/thread
    int idx = b * 256 + tid;             // < 18432
    int n = idx / 144, c8 = idx - n * 144;
    int k0 = c8 * 8;
    union { short s[8]; float4 f; } u;
#pragma unroll
    for (int j = 0; j < 8; j++) {
      int k = k0 + j; float v = 0.f;
      if (n < 64) { if (k < 20) v = ldf(a.gW1, k * 64 + n, f32); }
      else        { if (k >= 20 && k < 1148) v = ldf(a.tW1, (k - 20) * 64 + (n - 64), f32); }
      u.s[j] = f2bs(v);
    }
    *(float4*)(&a.W1t[(long)n * 1152 + k0]) = u.f;
    return;
  }
  b -= NB_W1T;
  if (b < NB_W2T) {                      // W2t (128 x 128) blockdiag, 8 elems/thread
    int idx = b * 256 + tid;             // < 2048
    int n = idx >> 4, k0 = (idx & 15) * 8;
    union { short s[8]; float4 f; } u;
#pragma unroll
    for (int j = 0; j < 8; j++) {
      int k = k0 + j; float v = 0.f;
      if (n < 64) { if (k < 64)  v = ldf(a.gW2, k * 64 + n, f32); }
      else        { if (k >= 64) v = ldf(a.tW2, (k - 64) * 64 + (n - 64), f32); }
      u.s[j] = f2bs(v);
    }
    *(float4*)(&a.W2t[n * 128 + k0]) = u.f;
    return;
  }
  b -= NB_W2T;
  if (b < 1) {                           // all bias vectors
    int i = tid;
    if (i < 64)       a.b1c[i] = __float2bfloat16(ldf(a.gb1, i, f32));
    else if (i < 128) a.b1c[i] = __float2bfloat16(ldf(a.tb1, i - 64, f32));
    else if (i < 192) a.b2c[i - 128] = __float2bfloat16(ldf(a.gb2, i - 128, f32));
    else              a.b2c[i - 128] = __float2bfloat16(ldf(a.tb2, i - 192, f32));
    a.bg1[tid] = __float2bfloat16(ldf(a.b1, tid, f32));
    a.bg2[tid] = __float2bfloat16(ldf(a.b2, tid, f32));
    return;
  }
  b -= 1;
  {                                      // zero deg + cursor, int4/thread
    int i0 = (b * 256 + tid) * 4;
    if (i0 < 2 * N_NODES_C) {
      int4 z = {0, 0, 0, 0};
      if (i0 < N_NODES_C) *(int4*)(a.deg + i0) = z;
      else                *(int4*)(a.cursor + (i0 - N_NODES_C)) = z;
    }
  }
}

// MFMA GEMM, N=128 (8 n-tiles), M rows with guard, optional relu, bias add.
// LDS-staged A and B tiles per k-step; B shared across all 4 waves.
// rawA != nullptr: A is raw mov_x (20000 x 1148, f32-or-bf16 per *flag) converted
// during staging (conv_movx kernel + 138 MB of round-trip traffic eliminated).
__global__ __launch_bounds__(256) void movie_gemm(
    const __hip_bfloat16* __restrict__ A, int lda, int M,
    const void* __restrict__ rawA, const int* __restrict__ flag,
    const __hip_bfloat16* __restrict__ Bt, int K,
    const __hip_bfloat16* __restrict__ bias, int do_relu,
    __hip_bfloat16* __restrict__ out, int ldo, int ocol){
  __shared__ short Bls[128 * ROWE];   // 10.0 KB
  __shared__ short Als[64 * ROWE];    //  5.0 KB
  int tid = threadIdx.x;
  int wave = tid >> 6;
  int lane = tid & 63;
  int l15 = lane & 15;
  int quad = lane >> 4;
  int rowbase_blk = blockIdx.x * 64;
  int rowbase = rowbase_blk + wave * 16;
  int f32v = rawA ? *flag : 0;
  ffrag acc[8];
#pragma unroll
  for (int i = 0; i < 8; i++) acc[i] = (ffrag){0.f, 0.f, 0.f, 0.f};
  const short* As = (const short*)A;
  const short* Bs = (const short*)Bt;
  int sr = tid >> 2, sc = tid & 3;              // A-staging: row sr in [0,64), 16B chunk sc
  int arow_st = rowbase_blk + sr; if (arow_st >= M) arow_st = M - 1;
  for (int k0 = 0; k0 < K; k0 += 32) {
    __syncthreads();   // previous iter's LDS reads done before overwrite
    // stage B: 128 rows x 4 chunks = 512 tasks
    for (int t = tid; t < 512; t += 256) {
      int r = t >> 2, c = t & 3;
      *(float4*)(&Bls[r * ROWE + c * 8]) = *(const float4*)(Bs + (long)r * K + k0 + c * 8);
    }
    // stage A: 64 rows x 4 chunks = 256 tasks (one per thread)
    int kc = k0 + sc * 8;
    if (rawA) {
      union { short s[8]; float4 f; } u;
      long base = (long)arow_st * 1148 + kc;
      if (kc + 8 <= 1148) {
        if (f32v) {
          const float* rf = (const float*)rawA + base;   // 16B-aligned (4592%16==0, kc%8==0)
          float4 x0 = *(const float4*)rf;
          float4 x1 = *(const float4*)(rf + 4);
          u.s[0]=f2bs(x0.x); u.s[1]=f2bs(x0.y); u.s[2]=f2bs(x0.z); u.s[3]=f2bs(x0.w);
          u.s[4]=f2bs(x1.x); u.s[5]=f2bs(x1.y); u.s[6]=f2bs(x1.z); u.s[7]=f2bs(x1.w);
        } else {
          const unsigned short* rs = (const unsigned short*)rawA + base;  // 8B-aligned
          ushort4 a0 = *(const ushort4*)rs;
          ushort4 a1 = *(const ushort4*)(rs + 4);
          u.s[0]=(short)a0.x; u.s[1]=(short)a0.y; u.s[2]=(short)a0.z; u.s[3]=(short)a0.w;
          u.s[4]=(short)a1.x; u.s[5]=(short)a1.y; u.s[6]=(short)a1.z; u.s[7]=(short)a1.w;
        }
      } else {
#pragma unroll
        for (int j = 0; j < 8; j++) {
          float v = (kc + j < 1148) ? ldf(rawA, base + j, f32v) : 0.f;
          u.s[j] = f2bs(v);
        }
      }
      *(float4*)(&Als[sr * ROWE + sc * 8]) = u.f;
    } else {
      *(float4*)(&Als[sr * ROWE + sc * 8]) =
          *(const float4*)(As + (long)arow_st * lda + kc);
    }
    __syncthreads();
    int koff = quad * 8;
    bfrag af = *(const bfrag*)(&Als[(wave * 16 + l15) * ROWE + koff]);
#pragma unroll
    for (int nt = 0; nt < 8; nt++) {
      bfrag bf = *(const bfrag*)(&Bls[(nt * 16 + l15) * ROWE + koff]);
      acc[nt] = __builtin_amdgcn_mfma_f32_16x16x32_bf16(af, bf, acc[nt], 0, 0, 0);
    }
  }
#pragma unroll
  for (int reg = 0; reg < 4; reg++) {
    int grow = rowbase + quad * 4 + reg;
    if (grow >= M) continue;
#pragma unroll
    for (int nt = 0; nt < 8; nt++) {
      float v = acc[nt][reg] + __bfloat162float(bias[nt * 16 + l15]);
      if (do_relu) v = fmaxf(v, 0.f);
      out[(long)grow * ldo + ocol + nt * 16 + l15] = __float2bfloat16(v);
    }
  }
}

// MFMA GEMM: A (M x K bf16) @ Bt^T -> Hout (M x 256 bf16) + als/ald (f32, M x natt).
// LDS-staged A and B per k-step; B shared by all 4 waves.
// ukmax: K-bound for blocks whose 64 rows are ALL users (x cols 64..K-1 are zero ->
// skipped K-range contributes exactly 0). Layer 1 passes 64; layer 2 passes K.
__global__ __launch_bounds__(256) void gemm_fused(
    const __hip_bfloat16* __restrict__ A, const __hip_bfloat16* __restrict__ Bt,
    __hip_bfloat16* __restrict__ Hout, float* __restrict__ als, float* __restrict__ ald,
    int K, int natt, int ukmax){
  __shared__ short Bls[272 * ROWE];   // 21.25 KB
  __shared__ short Als[64 * ROWE];    //  5.0 KB
  int tid = threadIdx.x;
  int wave = tid >> 6;
  int lane = tid & 63;
  int l15 = lane & 15;
  int quad = lane >> 4;
  int rowbase_blk = blockIdx.x * 64;
  int rowbase = rowbase_blk + wave * 16;
  int kmax = (rowbase_blk + 64 <= N_USERS_C) ? ukmax : K;
  ffrag acc[17];
#pragma unroll
  for (int i = 0; i < 17; i++) acc[i] = (ffrag){0.f, 0.f, 0.f, 0.f};
  const short* As = (const short*)A;
  const short* Bs = (const short*)Bt;
  int sr = tid >> 2, sc = tid & 3;   // A-staging row/chunk
  for (int k0 = 0; k0 < kmax; k0 += 32) {
    __syncthreads();
    // stage B: 272 rows x 4 chunks = 1088 tasks
    for (int t = tid; t < 1088; t += 256) {
      int r = t >> 2, c = t & 3;
      *(float4*)(&Bls[r * ROWE + c * 8]) = *(const float4*)(Bs + (long)r * K + k0 + c * 8);
    }
    // stage A: 64 rows x 4 chunks (grid is exact: rowbase_blk+63 < 120000)
    *(float4*)(&Als[sr * ROWE + sc * 8]) =
        *(const float4*)(As + (long)(rowbase_blk + sr) * K + k0 + sc * 8);
    __syncthreads();
    int koff = quad * 8;
    bfrag af = *(const bfrag*)(&Als[(wave * 16 + l15) * ROWE + koff]);
#pragma unroll
    for (int nt = 0; nt < 17; nt++) {
      bfrag bf = *(const bfrag*)(&Bls[(nt * 16 + l15) * ROWE + koff]);
      acc[nt] = __builtin_amdgcn_mfma_f32_16x16x32_bf16(af, bf, acc[nt], 0, 0, 0);
    }
  }
  int col = l15;
#pragma unroll
  for (int reg = 0; reg < 4; reg++) {
    int grow = rowbase + quad * 4 + reg;
    long obase = (long)grow * 256;
#pragma unroll
    for (int nt = 0; nt < 16; nt++)
      Hout[obase + nt * 16 + col] = __float2bfloat16(acc[nt][reg]);
    float v = acc[16][reg];
    if (col < natt) als[grow * natt + col] = v;
    else if (col < 2 * natt) ald[grow * natt + (col - natt)] = v;
  }
}

// ---------- CSR build (in-edges per dst) ----------
__global__ void deg_count(const int* __restrict__ ei, int* __restrict__ deg){
  int e = blockIdx.x * 256 + threadIdx.x;
  if (e >= E_TOT_C) return;
  int dst = ei[E_TOT_C + e];
  if (dst >= 0 && dst < N_NODES_C) atomicAdd(&deg[dst], 1);
}

// Stage 1: per-block (256-wide) sums.
__global__ __launch_bounds__(256) void deg_bsum(const int* __restrict__ deg,
                                                int* __restrict__ bsum){
  int i = blockIdx.x * 256 + threadIdx.x;
  int v = (i < N_NODES_C) ? deg[i] : 0;
#pragma unroll
  for (int o = 32; o > 0; o >>= 1) v += __shfl_down(v, o, 64);
  __shared__ int ws[4];
  int wave = threadIdx.x >> 6, lane = threadIdx.x & 63;
  if (lane == 0) ws[wave] = v;
  __syncthreads();
  if (threadIdx.x == 0) bsum[blockIdx.x] = ws[0] + ws[1] + ws[2] + ws[3];
}

// Stage 2: single-block Hillis-Steele scan of 469 block sums -> exclusive offsets.
__global__ __launch_bounds__(512) void bsum_scan(int* __restrict__ bsum,
                                                 int* __restrict__ ptrn){
  __shared__ int sm[512];
  int t = threadIdx.x;
  int v = (t < NB_SCAN) ? bsum[t] : 0;
  sm[t] = v;
  __syncthreads();
  for (int o = 1; o < 512; o <<= 1) {
    int add = (t >= o) ? sm[t - o] : 0;
    __syncthreads();
    sm[t] += add;
    __syncthreads();
  }
  int excl = (t == 0) ? 0 : sm[t - 1];
  if (t < NB_SCAN) bsum[t] = excl;
  if (t == NB_SCAN - 1) ptrn[N_NODES_C] = sm[t];
}

// Stage 3: in-block exclusive scan + block offset -> ptrn.
__global__ __launch_bounds__(256) void deg_scan_final(const int* __restrict__ deg,
                                                      const int* __restrict__ bexcl,
                                                      int* __restrict__ ptrn){
  __shared__ int sm[256];
  int i = blockIdx.x * 256 + threadIdx.x;
  int t = threadIdx.x;
  int v = (i < N_NODES_C) ? deg[i] : 0;
  sm[t] = v;
  __syncthreads();
  for (int o = 1; o < 256; o <<= 1) {
    int add = (t >= o) ? sm[t - o] : 0;
    __syncthreads();
    sm[t] += add;
    __syncthreads();
  }
  int excl = (t == 0) ? 0 : sm[t - 1];
  if (i < N_NODES_C) ptrn[i] = bexcl[blockIdx.x] + excl;
}

__global__ void scatter_edges(const int* __restrict__ ei, const int* __restrict__ ptrn,
                              int* __restrict__ cursor, int* __restrict__ elist_src){
  int e = blockIdx.x * 256 + threadIdx.x;
  if (e >= E_TOT_C) return;
  int dst = ei[E_TOT_C + e];
  if (dst < 0 || dst >= N_NODES_C) return;
  int pos = atomicAdd(&cursor[dst], 1);
  elist_src[ptrn[dst] + pos] = ei[e];
}

// ---------- layer 1: online-softmax aggregation, 2-deep software-pipelined gathers ----
__global__ __launch_bounds__(256) void aggregate1(
    const int* __restrict__ ptrn, const int* __restrict__ elist_src,
    const float* __restrict__ als, const float* __restrict__ ald,
    const __hip_bfloat16* __restrict__ hs, const __hip_bfloat16* __restrict__ bias,
    __hip_bfloat16* __restrict__ h1){
  int node = blockIdx.x * 4 + (threadIdx.x >> 6);
  if (node >= N_NODES_C) return;
  int lane = threadIdx.x & 63;
  int c0 = lane * 4;
  int h = lane >> 3;
  int beg = ptrn[node], end = ptrn[node + 1];
  float aldv = sane(ald[node * 8 + h]);
  float m = -1e30f;
  float wsum = 0.f, a0 = 0.f, a1 = 0.f, a2 = 0.f, a3 = 0.f;
  const unsigned short* hsu = (const unsigned short*)hs;
  float alsv_p = 0.f;
  ushort4 hv_p = {0, 0, 0, 0};
  int src_b = 0;
  if (beg < end) {
    int s0 = clampsrc(elist_src[beg]);
    alsv_p = als[(long)s0 * 8 + h];
    hv_p = *(const ushort4*)(hsu + (long)s0 * 256 + c0);
    if (beg + 1 < end) src_b = clampsrc(elist_src[beg + 1]);
  }
  for (int i = beg; i < end; i++) {
    float alsv = alsv_p;
    ushort4 hv = hv_p;
    if (i + 1 < end) {           // issue next-edge gathers before this edge's compute
      alsv_p = als[(long)src_b * 8 + h];
      hv_p = *(const ushort4*)(hsu + (long)src_b * 256 + c0);
    }
    if (i + 2 < end)             // and the src index one further ahead
      src_b = clampsrc(elist_src[i + 2]);
    float ev = sane(alsv) + aldv;
    ev = ev > 0.f ? ev : NEG_C * ev;
    float mnew = fmaxf(m, ev);
    float corr = __expf(m - mnew);   // first iter: exp(-inf)=0 zeroes empty history
    float w = __expf(ev - mnew);
    m = mnew;
    wsum = wsum * corr + w;
    a0 = a0 * corr + w * bf2f(hv.x); a1 = a1 * corr + w * bf2f(hv.y);
    a2 = a2 * corr + w * bf2f(hv.z); a3 = a3 * corr + w * bf2f(hv.w);
  }
  float inv = 1.f / (wsum + 1e-16f);
  float v0 = a0 * inv + __bfloat162float(bias[c0 + 0]);
  float v1 = a1 * inv + __bfloat162float(bias[c0 + 1]);
  float v2 = a2 * inv + __bfloat162float(bias[c0 + 2]);
  float v3 = a3 * inv + __bfloat162float(bias[c0 + 3]);
  v0 = v0 > 0.f ? v0 : (__expf(v0) - 1.f);
  v1 = v1 > 0.f ? v1 : (__expf(v1) - 1.f);
  v2 = v2 > 0.f ? v2 : (__expf(v2) - 1.f);
  v3 = v3 > 0.f ? v3 : (__expf(v3) - 1.f);
  v0 = fminf(fmaxf(v0, -CLAMP_C), CLAMP_C);
  v1 = fminf(fmaxf(v1, -CLAMP_C), CLAMP_C);
  v2 = fminf(fmaxf(v2, -CLAMP_C), CLAMP_C);
  v3 = fminf(fmaxf(v3, -CLAMP_C), CLAMP_C);
  long ob = (long)node * 256 + c0;
  h1[ob + 0] = __float2bfloat16(v0); h1[ob + 1] = __float2bfloat16(v1);
  h1[ob + 2] = __float2bfloat16(v2); h1[ob + 3] = __float2bfloat16(v3);
}

// ---------- layer 2: online softmax, pipelined, 1 head, f32 output (+tail fold) -----
__global__ __launch_bounds__(256) void aggregate2(
    const int* __restrict__ ptrn, const int* __restrict__ elist_src,
    const float* __restrict__ als, const float* __restrict__ ald,
    const __hip_bfloat16* __restrict__ hs, const __hip_bfloat16* __restrict__ bias,
    float* __restrict__ out, int out_size){
  if (blockIdx.x == 0 && threadIdx.x == 0) {   // write_tail folded (disjoint indices)
    out[out_size - 3] = 0.f;
    out[out_size - 2] = (float)N_USERS_C;
    out[out_size - 1] = (float)N_NODES_C;
  }
  int node = blockIdx.x * 4 + (threadIdx.x >> 6);
  if (node >= N_NODES_C) return;
  int lane = threadIdx.x & 63;
  int c0 = lane * 4;
  int beg = ptrn[node], end = ptrn[node + 1];
  float aldv = sane(ald[node]);
  float m = -1e30f;
  float wsum = 0.f, a0 = 0.f, a1 = 0.f, a2 = 0.f, a3 = 0.f;
  const unsigned short* hsu = (const unsigned short*)hs;
  float alsv_p = 0.f;
  ushort4 hv_p = {0, 0, 0, 0};
  int src_b = 0;
  if (beg < end) {
    int s0 = clampsrc(elist_src[beg]);
    alsv_p = als[s0];
    hv_p = *(const ushort4*)(hsu + (long)s0 * 256 + c0);
    if (beg + 1 < end) src_b = clampsrc(elist_src[beg + 1]);
  }
  for (int i = beg; i < end; i++) {
    float alsv = alsv_p;
    ushort4 hv = hv_p;
    if (i + 1 < end) {
      alsv_p = als[src_b];
      hv_p = *(const ushort4*)(hsu + (long)src_b * 256 + c0);
    }
    if (i + 2 < end)
      src_b = clampsrc(elist_src[i + 2]);
    float ev = sane(alsv) + aldv;
    ev = ev > 0.f ? ev : NEG_C * ev;
    float mnew = fmaxf(m, ev);
    float corr = __expf(m - mnew);
    float w = __expf(ev - mnew);
    m = mnew;
    wsum = wsum * corr + w;
    a0 = a0 * corr + w * bf2f(hv.x); a1 = a1 * corr + w * bf2f(hv.y);
    a2 = a2 * corr + w * bf2f(hv.z); a3 = a3 * corr + w * bf2f(hv.w);
  }
  float inv = 1.f / (wsum + 1e-16f);
  float4 v;
  v.x = a0 * inv + __bfloat162float(bias[c0 + 0]);
  v.y = a1 * inv + __bfloat162float(bias[c0 + 1]);
  v.z = a2 * inv + __bfloat162float(bias[c0 + 2]);
  v.w = a3 * inv + __bfloat162float(bias[c0 + 3]);
  v.x = fminf(fmaxf(v.x, -CLAMP_C), CLAMP_C);
  v.y = fminf(fmaxf(v.y, -CLAMP_C), CLAMP_C);
  v.z = fminf(fmaxf(v.z, -CLAMP_C), CLAMP_C);
  v.w = fminf(fmaxf(v.w, -CLAMP_C), CLAMP_C);
  *(float4*)(out + (long)node * 256 + c0) = v;
}

extern "C" void kernel_launch(void* const* d_in, const int* in_sizes, int n_in,
                              void* d_out, int out_size, void* d_ws, size_t ws_size,
                              hipStream_t stream) {
  const void* mov_x    = d_in[2];
  const int*  ei       = (const int*)d_in[3];
  const void* user_emb = d_in[4];
  const void* item_emb = d_in[5];

  char* ws = (char*)d_ws;
  size_t off = 0;
  auto alloc = [&](size_t bytes) -> void* {
    void* p = ws + off; off += (bytes + 255) / 256 * 256; return p;
  };
  int* flag   = (int*)alloc(4);
  __hip_bfloat16* Bt1 = (__hip_bfloat16*)alloc(272 * 192 * 2);
  __hip_bfloat16* Bt2 = (__hip_bfloat16*)alloc(272 * 256 * 2);
  __hip_bfloat16* W1t = (__hip_bfloat16*)alloc(128 * KPAD_C * 2);
  __hip_bfloat16* W2t = (__hip_bfloat16*)alloc(128 * 128 * 2);
  __hip_bfloat16* b1c = (__hip_bfloat16*)alloc(128 * 2);
  __hip_bfloat16* b2c = (__hip_bfloat16*)alloc(128 * 2);
  __hip_bfloat16* bg1 = (__hip_bfloat16*)alloc(256 * 2);
  __hip_bfloat16* bg2 = (__hip_bfloat16*)alloc(256 * 2);
  int* ptrn   = (int*)alloc((N_NODES_C + 1) * 4);
  int* deg    = (int*)alloc(N_NODES_C * 4);
  int* cursor = (int*)alloc(N_NODES_C * 4);
  int* bsum   = (int*)alloc(512 * 4);
  int* elist  = (int*)alloc(E_TOT_C * 4);
  float* als  = (float*)alloc((size_t)N_NODES_C * 8 * 4);
  float* ald  = (float*)alloc((size_t)N_NODES_C * 8 * 4);
  __hip_bfloat16* x  = (__hip_bfloat16*)alloc((size_t)N_NODES_C * D_IN_C * 2); // 46.08 MB
  __hip_bfloat16* hs = (__hip_bfloat16*)alloc((size_t)N_NODES_C * HID_C * 2);  // 61.44 MB
  // d_out (f32, 122.88 MB) hosts h1 (bf16, dead before aggregate2) at byte 0.
  __hip_bfloat16* h1  = (__hip_bfloat16*)d_out;
  __hip_bfloat16* hid = hs;  // movie hidden (20000x128) parks in hs

  detect_dtype<<<1, 256, 0, stream>>>((const unsigned short*)user_emb, flag);

  PrepArgs pa;
  pa.ue = user_emb; pa.ie = item_emb;
  pa.gW1 = d_in[6];  pa.gb1 = d_in[7];  pa.gW2 = d_in[8];  pa.gb2 = d_in[9];
  pa.tW1 = d_in[10]; pa.tb1 = d_in[11]; pa.tW2 = d_in[12]; pa.tb2 = d_in[13];
  pa.Ws1 = d_in[14]; pa.Wd1 = d_in[15]; pa.as1 = d_in[16]; pa.ad1 = d_in[17]; pa.b1 = d_in[18];
  pa.Ws2 = d_in[19]; pa.Wd2 = d_in[20]; pa.as2 = d_in[21]; pa.ad2 = d_in[22]; pa.b2 = d_in[23];
  pa.x = x; pa.Bt1 = Bt1; pa.Bt2 = Bt2; pa.W1t = W1t; pa.W2t = W2t;
  pa.b1c = b1c; pa.b2c = b2c; pa.bg1 = bg1; pa.bg2 = bg2;
  pa.deg = deg; pa.cursor = cursor; pa.flag = flag;
  mega_prep<<<NB_PREP, 256, 0, stream>>>(pa);

  // movie feature path (raw mov_x converted during staging; conv_movx eliminated)
  movie_gemm<<<(N_ITEMS_C + 63) / 64, 256, 0, stream>>>(
      nullptr, 0, N_ITEMS_C, mov_x, flag, W1t, KPAD_C, b1c, 1, hid, 128, 0);
  movie_gemm<<<(N_ITEMS_C + 63) / 64, 256, 0, stream>>>(
      hid, 128, N_ITEMS_C, nullptr, flag, W2t, 128, b2c, 0,
      x + (long)N_USERS_C * D_IN_C, D_IN_C, 64);

  // CSR of in-edges (deg/cursor pre-zeroed by mega_prep)
  deg_count<<<(E_TOT_C + 255) / 256, 256, 0, stream>>>(ei, deg);
  deg_bsum<<<NB_SCAN, 256, 0, stream>>>(deg, bsum);
  bsum_scan<<<1, 512, 0, stream>>>(bsum, ptrn);
  deg_scan_final<<<NB_SCAN, 256, 0, stream>>>(deg, bsum, ptrn);
  scatter_edges<<<(E_TOT_C + 255) / 256, 256, 0, stream>>>(ei, ptrn, cursor, elist);

  // layer 1 (ukmax=64: pure-user blocks skip the zero K-range)
  gemm_fused<<<N_NODES_C / 64, 256, 0, stream>>>(x, Bt1, hs, als, ald, 192, 8, 64);
  aggregate1<<<N_NODES_C / 4, 256, 0, stream>>>(ptrn, elist, als, ald, hs, bg1, h1);

  // layer 2 (ukmax=K: disabled)
  gemm_fused<<<N_NODES_C / 64, 256, 0, stream>>>(h1, Bt2, hs, als, ald, 256, 1, 256);
  aggregate2<<<N_NODES_C / 4, 256, 0, stream>>>(ptrn, elist, als, ald, hs, bg2,
                                                (float*)d_out, out_size);
}

// Round 9
// 571.936 us; speedup vs baseline: 2.0905x; 1.0281x over previous
//
#include <hip/hip_runtime.h>
#include <hip/hip_bf16.h>

#define N_USERS_C 100000
#define N_ITEMS_C 20000
#define N_NODES_C 120000
#define E_TOT_C   400000
#define D_IN_C    192
#define HID_C     256
#define NEG_C     0.2f
#define CLAMP_C   1000.0f
#define KPAD_C    1152   // 1148 padded to multiple of 32
#define NB_SCAN   ((N_NODES_C + 255) / 256)   // 469 scan blocks
#define ROWE      40     // LDS row length in shorts: 32 k-elems + 8 pad (80B, 16B-aligned)
#define NT_MOV    313    // ceil(20000/64) row tiles
#define KSPLIT    4
#define KCH       288    // 1152 / KSPLIT

typedef __attribute__((ext_vector_type(8))) short bfrag;
typedef __attribute__((ext_vector_type(4))) float ffrag;

__device__ __forceinline__ float bf2f(unsigned short u){
  return __uint_as_float(((unsigned)u) << 16);
}
__device__ __forceinline__ float ldf(const void* p, long i, int isf32){
  return isf32 ? ((const float*)p)[i] : bf2f(((const unsigned short*)p)[i]);
}
__device__ __forceinline__ float sane(float v){
  return (v > -1e30f && v < 1e30f) ? v : 0.f;
}
__device__ __forceinline__ int clampsrc(int s){
  return s < 0 ? 0 : (s >= N_NODES_C ? N_NODES_C - 1 : s);
}
__device__ __forceinline__ short f2bs(float f){
  __hip_bfloat16 h = __float2bfloat16(f);
  return *reinterpret_cast<short*>(&h);
}

// ---------- dtype discriminator (inputs) ----------
__global__ __launch_bounds__(256) void detect_dtype(const unsigned short* __restrict__ ue,
                                                    int* __restrict__ flag){
  __shared__ int cnt[256];
  int tid = threadIdx.x; int c = 0;
  for (int i = tid; i < 8192; i += 256){
    unsigned e = (ue[i] >> 7) & 0xFFu;
    if (e >= 129u) c++;
  }
  cnt[tid] = c; __syncthreads();
  if (tid == 0){
    int s = 0;
    for (int i = 0; i < 256; i++) s += cnt[i];
    *flag = (s > 100) ? 1 : 0;
  }
}

// ---------- MEGA-PREP: one launch, 8-elems/thread vectorized (G13) ----------
struct PrepArgs {
  const void *ue, *ie;
  const void *gW1, *gb1, *gW2, *gb2, *tW1, *tb1, *tW2, *tb2;
  const void *Ws1, *Wd1, *as1, *ad1, *b1, *Ws2, *Wd2, *as2, *ad2, *b2;
  __hip_bfloat16 *x, *Bt1, *Bt2, *W1t, *W2t, *b1c, *b2c, *bg1, *bg2;
  int *deg, *cursor;
  const int* flag;
};

#define NB_UEMB  3125   // 100000*64 /8 /256
#define NB_UZERO 2      // 32 rows x 128 cols /8 /256
#define NB_MOVE  625    // 20000*64 /8 /256
#define NB_BT1   204    // 272*192 /256 (scalar)
#define NB_BT2   272    // 272*256 /256 (scalar)
#define NB_W1T   72     // 128*1152 /8 /256
#define NB_W2T   8      // 128*128 /8 /256
#define NB_ZERO  235    // 240000 ints /4 /256
#define NB_PREP (NB_UEMB+NB_UZERO+NB_MOVE+NB_BT1+NB_BT2+NB_W1T+NB_W2T+1+NB_ZERO)

__global__ __launch_bounds__(256) void mega_prep(PrepArgs a){
  int b = blockIdx.x, tid = threadIdx.x;
  int f32 = *a.flag;
  if (b < NB_UEMB) {                     // x user rows cols 0..63, 8 elems/thread
    int idx = b * 256 + tid;
    int n = idx >> 3, c0 = (idx & 7) * 8;
    union { short s[8]; float4 f; } u;
    if (f32) {
      const float* rf = (const float*)a.ue + (long)n * 64 + c0;
      float4 x0 = *(const float4*)rf, x1 = *(const float4*)(rf + 4);
      u.s[0]=f2bs(x0.x); u.s[1]=f2bs(x0.y); u.s[2]=f2bs(x0.z); u.s[3]=f2bs(x0.w);
      u.s[4]=f2bs(x1.x); u.s[5]=f2bs(x1.y); u.s[6]=f2bs(x1.z); u.s[7]=f2bs(x1.w);
    } else {
      u.f = *(const float4*)((const unsigned short*)a.ue + (long)n * 64 + c0);
    }
    *(float4*)(&a.x[(long)n * 192 + c0]) = u.f;
    return;
  }
  b -= NB_UEMB;
  if (b < NB_UZERO) {                    // boundary user rows 99968..99999, cols 64..191 = 0
    int idx = b * 256 + tid;
    int r = idx >> 4, c0 = 64 + (idx & 15) * 8;
    float4 z = {0.f, 0.f, 0.f, 0.f};
    *(float4*)(&a.x[(long)(99968 + r) * 192 + c0]) = z;
    return;
  }
  b -= NB_UZERO;
  if (b < NB_MOVE) {                     // x movie rows cols 0..63 = item_emb
    int idx = b * 256 + tid;
    int m = idx >> 3, c0 = (idx & 7) * 8;
    union { short s[8]; float4 f; } u;
    if (f32) {
      const float* rf = (const float*)a.ie + (long)m * 64 + c0;
      float4 x0 = *(const float4*)rf, x1 = *(const float4*)(rf + 4);
      u.s[0]=f2bs(x0.x); u.s[1]=f2bs(x0.y); u.s[2]=f2bs(x0.z); u.s[3]=f2bs(x0.w);
      u.s[4]=f2bs(x1.x); u.s[5]=f2bs(x1.y); u.s[6]=f2bs(x1.z); u.s[7]=f2bs(x1.w);
    } else {
      u.f = *(const float4*)((const unsigned short*)a.ie + (long)m * 64 + c0);
    }
    *(float4*)(&a.x[(long)(N_USERS_C + m) * 192 + c0]) = u.f;
    return;
  }
  b -= NB_MOVE;
  if (b < NB_BT1) {                      // Bt1 (272 x 192)
    int idx = b * 256 + tid;
    int col = idx / 192, k = idx - col * 192;
    float v;
    if (col < 256) v = ldf(a.Ws1, k * 256 + col, f32);
    else if (col < 264) {
      int h = col - 256; float s = 0.f;
      for (int c = 0; c < 32; c++)
        s += ldf(a.Ws1, k * 256 + h * 32 + c, f32) * ldf(a.as1, h * 32 + c, f32);
      v = s;
    } else {
      int h = col - 264; float s = 0.f;
      for (int c = 0; c < 32; c++)
        s += ldf(a.Wd1, k * 256 + h * 32 + c, f32) * ldf(a.ad1, h * 32 + c, f32);
      v = s;
    }
    a.Bt1[col * 192 + k] = __float2bfloat16(v);
    return;
  }
  b -= NB_BT1;
  if (b < NB_BT2) {                      // Bt2 (272 x 256), H=1, C=256
    int idx = b * 256 + tid;
    int col = idx / 256, k = idx & 255;
    float v;
    if (col < 256) v = ldf(a.Ws2, k * 256 + col, f32);
    else if (col == 256) {
      float s = 0.f;
      for (int c = 0; c < 256; c++)
        s += ldf(a.Ws2, k * 256 + c, f32) * ldf(a.as2, c, f32);
      v = s;
    } else if (col == 257) {
      float s = 0.f;
      for (int c = 0; c < 256; c++)
        s += ldf(a.Wd2, k * 256 + c, f32) * ldf(a.ad2, c, f32);
      v = s;
    } else v = 0.f;
    a.Bt2[col * 256 + k] = __float2bfloat16(v);
    return;
  }
  b -= NB_BT2;
  if (b < NB_W1T) {                      // W1t (128 x 1152), 8 elems/thread
    int idx = b * 256 + tid;
    int n = idx / 144, c8 = idx - n * 144;
    int k0 = c8 * 8;
    union { short s[8]; float4 f; } u;
#pragma unroll
    for (int j = 0; j < 8; j++) {
      int k = k0 + j; float v = 0.f;
      if (n < 64) { if (k < 20) v = ldf(a.gW1, k * 64 + n, f32); }
      else        { if (k >= 20 && k < 1148) v = ldf(a.tW1, (k - 20) * 64 + (n - 64), f32); }
      u.s[j] = f2bs(v);
    }
    *(float4*)(&a.W1t[(long)n * 1152 + k0]) = u.f;
    return;
  }
  b -= NB_W1T;
  if (b < NB_W2T) {                      // W2t (128 x 128) blockdiag, 8 elems/thread
    int idx = b * 256 + tid;
    int n = idx >> 4, k0 = (idx & 15) * 8;
    union { short s[8]; float4 f; } u;
#pragma unroll
    for (int j = 0; j < 8; j++) {
      int k = k0 + j; float v = 0.f;
      if (n < 64) { if (k < 64)  v = ldf(a.gW2, k * 64 + n, f32); }
      else        { if (k >= 64) v = ldf(a.tW2, (k - 64) * 64 + (n - 64), f32); }
      u.s[j] = f2bs(v);
    }
    *(float4*)(&a.W2t[n * 128 + k0]) = u.f;
    return;
  }
  b -= NB_W2T;
  if (b < 1) {                           // all bias vectors
    int i = tid;
    if (i < 64)       a.b1c[i] = __float2bfloat16(ldf(a.gb1, i, f32));
    else if (i < 128) a.b1c[i] = __float2bfloat16(ldf(a.tb1, i - 64, f32));
    else if (i < 192) a.b2c[i - 128] = __float2bfloat16(ldf(a.gb2, i - 128, f32));
    else              a.b2c[i - 128] = __float2bfloat16(ldf(a.tb2, i - 192, f32));
    a.bg1[tid] = __float2bfloat16(ldf(a.b1, tid, f32));
    a.bg2[tid] = __float2bfloat16(ldf(a.b2, tid, f32));
    return;
  }
  b -= 1;
  {                                      // zero deg + cursor, int4/thread
    int i0 = (b * 256 + tid) * 4;
    if (i0 < 2 * N_NODES_C) {
      int4 z = {0, 0, 0, 0};
      if (i0 < N_NODES_C) *(int4*)(a.deg + i0) = z;
      else                *(int4*)(a.cursor + (i0 - N_NODES_C)) = z;
    }
  }
}

// ---------- movie layer 1, K-SPLIT: grid = NT_MOV*KSPLIT blocks ----------
// Each block: 64 rows x 128 cols partial over k in [split*KCH, split*KCH+KCH).
// Writes f32 partial (own slice, exactly once -> no atomics, no zero-init).
// Fixes the 11%-occupancy bottleneck (313 -> 1252 blocks).
__global__ __launch_bounds__(256) void movie_gemm_k(
    const void* __restrict__ rawA, const int* __restrict__ flag,
    const __hip_bfloat16* __restrict__ W1t,
    float* __restrict__ part){
  __shared__ short Bls[128 * ROWE];   // 10.0 KB
  __shared__ short Als[64 * ROWE];    //  5.0 KB
  int tid = threadIdx.x;
  int wave = tid >> 6;
  int lane = tid & 63;
  int l15 = lane & 15;
  int quad = lane >> 4;
  int bid = blockIdx.x;
  int tile = bid % NT_MOV, split = bid / NT_MOV;  // consecutive bids = adjacent A rows
  int rowbase_blk = tile * 64;
  int rowbase = rowbase_blk + wave * 16;
  int f32v = *flag;
  ffrag acc[8];
#pragma unroll
  for (int i = 0; i < 8; i++) acc[i] = (ffrag){0.f, 0.f, 0.f, 0.f};
  const short* Bs = (const short*)W1t;
  int sr = tid >> 2, sc = tid & 3;
  int arow_st = rowbase_blk + sr; if (arow_st >= N_ITEMS_C) arow_st = N_ITEMS_C - 1;
  int kbeg = split * KCH;
  for (int k0 = kbeg; k0 < kbeg + KCH; k0 += 32) {
    __syncthreads();
    // stage B: 128 rows x 4 chunks (row stride KPAD_C)
    for (int t = tid; t < 512; t += 256) {
      int r = t >> 2, c = t & 3;
      *(float4*)(&Bls[r * ROWE + c * 8]) =
          *(const float4*)(Bs + (long)r * KPAD_C + k0 + c * 8);
    }
    // stage A: raw mov_x (20000 x 1148) converted to bf16 on the fly
    int kc = k0 + sc * 8;
    union { short s[8]; float4 f; } u;
    long base = (long)arow_st * 1148 + kc;
    if (kc + 8 <= 1148) {
      if (f32v) {
        const float* rf = (const float*)rawA + base;
        float4 x0 = *(const float4*)rf;
        float4 x1 = *(const float4*)(rf + 4);
        u.s[0]=f2bs(x0.x); u.s[1]=f2bs(x0.y); u.s[2]=f2bs(x0.z); u.s[3]=f2bs(x0.w);
        u.s[4]=f2bs(x1.x); u.s[5]=f2bs(x1.y); u.s[6]=f2bs(x1.z); u.s[7]=f2bs(x1.w);
      } else {
        const unsigned short* rs = (const unsigned short*)rawA + base;
        ushort4 a0 = *(const ushort4*)rs;
        ushort4 a1 = *(const ushort4*)(rs + 4);
        u.s[0]=(short)a0.x; u.s[1]=(short)a0.y; u.s[2]=(short)a0.z; u.s[3]=(short)a0.w;
        u.s[4]=(short)a1.x; u.s[5]=(short)a1.y; u.s[6]=(short)a1.z; u.s[7]=(short)a1.w;
      }
    } else {
#pragma unroll
      for (int j = 0; j < 8; j++) {
        float v = (kc + j < 1148) ? ldf(rawA, base + j, f32v) : 0.f;
        u.s[j] = f2bs(v);
      }
    }
    *(float4*)(&Als[sr * ROWE + sc * 8]) = u.f;
    __syncthreads();
    int koff = quad * 8;
    bfrag af = *(const bfrag*)(&Als[(wave * 16 + l15) * ROWE + koff]);
#pragma unroll
    for (int nt = 0; nt < 8; nt++) {
      bfrag bf = *(const bfrag*)(&Bls[(nt * 16 + l15) * ROWE + koff]);
      acc[nt] = __builtin_amdgcn_mfma_f32_16x16x32_bf16(af, bf, acc[nt], 0, 0, 0);
    }
  }
  float* pb = part + (long)split * (N_ITEMS_C * 128);
#pragma unroll
  for (int reg = 0; reg < 4; reg++) {
    int grow = rowbase + quad * 4 + reg;
    if (grow >= N_ITEMS_C) continue;
#pragma unroll
    for (int nt = 0; nt < 8; nt++)
      pb[(long)grow * 128 + nt * 16 + l15] = acc[nt][reg];
  }
}

// ---------- movie layer 2: reduce KSPLIT partials + bias1 + relu in A-staging ----------
__global__ __launch_bounds__(256) void movie_gemm2(
    const float* __restrict__ part, const __hip_bfloat16* __restrict__ b1c,
    const __hip_bfloat16* __restrict__ W2t, const __hip_bfloat16* __restrict__ b2c,
    __hip_bfloat16* __restrict__ out){   // out = x + N_USERS*192, ldo=192, ocol=64
  __shared__ short Bls[128 * ROWE];
  __shared__ short Als[64 * ROWE];
  int tid = threadIdx.x;
  int wave = tid >> 6;
  int lane = tid & 63;
  int l15 = lane & 15;
  int quad = lane >> 4;
  int rowbase_blk = blockIdx.x * 64;
  int rowbase = rowbase_blk + wave * 16;
  ffrag acc[8];
#pragma unroll
  for (int i = 0; i < 8; i++) acc[i] = (ffrag){0.f, 0.f, 0.f, 0.f};
  const short* Bs = (const short*)W2t;
  int sr = tid >> 2, sc = tid & 3;
  int arow_st = rowbase_blk + sr; if (arow_st >= N_ITEMS_C) arow_st = N_ITEMS_C - 1;
  for (int k0 = 0; k0 < 128; k0 += 32) {
    __syncthreads();
    for (int t = tid; t < 512; t += 256) {
      int r = t >> 2, c = t & 3;
      *(float4*)(&Bls[r * ROWE + c * 8]) =
          *(const float4*)(Bs + (long)r * 128 + k0 + c * 8);
    }
    // stage A: sum partials + bias1 + relu -> bf16
    int kc = k0 + sc * 8;
    float vs[8];
#pragma unroll
    for (int j = 0; j < 8; j++) vs[j] = __bfloat162float(b1c[kc + j]);
    long base = (long)arow_st * 128 + kc;
#pragma unroll
    for (int s = 0; s < KSPLIT; s++) {
      const float* p = part + (long)s * (N_ITEMS_C * 128) + base;
      float4 q0 = *(const float4*)p, q1 = *(const float4*)(p + 4);
      vs[0] += q0.x; vs[1] += q0.y; vs[2] += q0.z; vs[3] += q0.w;
      vs[4] += q1.x; vs[5] += q1.y; vs[6] += q1.z; vs[7] += q1.w;
    }
    union { short s[8]; float4 f; } u;
#pragma unroll
    for (int j = 0; j < 8; j++) u.s[j] = f2bs(fmaxf(vs[j], 0.f));
    *(float4*)(&Als[sr * ROWE + sc * 8]) = u.f;
    __syncthreads();
    int koff = quad * 8;
    bfrag af = *(const bfrag*)(&Als[(wave * 16 + l15) * ROWE + koff]);
#pragma unroll
    for (int nt = 0; nt < 8; nt++) {
      bfrag bf = *(const bfrag*)(&Bls[(nt * 16 + l15) * ROWE + koff]);
      acc[nt] = __builtin_amdgcn_mfma_f32_16x16x32_bf16(af, bf, acc[nt], 0, 0, 0);
    }
  }
#pragma unroll
  for (int reg = 0; reg < 4; reg++) {
    int grow = rowbase + quad * 4 + reg;
    if (grow >= N_ITEMS_C) continue;
#pragma unroll
    for (int nt = 0; nt < 8; nt++) {
      float v = acc[nt][reg] + __bfloat162float(b2c[nt * 16 + l15]);
      out[(long)grow * D_IN_C + 64 + nt * 16 + l15] = __float2bfloat16(v);
    }
  }
}

// MFMA GEMM: A (M x K bf16) @ Bt^T -> Hout (M x 256 bf16) + als/ald (f32, M x natt).
// ukmax: K-bound for all-user blocks (cols 64..K-1 zero). L1 passes 64; L2 passes K.
__global__ __launch_bounds__(256) void gemm_fused(
    const __hip_bfloat16* __restrict__ A, const __hip_bfloat16* __restrict__ Bt,
    __hip_bfloat16* __restrict__ Hout, float* __restrict__ als, float* __restrict__ ald,
    int K, int natt, int ukmax){
  __shared__ short Bls[272 * ROWE];   // 21.25 KB
  __shared__ short Als[64 * ROWE];    //  5.0 KB
  int tid = threadIdx.x;
  int wave = tid >> 6;
  int lane = tid & 63;
  int l15 = lane & 15;
  int quad = lane >> 4;
  int rowbase_blk = blockIdx.x * 64;
  int rowbase = rowbase_blk + wave * 16;
  int kmax = (rowbase_blk + 64 <= N_USERS_C) ? ukmax : K;
  ffrag acc[17];
#pragma unroll
  for (int i = 0; i < 17; i++) acc[i] = (ffrag){0.f, 0.f, 0.f, 0.f};
  const short* As = (const short*)A;
  const short* Bs = (const short*)Bt;
  int sr = tid >> 2, sc = tid & 3;
  for (int k0 = 0; k0 < kmax; k0 += 32) {
    __syncthreads();
    for (int t = tid; t < 1088; t += 256) {
      int r = t >> 2, c = t & 3;
      *(float4*)(&Bls[r * ROWE + c * 8]) = *(const float4*)(Bs + (long)r * K + k0 + c * 8);
    }
    *(float4*)(&Als[sr * ROWE + sc * 8]) =
        *(const float4*)(As + (long)(rowbase_blk + sr) * K + k0 + sc * 8);
    __syncthreads();
    int koff = quad * 8;
    bfrag af = *(const bfrag*)(&Als[(wave * 16 + l15) * ROWE + koff]);
#pragma unroll
    for (int nt = 0; nt < 17; nt++) {
      bfrag bf = *(const bfrag*)(&Bls[(nt * 16 + l15) * ROWE + koff]);
      acc[nt] = __builtin_amdgcn_mfma_f32_16x16x32_bf16(af, bf, acc[nt], 0, 0, 0);
    }
  }
  int col = l15;
#pragma unroll
  for (int reg = 0; reg < 4; reg++) {
    int grow = rowbase + quad * 4 + reg;
    long obase = (long)grow * 256;
#pragma unroll
    for (int nt = 0; nt < 16; nt++)
      Hout[obase + nt * 16 + col] = __float2bfloat16(acc[nt][reg]);
    float v = acc[16][reg];
    if (col < natt) als[grow * natt + col] = v;
    else if (col < 2 * natt) ald[grow * natt + (col - natt)] = v;
  }
}

// ---------- CSR build (in-edges per dst) ----------
__global__ void deg_count(const int* __restrict__ ei, int* __restrict__ deg){
  int e = blockIdx.x * 256 + threadIdx.x;
  if (e >= E_TOT_C) return;
  int dst = ei[E_TOT_C + e];
  if (dst >= 0 && dst < N_NODES_C) atomicAdd(&deg[dst], 1);
}

__global__ __launch_bounds__(256) void deg_bsum(const int* __restrict__ deg,
                                                int* __restrict__ bsum){
  int i = blockIdx.x * 256 + threadIdx.x;
  int v = (i < N_NODES_C) ? deg[i] : 0;
#pragma unroll
  for (int o = 32; o > 0; o >>= 1) v += __shfl_down(v, o, 64);
  __shared__ int ws[4];
  int wave = threadIdx.x >> 6, lane = threadIdx.x & 63;
  if (lane == 0) ws[wave] = v;
  __syncthreads();
  if (threadIdx.x == 0) bsum[blockIdx.x] = ws[0] + ws[1] + ws[2] + ws[3];
}

__global__ __launch_bounds__(512) void bsum_scan(int* __restrict__ bsum,
                                                 int* __restrict__ ptrn){
  __shared__ int sm[512];
  int t = threadIdx.x;
  int v = (t < NB_SCAN) ? bsum[t] : 0;
  sm[t] = v;
  __syncthreads();
  for (int o = 1; o < 512; o <<= 1) {
    int add = (t >= o) ? sm[t - o] : 0;
    __syncthreads();
    sm[t] += add;
    __syncthreads();
  }
  int excl = (t == 0) ? 0 : sm[t - 1];
  if (t < NB_SCAN) bsum[t] = excl;
  if (t == NB_SCAN - 1) ptrn[N_NODES_C] = sm[t];
}

__global__ __launch_bounds__(256) void deg_scan_final(const int* __restrict__ deg,
                                                      const int* __restrict__ bexcl,
                                                      int* __restrict__ ptrn){
  __shared__ int sm[256];
  int i = blockIdx.x * 256 + threadIdx.x;
  int t = threadIdx.x;
  int v = (i < N_NODES_C) ? deg[i] : 0;
  sm[t] = v;
  __syncthreads();
  for (int o = 1; o < 256; o <<= 1) {
    int add = (t >= o) ? sm[t - o] : 0;
    __syncthreads();
    sm[t] += add;
    __syncthreads();
  }
  int excl = (t == 0) ? 0 : sm[t - 1];
  if (i < N_NODES_C) ptrn[i] = bexcl[blockIdx.x] + excl;
}

__global__ void scatter_edges(const int* __restrict__ ei, const int* __restrict__ ptrn,
                              int* __restrict__ cursor, int* __restrict__ elist_src){
  int e = blockIdx.x * 256 + threadIdx.x;
  if (e >= E_TOT_C) return;
  int dst = ei[E_TOT_C + e];
  if (dst < 0 || dst >= N_NODES_C) return;
  int pos = atomicAdd(&cursor[dst], 1);
  elist_src[ptrn[dst] + pos] = ei[e];
}

// ---------- layer 1: online-softmax aggregation, 2-deep software-pipelined gathers ----
__global__ __launch_bounds__(256) void aggregate1(
    const int* __restrict__ ptrn, const int* __restrict__ elist_src,
    const float* __restrict__ als, const float* __restrict__ ald,
    const __hip_bfloat16* __restrict__ hs, const __hip_bfloat16* __restrict__ bias,
    __hip_bfloat16* __restrict__ h1){
  int node = blockIdx.x * 4 + (threadIdx.x >> 6);
  if (node >= N_NODES_C) return;
  int lane = threadIdx.x & 63;
  int c0 = lane * 4;
  int h = lane >> 3;
  int beg = ptrn[node], end = ptrn[node + 1];
  float aldv = sane(ald[node * 8 + h]);
  float m = -1e30f;
  float wsum = 0.f, a0 = 0.f, a1 = 0.f, a2 = 0.f, a3 = 0.f;
  const unsigned short* hsu = (const unsigned short*)hs;
  float alsv_p = 0.f;
  ushort4 hv_p = {0, 0, 0, 0};
  int src_b = 0;
  if (beg < end) {
    int s0 = clampsrc(elist_src[beg]);
    alsv_p = als[(long)s0 * 8 + h];
    hv_p = *(const ushort4*)(hsu + (long)s0 * 256 + c0);
    if (beg + 1 < end) src_b = clampsrc(elist_src[beg + 1]);
  }
  for (int i = beg; i < end; i++) {
    float alsv = alsv_p;
    ushort4 hv = hv_p;
    if (i + 1 < end) {
      alsv_p = als[(long)src_b * 8 + h];
      hv_p = *(const ushort4*)(hsu + (long)src_b * 256 + c0);
    }
    if (i + 2 < end)
      src_b = clampsrc(elist_src[i + 2]);
    float ev = sane(alsv) + aldv;
    ev = ev > 0.f ? ev : NEG_C * ev;
    float mnew = fmaxf(m, ev);
    float corr = __expf(m - mnew);
    float w = __expf(ev - mnew);
    m = mnew;
    wsum = wsum * corr + w;
    a0 = a0 * corr + w * bf2f(hv.x); a1 = a1 * corr + w * bf2f(hv.y);
    a2 = a2 * corr + w * bf2f(hv.z); a3 = a3 * corr + w * bf2f(hv.w);
  }
  float inv = 1.f / (wsum + 1e-16f);
  float v0 = a0 * inv + __bfloat162float(bias[c0 + 0]);
  float v1 = a1 * inv + __bfloat162float(bias[c0 + 1]);
  float v2 = a2 * inv + __bfloat162float(bias[c0 + 2]);
  float v3 = a3 * inv + __bfloat162float(bias[c0 + 3]);
  v0 = v0 > 0.f ? v0 : (__expf(v0) - 1.f);
  v1 = v1 > 0.f ? v1 : (__expf(v1) - 1.f);
  v2 = v2 > 0.f ? v2 : (__expf(v2) - 1.f);
  v3 = v3 > 0.f ? v3 : (__expf(v3) - 1.f);
  v0 = fminf(fmaxf(v0, -CLAMP_C), CLAMP_C);
  v1 = fminf(fmaxf(v1, -CLAMP_C), CLAMP_C);
  v2 = fminf(fmaxf(v2, -CLAMP_C), CLAMP_C);
  v3 = fminf(fmaxf(v3, -CLAMP_C), CLAMP_C);
  long ob = (long)node * 256 + c0;
  h1[ob + 0] = __float2bfloat16(v0); h1[ob + 1] = __float2bfloat16(v1);
  h1[ob + 2] = __float2bfloat16(v2); h1[ob + 3] = __float2bfloat16(v3);
}

// ---------- layer 2: online softmax, pipelined, 1 head, f32 output (+tail fold) -----
__global__ __launch_bounds__(256) void aggregate2(
    const int* __restrict__ ptrn, const int* __restrict__ elist_src,
    const float* __restrict__ als, const float* __restrict__ ald,
    const __hip_bfloat16* __restrict__ hs, const __hip_bfloat16* __restrict__ bias,
    float* __restrict__ out, int out_size){
  if (blockIdx.x == 0 && threadIdx.x == 0) {
    out[out_size - 3] = 0.f;
    out[out_size - 2] = (float)N_USERS_C;
    out[out_size - 1] = (float)N_NODES_C;
  }
  int node = blockIdx.x * 4 + (threadIdx.x >> 6);
  if (node >= N_NODES_C) return;
  int lane = threadIdx.x & 63;
  int c0 = lane * 4;
  int beg = ptrn[node], end = ptrn[node + 1];
  float aldv = sane(ald[node]);
  float m = -1e30f;
  float wsum = 0.f, a0 = 0.f, a1 = 0.f, a2 = 0.f, a3 = 0.f;
  const unsigned short* hsu = (const unsigned short*)hs;
  float alsv_p = 0.f;
  ushort4 hv_p = {0, 0, 0, 0};
  int src_b = 0;
  if (beg < end) {
    int s0 = clampsrc(elist_src[beg]);
    alsv_p = als[s0];
    hv_p = *(const ushort4*)(hsu + (long)s0 * 256 + c0);
    if (beg + 1 < end) src_b = clampsrc(elist_src[beg + 1]);
  }
  for (int i = beg; i < end; i++) {
    float alsv = alsv_p;
    ushort4 hv = hv_p;
    if (i + 1 < end) {
      alsv_p = als[src_b];
      hv_p = *(const ushort4*)(hsu + (long)src_b * 256 + c0);
    }
    if (i + 2 < end)
      src_b = clampsrc(elist_src[i + 2]);
    float ev = sane(alsv) + aldv;
    ev = ev > 0.f ? ev : NEG_C * ev;
    float mnew = fmaxf(m, ev);
    float corr = __expf(m - mnew);
    float w = __expf(ev - mnew);
    m = mnew;
    wsum = wsum * corr + w;
    a0 = a0 * corr + w * bf2f(hv.x); a1 = a1 * corr + w * bf2f(hv.y);
    a2 = a2 * corr + w * bf2f(hv.z); a3 = a3 * corr + w * bf2f(hv.w);
  }
  float inv = 1.f / (wsum + 1e-16f);
  float4 v;
  v.x = a0 * inv + __bfloat162float(bias[c0 + 0]);
  v.y = a1 * inv + __bfloat162float(bias[c0 + 1]);
  v.z = a2 * inv + __bfloat162float(bias[c0 + 2]);
  v.w = a3 * inv + __bfloat162float(bias[c0 + 3]);
  v.x = fminf(fmaxf(v.x, -CLAMP_C), CLAMP_C);
  v.y = fminf(fmaxf(v.y, -CLAMP_C), CLAMP_C);
  v.z = fminf(fmaxf(v.z, -CLAMP_C), CLAMP_C);
  v.w = fminf(fmaxf(v.w, -CLAMP_C), CLAMP_C);
  *(float4*)(out + (long)node * 256 + c0) = v;
}

extern "C" void kernel_launch(void* const* d_in, const int* in_sizes, int n_in,
                              void* d_out, int out_size, void* d_ws, size_t ws_size,
                              hipStream_t stream) {
  const void* mov_x    = d_in[2];
  const int*  ei       = (const int*)d_in[3];
  const void* user_emb = d_in[4];
  const void* item_emb = d_in[5];

  char* ws = (char*)d_ws;
  size_t off = 0;
  auto alloc = [&](size_t bytes) -> void* {
    void* p = ws + off; off += (bytes + 255) / 256 * 256; return p;
  };
  int* flag   = (int*)alloc(4);
  __hip_bfloat16* Bt1 = (__hip_bfloat16*)alloc(272 * 192 * 2);
  __hip_bfloat16* Bt2 = (__hip_bfloat16*)alloc(272 * 256 * 2);
  __hip_bfloat16* W1t = (__hip_bfloat16*)alloc(128 * KPAD_C * 2);
  __hip_bfloat16* W2t = (__hip_bfloat16*)alloc(128 * 128 * 2);
  __hip_bfloat16* b1c = (__hip_bfloat16*)alloc(128 * 2);
  __hip_bfloat16* b2c = (__hip_bfloat16*)alloc(128 * 2);
  __hip_bfloat16* bg1 = (__hip_bfloat16*)alloc(256 * 2);
  __hip_bfloat16* bg2 = (__hip_bfloat16*)alloc(256 * 2);
  int* ptrn   = (int*)alloc((N_NODES_C + 1) * 4);
  int* deg    = (int*)alloc(N_NODES_C * 4);
  int* cursor = (int*)alloc(N_NODES_C * 4);
  int* bsum   = (int*)alloc(512 * 4);
  int* elist  = (int*)alloc(E_TOT_C * 4);
  float* als  = (float*)alloc((size_t)N_NODES_C * 8 * 4);
  float* ald  = (float*)alloc((size_t)N_NODES_C * 8 * 4);
  __hip_bfloat16* x  = (__hip_bfloat16*)alloc((size_t)N_NODES_C * D_IN_C * 2); // 46.08 MB
  __hip_bfloat16* hs = (__hip_bfloat16*)alloc((size_t)N_NODES_C * HID_C * 2);  // 61.44 MB
  // d_out (f32, 122.88 MB) hosts dead-before-aggregate2 temporaries:
  //   h1 (bf16 61.44 MB) at byte 0; movie K-split partials (4 x 10.24 MB f32)
  //   at byte 61,440,000 (..102.4 MB; consumed by movie_gemm2 long before aggregate2).
  __hip_bfloat16* h1  = (__hip_bfloat16*)d_out;
  float* part = (float*)((char*)d_out + 61440000);

  detect_dtype<<<1, 256, 0, stream>>>((const unsigned short*)user_emb, flag);

  PrepArgs pa;
  pa.ue = user_emb; pa.ie = item_emb;
  pa.gW1 = d_in[6];  pa.gb1 = d_in[7];  pa.gW2 = d_in[8];  pa.gb2 = d_in[9];
  pa.tW1 = d_in[10]; pa.tb1 = d_in[11]; pa.tW2 = d_in[12]; pa.tb2 = d_in[13];
  pa.Ws1 = d_in[14]; pa.Wd1 = d_in[15]; pa.as1 = d_in[16]; pa.ad1 = d_in[17]; pa.b1 = d_in[18];
  pa.Ws2 = d_in[19]; pa.Wd2 = d_in[20]; pa.as2 = d_in[21]; pa.ad2 = d_in[22]; pa.b2 = d_in[23];
  pa.x = x; pa.Bt1 = Bt1; pa.Bt2 = Bt2; pa.W1t = W1t; pa.W2t = W2t;
  pa.b1c = b1c; pa.b2c = b2c; pa.bg1 = bg1; pa.bg2 = bg2;
  pa.deg = deg; pa.cursor = cursor; pa.flag = flag;
  mega_prep<<<NB_PREP, 256, 0, stream>>>(pa);

  // movie feature path: K-split layer 1 (1252 blocks) + fused-reduce layer 2
  movie_gemm_k<<<NT_MOV * KSPLIT, 256, 0, stream>>>(mov_x, flag, W1t, part);
  movie_gemm2<<<NT_MOV, 256, 0, stream>>>(part, b1c, W2t, b2c,
                                          x + (long)N_USERS_C * D_IN_C);

  // CSR of in-edges (deg/cursor pre-zeroed by mega_prep)
  deg_count<<<(E_TOT_C + 255) / 256, 256, 0, stream>>>(ei, deg);
  deg_bsum<<<NB_SCAN, 256, 0, stream>>>(deg, bsum);
  bsum_scan<<<1, 512, 0, stream>>>(bsum, ptrn);
  deg_scan_final<<<NB_SCAN, 256, 0, stream>>>(deg, bsum, ptrn);
  scatter_edges<<<(E_TOT_C + 255) / 256, 256, 0, stream>>>(ei, ptrn, cursor, elist);

  // layer 1 (ukmax=64: pure-user blocks skip the zero K-range)
  gemm_fused<<<N_NODES_C / 64, 256, 0, stream>>>(x, Bt1, hs, als, ald, 192, 8, 64);
  aggregate1<<<N_NODES_C / 4, 256, 0, stream>>>(ptrn, elist, als, ald, hs, bg1, h1);

  // layer 2 (ukmax=K: disabled)
  gemm_fused<<<N_NODES_C / 64, 256, 0, stream>>>(h1, Bt2, hs, als, ald, 256, 1, 256);
  aggregate2<<<N_NODES_C / 4, 256, 0, stream>>>(ptrn, elist, als, ald, hs, bg2,
                                                (float*)d_out, out_size);
}

// Round 10
// 557.599 us; speedup vs baseline: 2.1443x; 1.0257x over previous
//
#include <hip/hip_runtime.h>
#include <hip/hip_bf16.h>

#define N_USERS_C 100000
#define N_ITEMS_C 20000
#define N_NODES_C 120000
#define E_TOT_C   400000
#define D_IN_C    192
#define HID_C     256
#define NEG_C     0.2f
#define CLAMP_C   1000.0f
#define KPAD_C    1152   // 1148 padded to multiple of 32
#define NB_SCAN   ((N_NODES_C + 255) / 256)   // 469 scan blocks
#define NB_EDGE   ((E_TOT_C + 255) / 256)     // 1563 edge blocks
#define NB_GEMM   (N_NODES_C / 64)            // 1875 gemm blocks
#define ROWE      40     // LDS row length in shorts: 32 k-elems + 8 pad (80B, 16B-aligned)
#define NT_MOV    313    // ceil(20000/64) row tiles
#define KSPLIT    4
#define KCH       288    // 1152 / KSPLIT

typedef __attribute__((ext_vector_type(8))) short bfrag;
typedef __attribute__((ext_vector_type(4))) float ffrag;

__device__ __forceinline__ float bf2f(unsigned short u){
  return __uint_as_float(((unsigned)u) << 16);
}
__device__ __forceinline__ float ldf(const void* p, long i, int isf32){
  return isf32 ? ((const float*)p)[i] : bf2f(((const unsigned short*)p)[i]);
}
__device__ __forceinline__ float sane(float v){
  return (v > -1e30f && v < 1e30f) ? v : 0.f;
}
__device__ __forceinline__ int clampsrc(int s){
  return s < 0 ? 0 : (s >= N_NODES_C ? N_NODES_C - 1 : s);
}
__device__ __forceinline__ short f2bs(float f){
  __hip_bfloat16 h = __float2bfloat16(f);
  return *reinterpret_cast<short*>(&h);
}

// ---------- dtype discriminator (inputs) ----------
__global__ __launch_bounds__(256) void detect_dtype(const unsigned short* __restrict__ ue,
                                                    int* __restrict__ flag){
  __shared__ int cnt[256];
  int tid = threadIdx.x; int c = 0;
  for (int i = tid; i < 8192; i += 256){
    unsigned e = (ue[i] >> 7) & 0xFFu;
    if (e >= 129u) c++;
  }
  cnt[tid] = c; __syncthreads();
  if (tid == 0){
    int s = 0;
    for (int i = 0; i < 256; i++) s += cnt[i];
    *flag = (s > 100) ? 1 : 0;
  }
}

// ---------- MEGA-PREP: one launch, 8-elems/thread vectorized (G13) ----------
struct PrepArgs {
  const void *ue, *ie;
  const void *gW1, *gb1, *gW2, *gb2, *tW1, *tb1, *tW2, *tb2;
  const void *Ws1, *Wd1, *as1, *ad1, *b1, *Ws2, *Wd2, *as2, *ad2, *b2;
  __hip_bfloat16 *x, *Bt1, *Bt2, *W1t, *W2t, *b1c, *b2c, *bg1, *bg2;
  int *deg, *cursor;
  const int* flag;
};

#define NB_UEMB  3125   // 100000*64 /8 /256
#define NB_UZERO 2      // 32 rows x 128 cols /8 /256
#define NB_MOVE  625    // 20000*64 /8 /256
#define NB_BT1   204    // 272*192 /256 (scalar)
#define NB_BT2   272    // 272*256 /256 (scalar)
#define NB_W1T   72     // 128*1152 /8 /256
#define NB_W2T   8      // 128*128 /8 /256
#define NB_ZERO  235    // 240000 ints /4 /256
#define NB_PREP (NB_UEMB+NB_UZERO+NB_MOVE+NB_BT1+NB_BT2+NB_W1T+NB_W2T+1+NB_ZERO)

__global__ __launch_bounds__(256) void mega_prep(PrepArgs a){
  int b = blockIdx.x, tid = threadIdx.x;
  int f32 = *a.flag;
  if (b < NB_UEMB) {                     // x user rows cols 0..63, 8 elems/thread
    int idx = b * 256 + tid;
    int n = idx >> 3, c0 = (idx & 7) * 8;
    union { short s[8]; float4 f; } u;
    if (f32) {
      const float* rf = (const float*)a.ue + (long)n * 64 + c0;
      float4 x0 = *(const float4*)rf, x1 = *(const float4*)(rf + 4);
      u.s[0]=f2bs(x0.x); u.s[1]=f2bs(x0.y); u.s[2]=f2bs(x0.z); u.s[3]=f2bs(x0.w);
      u.s[4]=f2bs(x1.x); u.s[5]=f2bs(x1.y); u.s[6]=f2bs(x1.z); u.s[7]=f2bs(x1.w);
    } else {
      u.f = *(const float4*)((const unsigned short*)a.ue + (long)n * 64 + c0);
    }
    *(float4*)(&a.x[(long)n * 192 + c0]) = u.f;
    return;
  }
  b -= NB_UEMB;
  if (b < NB_UZERO) {                    // boundary user rows 99968..99999, cols 64..191 = 0
    int idx = b * 256 + tid;
    int r = idx >> 4, c0 = 64 + (idx & 15) * 8;
    float4 z = {0.f, 0.f, 0.f, 0.f};
    *(float4*)(&a.x[(long)(99968 + r) * 192 + c0]) = z;
    return;
  }
  b -= NB_UZERO;
  if (b < NB_MOVE) {                     // x movie rows cols 0..63 = item_emb
    int idx = b * 256 + tid;
    int m = idx >> 3, c0 = (idx & 7) * 8;
    union { short s[8]; float4 f; } u;
    if (f32) {
      const float* rf = (const float*)a.ie + (long)m * 64 + c0;
      float4 x0 = *(const float4*)rf, x1 = *(const float4*)(rf + 4);
      u.s[0]=f2bs(x0.x); u.s[1]=f2bs(x0.y); u.s[2]=f2bs(x0.z); u.s[3]=f2bs(x0.w);
      u.s[4]=f2bs(x1.x); u.s[5]=f2bs(x1.y); u.s[6]=f2bs(x1.z); u.s[7]=f2bs(x1.w);
    } else {
      u.f = *(const float4*)((const unsigned short*)a.ie + (long)m * 64 + c0);
    }
    *(float4*)(&a.x[(long)(N_USERS_C + m) * 192 + c0]) = u.f;
    return;
  }
  b -= NB_MOVE;
  if (b < NB_BT1) {                      // Bt1 (272 x 192)
    int idx = b * 256 + tid;
    int col = idx / 192, k = idx - col * 192;
    float v;
    if (col < 256) v = ldf(a.Ws1, k * 256 + col, f32);
    else if (col < 264) {
      int h = col - 256; float s = 0.f;
      for (int c = 0; c < 32; c++)
        s += ldf(a.Ws1, k * 256 + h * 32 + c, f32) * ldf(a.as1, h * 32 + c, f32);
      v = s;
    } else {
      int h = col - 264; float s = 0.f;
      for (int c = 0; c < 32; c++)
        s += ldf(a.Wd1, k * 256 + h * 32 + c, f32) * ldf(a.ad1, h * 32 + c, f32);
      v = s;
    }
    a.Bt1[col * 192 + k] = __float2bfloat16(v);
    return;
  }
  b -= NB_BT1;
  if (b < NB_BT2) {                      // Bt2 (272 x 256), H=1, C=256
    int idx = b * 256 + tid;
    int col = idx / 256, k = idx & 255;
    float v;
    if (col < 256) v = ldf(a.Ws2, k * 256 + col, f32);
    else if (col == 256) {
      float s = 0.f;
      for (int c = 0; c < 256; c++)
        s += ldf(a.Ws2, k * 256 + c, f32) * ldf(a.as2, c, f32);
      v = s;
    } else if (col == 257) {
      float s = 0.f;
      for (int c = 0; c < 256; c++)
        s += ldf(a.Wd2, k * 256 + c, f32) * ldf(a.ad2, c, f32);
      v = s;
    } else v = 0.f;
    a.Bt2[col * 256 + k] = __float2bfloat16(v);
    return;
  }
  b -= NB_BT2;
  if (b < NB_W1T) {                      // W1t (128 x 1152), 8 elems/thread
    int idx = b * 256 + tid;
    int n = idx / 144, c8 = idx - n * 144;
    int k0 = c8 * 8;
    union { short s[8]; float4 f; } u;
#pragma unroll
    for (int j = 0; j < 8; j++) {
      int k = k0 + j; float v = 0.f;
      if (n < 64) { if (k < 20) v = ldf(a.gW1, k * 64 + n, f32); }
      else        { if (k >= 20 && k < 1148) v = ldf(a.tW1, (k - 20) * 64 + (n - 64), f32); }
      u.s[j] = f2bs(v);
    }
    *(float4*)(&a.W1t[(long)n * 1152 + k0]) = u.f;
    return;
  }
  b -= NB_W1T;
  if (b < NB_W2T) {                      // W2t (128 x 128) blockdiag, 8 elems/thread
    int idx = b * 256 + tid;
    int n = idx >> 4, k0 = (idx & 15) * 8;
    union { short s[8]; float4 f; } u;
#pragma unroll
    for (int j = 0; j < 8; j++) {
      int k = k0 + j; float v = 0.f;
      if (n < 64) { if (k < 64)  v = ldf(a.gW2, k * 64 + n, f32); }
      else        { if (k >= 64) v = ldf(a.tW2, (k - 64) * 64 + (n - 64), f32); }
      u.s[j] = f2bs(v);
    }
    *(float4*)(&a.W2t[n * 128 + k0]) = u.f;
    return;
  }
  b -= NB_W2T;
  if (b < 1) {                           // all bias vectors
    int i = tid;
    if (i < 64)       a.b1c[i] = __float2bfloat16(ldf(a.gb1, i, f32));
    else if (i < 128) a.b1c[i] = __float2bfloat16(ldf(a.tb1, i - 64, f32));
    else if (i < 192) a.b2c[i - 128] = __float2bfloat16(ldf(a.gb2, i - 128, f32));
    else              a.b2c[i - 128] = __float2bfloat16(ldf(a.tb2, i - 192, f32));
    a.bg1[tid] = __float2bfloat16(ldf(a.b1, tid, f32));
    a.bg2[tid] = __float2bfloat16(ldf(a.b2, tid, f32));
    return;
  }
  b -= 1;
  {                                      // zero deg + cursor, int4/thread
    int i0 = (b * 256 + tid) * 4;
    if (i0 < 2 * N_NODES_C) {
      int4 z = {0, 0, 0, 0};
      if (i0 < N_NODES_C) *(int4*)(a.deg + i0) = z;
      else                *(int4*)(a.cursor + (i0 - N_NODES_C)) = z;
    }
  }
}

// ---------- device bodies (shared between standalone & merged kernels) ----------

// movie layer 1 K-split partial: 64 rows x 128 cols over k-slice.
__device__ void movie_k_body(int bid, const void* __restrict__ rawA, int f32v,
                             const __hip_bfloat16* __restrict__ W1t,
                             float* __restrict__ part){
  __shared__ short Bls[128 * ROWE];
  __shared__ short Als[64 * ROWE];
  int tid = threadIdx.x;
  int wave = tid >> 6;
  int lane = tid & 63;
  int l15 = lane & 15;
  int quad = lane >> 4;
  int tile = bid % NT_MOV, split = bid / NT_MOV;
  int rowbase_blk = tile * 64;
  int rowbase = rowbase_blk + wave * 16;
  ffrag acc[8];
#pragma unroll
  for (int i = 0; i < 8; i++) acc[i] = (ffrag){0.f, 0.f, 0.f, 0.f};
  const short* Bs = (const short*)W1t;
  int sr = tid >> 2, sc = tid & 3;
  int arow_st = rowbase_blk + sr; if (arow_st >= N_ITEMS_C) arow_st = N_ITEMS_C - 1;
  int kbeg = split * KCH;
  for (int k0 = kbeg; k0 < kbeg + KCH; k0 += 32) {
    __syncthreads();
    for (int t = tid; t < 512; t += 256) {
      int r = t >> 2, c = t & 3;
      *(float4*)(&Bls[r * ROWE + c * 8]) =
          *(const float4*)(Bs + (long)r * KPAD_C + k0 + c * 8);
    }
    int kc = k0 + sc * 8;
    union { short s[8]; float4 f; } u;
    long base = (long)arow_st * 1148 + kc;
    if (kc + 8 <= 1148) {
      if (f32v) {
        const float* rf = (const float*)rawA + base;
        float4 x0 = *(const float4*)rf;
        float4 x1 = *(const float4*)(rf + 4);
        u.s[0]=f2bs(x0.x); u.s[1]=f2bs(x0.y); u.s[2]=f2bs(x0.z); u.s[3]=f2bs(x0.w);
        u.s[4]=f2bs(x1.x); u.s[5]=f2bs(x1.y); u.s[6]=f2bs(x1.z); u.s[7]=f2bs(x1.w);
      } else {
        const unsigned short* rs = (const unsigned short*)rawA + base;
        ushort4 a0 = *(const ushort4*)rs;
        ushort4 a1 = *(const ushort4*)(rs + 4);
        u.s[0]=(short)a0.x; u.s[1]=(short)a0.y; u.s[2]=(short)a0.z; u.s[3]=(short)a0.w;
        u.s[4]=(short)a1.x; u.s[5]=(short)a1.y; u.s[6]=(short)a1.z; u.s[7]=(short)a1.w;
      }
    } else {
#pragma unroll
      for (int j = 0; j < 8; j++) {
        float v = (kc + j < 1148) ? ldf(rawA, base + j, f32v) : 0.f;
        u.s[j] = f2bs(v);
      }
    }
    *(float4*)(&Als[sr * ROWE + sc * 8]) = u.f;
    __syncthreads();
    int koff = quad * 8;
    bfrag af = *(const bfrag*)(&Als[(wave * 16 + l15) * ROWE + koff]);
#pragma unroll
    for (int nt = 0; nt < 8; nt++) {
      bfrag bf = *(const bfrag*)(&Bls[(nt * 16 + l15) * ROWE + koff]);
      acc[nt] = __builtin_amdgcn_mfma_f32_16x16x32_bf16(af, bf, acc[nt], 0, 0, 0);
    }
  }
  float* pb = part + (long)split * (N_ITEMS_C * 128);
#pragma unroll
  for (int reg = 0; reg < 4; reg++) {
    int grow = rowbase + quad * 4 + reg;
    if (grow >= N_ITEMS_C) continue;
#pragma unroll
    for (int nt = 0; nt < 8; nt++)
      pb[(long)grow * 128 + nt * 16 + l15] = acc[nt][reg];
  }
}

// movie layer 2: reduce KSPLIT partials + bias1 + relu in A-staging.
__device__ void movie2_body(int bid, const float* __restrict__ part,
                            const __hip_bfloat16* __restrict__ b1c,
                            const __hip_bfloat16* __restrict__ W2t,
                            const __hip_bfloat16* __restrict__ b2c,
                            __hip_bfloat16* __restrict__ out){
  __shared__ short Bls[128 * ROWE];
  __shared__ short Als[64 * ROWE];
  int tid = threadIdx.x;
  int wave = tid >> 6;
  int lane = tid & 63;
  int l15 = lane & 15;
  int quad = lane >> 4;
  int rowbase_blk = bid * 64;
  int rowbase = rowbase_blk + wave * 16;
  ffrag acc[8];
#pragma unroll
  for (int i = 0; i < 8; i++) acc[i] = (ffrag){0.f, 0.f, 0.f, 0.f};
  const short* Bs = (const short*)W2t;
  int sr = tid >> 2, sc = tid & 3;
  int arow_st = rowbase_blk + sr; if (arow_st >= N_ITEMS_C) arow_st = N_ITEMS_C - 1;
  for (int k0 = 0; k0 < 128; k0 += 32) {
    __syncthreads();
    for (int t = tid; t < 512; t += 256) {
      int r = t >> 2, c = t & 3;
      *(float4*)(&Bls[r * ROWE + c * 8]) =
          *(const float4*)(Bs + (long)r * 128 + k0 + c * 8);
    }
    int kc = k0 + sc * 8;
    float vs[8];
#pragma unroll
    for (int j = 0; j < 8; j++) vs[j] = __bfloat162float(b1c[kc + j]);
    long base = (long)arow_st * 128 + kc;
#pragma unroll
    for (int s = 0; s < KSPLIT; s++) {
      const float* p = part + (long)s * (N_ITEMS_C * 128) + base;
      float4 q0 = *(const float4*)p, q1 = *(const float4*)(p + 4);
      vs[0] += q0.x; vs[1] += q0.y; vs[2] += q0.z; vs[3] += q0.w;
      vs[4] += q1.x; vs[5] += q1.y; vs[6] += q1.z; vs[7] += q1.w;
    }
    union { short s[8]; float4 f; } u;
#pragma unroll
    for (int j = 0; j < 8; j++) u.s[j] = f2bs(fmaxf(vs[j], 0.f));
    *(float4*)(&Als[sr * ROWE + sc * 8]) = u.f;
    __syncthreads();
    int koff = quad * 8;
    bfrag af = *(const bfrag*)(&Als[(wave * 16 + l15) * ROWE + koff]);
#pragma unroll
    for (int nt = 0; nt < 8; nt++) {
      bfrag bf = *(const bfrag*)(&Bls[(nt * 16 + l15) * ROWE + koff]);
      acc[nt] = __builtin_amdgcn_mfma_f32_16x16x32_bf16(af, bf, acc[nt], 0, 0, 0);
    }
  }
#pragma unroll
  for (int reg = 0; reg < 4; reg++) {
    int grow = rowbase + quad * 4 + reg;
    if (grow >= N_ITEMS_C) continue;
#pragma unroll
    for (int nt = 0; nt < 8; nt++) {
      float v = acc[nt][reg] + __bfloat162float(b2c[nt * 16 + l15]);
      out[(long)grow * D_IN_C + 64 + nt * 16 + l15] = __float2bfloat16(v);
    }
  }
}

// gemm_fused body: A (M x K bf16) @ Bt^T -> Hout + als/ald. ukmax per R5.
__device__ void gemm_fused_body(int bid,
    const __hip_bfloat16* __restrict__ A, const __hip_bfloat16* __restrict__ Bt,
    __hip_bfloat16* __restrict__ Hout, float* __restrict__ als, float* __restrict__ ald,
    int K, int natt, int ukmax){
  __shared__ short Bls[272 * ROWE];   // 21.25 KB
  __shared__ short Als[64 * ROWE];    //  5.0 KB
  int tid = threadIdx.x;
  int wave = tid >> 6;
  int lane = tid & 63;
  int l15 = lane & 15;
  int quad = lane >> 4;
  int rowbase_blk = bid * 64;
  int rowbase = rowbase_blk + wave * 16;
  int kmax = (rowbase_blk + 64 <= N_USERS_C) ? ukmax : K;
  ffrag acc[17];
#pragma unroll
  for (int i = 0; i < 17; i++) acc[i] = (ffrag){0.f, 0.f, 0.f, 0.f};
  const short* As = (const short*)A;
  const short* Bs = (const short*)Bt;
  int sr = tid >> 2, sc = tid & 3;
  for (int k0 = 0; k0 < kmax; k0 += 32) {
    __syncthreads();
    for (int t = tid; t < 1088; t += 256) {
      int r = t >> 2, c = t & 3;
      *(float4*)(&Bls[r * ROWE + c * 8]) = *(const float4*)(Bs + (long)r * K + k0 + c * 8);
    }
    *(float4*)(&Als[sr * ROWE + sc * 8]) =
        *(const float4*)(As + (long)(rowbase_blk + sr) * K + k0 + sc * 8);
    __syncthreads();
    int koff = quad * 8;
    bfrag af = *(const bfrag*)(&Als[(wave * 16 + l15) * ROWE + koff]);
#pragma unroll
    for (int nt = 0; nt < 17; nt++) {
      bfrag bf = *(const bfrag*)(&Bls[(nt * 16 + l15) * ROWE + koff]);
      acc[nt] = __builtin_amdgcn_mfma_f32_16x16x32_bf16(af, bf, acc[nt], 0, 0, 0);
    }
  }
  int col = l15;
#pragma unroll
  for (int reg = 0; reg < 4; reg++) {
    int grow = rowbase + quad * 4 + reg;
    long obase = (long)grow * 256;
#pragma unroll
    for (int nt = 0; nt < 16; nt++)
      Hout[obase + nt * 16 + col] = __float2bfloat16(acc[nt][reg]);
    float v = acc[16][reg];
    if (col < natt) als[grow * natt + col] = v;
    else if (col < 2 * natt) ald[grow * natt + (col - natt)] = v;
  }
}

__device__ void deg_count_body(int e, const int* __restrict__ ei, int* __restrict__ deg){
  if (e >= E_TOT_C) return;
  int dst = ei[E_TOT_C + e];
  if (dst >= 0 && dst < N_NODES_C) atomicAdd(&deg[dst], 1);
}

__device__ void deg_bsum_body(int bid, const int* __restrict__ deg, int* __restrict__ bsum){
  int i = bid * 256 + threadIdx.x;
  int v = (i < N_NODES_C) ? deg[i] : 0;
#pragma unroll
  for (int o = 32; o > 0; o >>= 1) v += __shfl_down(v, o, 64);
  __shared__ int ws[4];
  int wave = threadIdx.x >> 6, lane = threadIdx.x & 63;
  if (lane == 0) ws[wave] = v;
  __syncthreads();
  if (threadIdx.x == 0) bsum[bid] = ws[0] + ws[1] + ws[2] + ws[3];
}

__device__ void scatter_body(int e, const int* __restrict__ ei, const int* __restrict__ ptrn,
                             int* __restrict__ cursor, int* __restrict__ elist_src){
  if (e >= E_TOT_C) return;
  int dst = ei[E_TOT_C + e];
  if (dst < 0 || dst >= N_NODES_C) return;
  int pos = atomicAdd(&cursor[dst], 1);
  elist_src[ptrn[dst] + pos] = ei[e];
}

// ---------- merged kernels (block-range dispatch; each block takes ONE path) ----------
#define NB_KA (NT_MOV * KSPLIT + NB_EDGE)   // 1252 + 1563 = 2815
__global__ __launch_bounds__(256) void movie_k_degcnt(
    const void* __restrict__ rawA, const int* __restrict__ flag,
    const __hip_bfloat16* __restrict__ W1t, float* __restrict__ part,
    const int* __restrict__ ei, int* __restrict__ deg){
  int b = blockIdx.x;
  if (b < NT_MOV * KSPLIT) movie_k_body(b, rawA, *flag, W1t, part);
  else deg_count_body((b - NT_MOV * KSPLIT) * 256 + threadIdx.x, ei, deg);
}

#define NB_KB (NT_MOV + NB_SCAN)            // 313 + 469 = 782
__global__ __launch_bounds__(256) void movie2_bsum(
    const float* __restrict__ part, const __hip_bfloat16* __restrict__ b1c,
    const __hip_bfloat16* __restrict__ W2t, const __hip_bfloat16* __restrict__ b2c,
    __hip_bfloat16* __restrict__ out,
    const int* __restrict__ deg, int* __restrict__ bsum){
  int b = blockIdx.x;
  if (b < NT_MOV) movie2_body(b, part, b1c, W2t, b2c, out);
  else deg_bsum_body(b - NT_MOV, deg, bsum);
}

#define NB_KC (NB_GEMM + NB_EDGE)           // 1875 + 1563 = 3438
__global__ __launch_bounds__(256) void gemm1_scatter(
    const __hip_bfloat16* __restrict__ A, const __hip_bfloat16* __restrict__ Bt,
    __hip_bfloat16* __restrict__ Hout, float* __restrict__ als, float* __restrict__ ald,
    const int* __restrict__ ei, const int* __restrict__ ptrn,
    int* __restrict__ cursor, int* __restrict__ elist_src){
  int b = blockIdx.x;
  if (b < NB_GEMM) gemm_fused_body(b, A, Bt, Hout, als, ald, 192, 8, 64);
  else scatter_body((b - NB_GEMM) * 256 + threadIdx.x, ei, ptrn, cursor, elist_src);
}

// standalone gemm_fused for layer 2
__global__ __launch_bounds__(256) void gemm_fused(
    const __hip_bfloat16* __restrict__ A, const __hip_bfloat16* __restrict__ Bt,
    __hip_bfloat16* __restrict__ Hout, float* __restrict__ als, float* __restrict__ ald,
    int K, int natt, int ukmax){
  gemm_fused_body(blockIdx.x, A, Bt, Hout, als, ald, K, natt, ukmax);
}

// Stage 2: single-block Hillis-Steele scan of 469 block sums -> exclusive offsets.
__global__ __launch_bounds__(512) void bsum_scan(int* __restrict__ bsum,
                                                 int* __restrict__ ptrn){
  __shared__ int sm[512];
  int t = threadIdx.x;
  int v = (t < NB_SCAN) ? bsum[t] : 0;
  sm[t] = v;
  __syncthreads();
  for (int o = 1; o < 512; o <<= 1) {
    int add = (t >= o) ? sm[t - o] : 0;
    __syncthreads();
    sm[t] += add;
    __syncthreads();
  }
  int excl = (t == 0) ? 0 : sm[t - 1];
  if (t < NB_SCAN) bsum[t] = excl;
  if (t == NB_SCAN - 1) ptrn[N_NODES_C] = sm[t];
}

// Stage 3: in-block exclusive scan + block offset -> ptrn.
__global__ __launch_bounds__(256) void deg_scan_final(const int* __restrict__ deg,
                                                      const int* __restrict__ bexcl,
                                                      int* __restrict__ ptrn){
  __shared__ int sm[256];
  int i = blockIdx.x * 256 + threadIdx.x;
  int t = threadIdx.x;
  int v = (i < N_NODES_C) ? deg[i] : 0;
  sm[t] = v;
  __syncthreads();
  for (int o = 1; o < 256; o <<= 1) {
    int add = (t >= o) ? sm[t - o] : 0;
    __syncthreads();
    sm[t] += add;
    __syncthreads();
  }
  int excl = (t == 0) ? 0 : sm[t - 1];
  if (i < N_NODES_C) ptrn[i] = bexcl[blockIdx.x] + excl;
}

// ---------- layer 1: online-softmax aggregation, 2-deep software-pipelined gathers ----
__global__ __launch_bounds__(256) void aggregate1(
    const int* __restrict__ ptrn, const int* __restrict__ elist_src,
    const float* __restrict__ als, const float* __restrict__ ald,
    const __hip_bfloat16* __restrict__ hs, const __hip_bfloat16* __restrict__ bias,
    __hip_bfloat16* __restrict__ h1){
  int node = blockIdx.x * 4 + (threadIdx.x >> 6);
  if (node >= N_NODES_C) return;
  int lane = threadIdx.x & 63;
  int c0 = lane * 4;
  int h = lane >> 3;
  int beg = ptrn[node], end = ptrn[node + 1];
  float aldv = sane(ald[node * 8 + h]);
  float m = -1e30f;
  float wsum = 0.f, a0 = 0.f, a1 = 0.f, a2 = 0.f, a3 = 0.f;
  const unsigned short* hsu = (const unsigned short*)hs;
  float alsv_p = 0.f;
  ushort4 hv_p = {0, 0, 0, 0};
  int src_b = 0;
  if (beg < end) {
    int s0 = clampsrc(elist_src[beg]);
    alsv_p = als[(long)s0 * 8 + h];
    hv_p = *(const ushort4*)(hsu + (long)s0 * 256 + c0);
    if (beg + 1 < end) src_b = clampsrc(elist_src[beg + 1]);
  }
  for (int i = beg; i < end; i++) {
    float alsv = alsv_p;
    ushort4 hv = hv_p;
    if (i + 1 < end) {
      alsv_p = als[(long)src_b * 8 + h];
      hv_p = *(const ushort4*)(hsu + (long)src_b * 256 + c0);
    }
    if (i + 2 < end)
      src_b = clampsrc(elist_src[i + 2]);
    float ev = sane(alsv) + aldv;
    ev = ev > 0.f ? ev : NEG_C * ev;
    float mnew = fmaxf(m, ev);
    float corr = __expf(m - mnew);
    float w = __expf(ev - mnew);
    m = mnew;
    wsum = wsum * corr + w;
    a0 = a0 * corr + w * bf2f(hv.x); a1 = a1 * corr + w * bf2f(hv.y);
    a2 = a2 * corr + w * bf2f(hv.z); a3 = a3 * corr + w * bf2f(hv.w);
  }
  float inv = 1.f / (wsum + 1e-16f);
  float v0 = a0 * inv + __bfloat162float(bias[c0 + 0]);
  float v1 = a1 * inv + __bfloat162float(bias[c0 + 1]);
  float v2 = a2 * inv + __bfloat162float(bias[c0 + 2]);
  float v3 = a3 * inv + __bfloat162float(bias[c0 + 3]);
  v0 = v0 > 0.f ? v0 : (__expf(v0) - 1.f);
  v1 = v1 > 0.f ? v1 : (__expf(v1) - 1.f);
  v2 = v2 > 0.f ? v2 : (__expf(v2) - 1.f);
  v3 = v3 > 0.f ? v3 : (__expf(v3) - 1.f);
  v0 = fminf(fmaxf(v0, -CLAMP_C), CLAMP_C);
  v1 = fminf(fmaxf(v1, -CLAMP_C), CLAMP_C);
  v2 = fminf(fmaxf(v2, -CLAMP_C), CLAMP_C);
  v3 = fminf(fmaxf(v3, -CLAMP_C), CLAMP_C);
  long ob = (long)node * 256 + c0;
  h1[ob + 0] = __float2bfloat16(v0); h1[ob + 1] = __float2bfloat16(v1);
  h1[ob + 2] = __float2bfloat16(v2); h1[ob + 3] = __float2bfloat16(v3);
}

// ---------- layer 2: online softmax, pipelined, 1 head, f32 output (+tail fold) -----
__global__ __launch_bounds__(256) void aggregate2(
    const int* __restrict__ ptrn, const int* __restrict__ elist_src,
    const float* __restrict__ als, const float* __restrict__ ald,
    const __hip_bfloat16* __restrict__ hs, const __hip_bfloat16* __restrict__ bias,
    float* __restrict__ out, int out_size){
  if (blockIdx.x == 0 && threadIdx.x == 0) {
    out[out_size - 3] = 0.f;
    out[out_size - 2] = (float)N_USERS_C;
    out[out_size - 1] = (float)N_NODES_C;
  }
  int node = blockIdx.x * 4 + (threadIdx.x >> 6);
  if (node >= N_NODES_C) return;
  int lane = threadIdx.x & 63;
  int c0 = lane * 4;
  int beg = ptrn[node], end = ptrn[node + 1];
  float aldv = sane(ald[node]);
  float m = -1e30f;
  float wsum = 0.f, a0 = 0.f, a1 = 0.f, a2 = 0.f, a3 = 0.f;
  const unsigned short* hsu = (const unsigned short*)hs;
  float alsv_p = 0.f;
  ushort4 hv_p = {0, 0, 0, 0};
  int src_b = 0;
  if (beg < end) {
    int s0 = clampsrc(elist_src[beg]);
    alsv_p = als[s0];
    hv_p = *(const ushort4*)(hsu + (long)s0 * 256 + c0);
    if (beg + 1 < end) src_b = clampsrc(elist_src[beg + 1]);
  }
  for (int i = beg; i < end; i++) {
    float alsv = alsv_p;
    ushort4 hv = hv_p;
    if (i + 1 < end) {
      alsv_p = als[src_b];
      hv_p = *(const ushort4*)(hsu + (long)src_b * 256 + c0);
    }
    if (i + 2 < end)
      src_b = clampsrc(elist_src[i + 2]);
    float ev = sane(alsv) + aldv;
    ev = ev > 0.f ? ev : NEG_C * ev;
    float mnew = fmaxf(m, ev);
    float corr = __expf(m - mnew);
    float w = __expf(ev - mnew);
    m = mnew;
    wsum = wsum * corr + w;
    a0 = a0 * corr + w * bf2f(hv.x); a1 = a1 * corr + w * bf2f(hv.y);
    a2 = a2 * corr + w * bf2f(hv.z); a3 = a3 * corr + w * bf2f(hv.w);
  }
  float inv = 1.f / (wsum + 1e-16f);
  float4 v;
  v.x = a0 * inv + __bfloat162float(bias[c0 + 0]);
  v.y = a1 * inv + __bfloat162float(bias[c0 + 1]);
  v.z = a2 * inv + __bfloat162float(bias[c0 + 2]);
  v.w = a3 * inv + __bfloat162float(bias[c0 + 3]);
  v.x = fminf(fmaxf(v.x, -CLAMP_C), CLAMP_C);
  v.y = fminf(fmaxf(v.y, -CLAMP_C), CLAMP_C);
  v.z = fminf(fmaxf(v.z, -CLAMP_C), CLAMP_C);
  v.w = fminf(fmaxf(v.w, -CLAMP_C), CLAMP_C);
  *(float4*)(out + (long)node * 256 + c0) = v;
}

extern "C" void kernel_launch(void* const* d_in, const int* in_sizes, int n_in,
                              void* d_out, int out_size, void* d_ws, size_t ws_size,
                              hipStream_t stream) {
  const void* mov_x    = d_in[2];
  const int*  ei       = (const int*)d_in[3];
  const void* user_emb = d_in[4];
  const void* item_emb = d_in[5];

  char* ws = (char*)d_ws;
  size_t off = 0;
  auto alloc = [&](size_t bytes) -> void* {
    void* p = ws + off; off += (bytes + 255) / 256 * 256; return p;
  };
  int* flag   = (int*)alloc(4);
  __hip_bfloat16* Bt1 = (__hip_bfloat16*)alloc(272 * 192 * 2);
  __hip_bfloat16* Bt2 = (__hip_bfloat16*)alloc(272 * 256 * 2);
  __hip_bfloat16* W1t = (__hip_bfloat16*)alloc(128 * KPAD_C * 2);
  __hip_bfloat16* W2t = (__hip_bfloat16*)alloc(128 * 128 * 2);
  __hip_bfloat16* b1c = (__hip_bfloat16*)alloc(128 * 2);
  __hip_bfloat16* b2c = (__hip_bfloat16*)alloc(128 * 2);
  __hip_bfloat16* bg1 = (__hip_bfloat16*)alloc(256 * 2);
  __hip_bfloat16* bg2 = (__hip_bfloat16*)alloc(256 * 2);
  int* ptrn   = (int*)alloc((N_NODES_C + 1) * 4);
  int* deg    = (int*)alloc(N_NODES_C * 4);
  int* cursor = (int*)alloc(N_NODES_C * 4);
  int* bsum   = (int*)alloc(512 * 4);
  int* elist  = (int*)alloc(E_TOT_C * 4);
  float* als  = (float*)alloc((size_t)N_NODES_C * 8 * 4);
  float* ald  = (float*)alloc((size_t)N_NODES_C * 8 * 4);
  __hip_bfloat16* x  = (__hip_bfloat16*)alloc((size_t)N_NODES_C * D_IN_C * 2); // 46.08 MB
  __hip_bfloat16* hs = (__hip_bfloat16*)alloc((size_t)N_NODES_C * HID_C * 2);  // 61.44 MB
  // d_out (f32, 122.88 MB) hosts dead-before-aggregate2 temporaries:
  //   h1 (bf16 61.44 MB) at byte 0; movie K-split partials (4 x 10.24 MB f32)
  //   at byte 61,440,000 (consumed by movie2 long before aggregate2).
  __hip_bfloat16* h1  = (__hip_bfloat16*)d_out;
  float* part = (float*)((char*)d_out + 61440000);

  detect_dtype<<<1, 256, 0, stream>>>((const unsigned short*)user_emb, flag);

  PrepArgs pa;
  pa.ue = user_emb; pa.ie = item_emb;
  pa.gW1 = d_in[6];  pa.gb1 = d_in[7];  pa.gW2 = d_in[8];  pa.gb2 = d_in[9];
  pa.tW1 = d_in[10]; pa.tb1 = d_in[11]; pa.tW2 = d_in[12]; pa.tb2 = d_in[13];
  pa.Ws1 = d_in[14]; pa.Wd1 = d_in[15]; pa.as1 = d_in[16]; pa.ad1 = d_in[17]; pa.b1 = d_in[18];
  pa.Ws2 = d_in[19]; pa.Wd2 = d_in[20]; pa.as2 = d_in[21]; pa.ad2 = d_in[22]; pa.b2 = d_in[23];
  pa.x = x; pa.Bt1 = Bt1; pa.Bt2 = Bt2; pa.W1t = W1t; pa.W2t = W2t;
  pa.b1c = b1c; pa.b2c = b2c; pa.bg1 = bg1; pa.bg2 = bg2;
  pa.deg = deg; pa.cursor = cursor; pa.flag = flag;
  mega_prep<<<NB_PREP, 256, 0, stream>>>(pa);

  // [movie layer-1 K-split || deg_count]  (both depend only on mega_prep)
  movie_k_degcnt<<<NB_KA, 256, 0, stream>>>(mov_x, flag, W1t, part, ei, deg);
  // [movie layer-2 reduce || deg block sums]
  movie2_bsum<<<NB_KB, 256, 0, stream>>>(part, b1c, W2t, b2c,
                                         x + (long)N_USERS_C * D_IN_C, deg, bsum);
  bsum_scan<<<1, 512, 0, stream>>>(bsum, ptrn);
  deg_scan_final<<<NB_SCAN, 256, 0, stream>>>(deg, bsum, ptrn);

  // [gemm layer 1 (ukmax=64) || scatter_edges]  (deps: x-ready / ptrn-ready)
  gemm1_scatter<<<NB_KC, 256, 0, stream>>>(x, Bt1, hs, als, ald,
                                           ei, ptrn, cursor, elist);
  aggregate1<<<N_NODES_C / 4, 256, 0, stream>>>(ptrn, elist, als, ald, hs, bg1, h1);

  // layer 2
  gemm_fused<<<NB_GEMM, 256, 0, stream>>>(h1, Bt2, hs, als, ald, 256, 1, 256);
  aggregate2<<<N_NODES_C / 4, 256, 0, stream>>>(ptrn, elist, als, ald, hs, bg2,
                                                (float*)d_out, out_size);
}